// Round 1
// baseline (10761.633 us; speedup 1.0000x reference)
//
#include <hip/hip_runtime.h>
#include <cstdint>
#include <cstddef>

#define BB 2
#define TT 16385
#define NPAD 16640
#define DD 512
#define HH 8
#define DHH 64
#define MLAND 256
#define PADF 255

__device__ __forceinline__ float dot4f(const float4 a, const float4 b) {
  return a.x * b.x + a.y * b.y + a.z * b.z + a.w * b.w;
}

__device__ __forceinline__ float gelu_f(float v) {
  float c = 0.7978845608028654f * (v + 0.044715f * v * v * v);
  return 0.5f * v * (1.0f + tanhf(c));
}

// ---------------------------------------------------------------- cls rows
__global__ void k_set_cls(float* __restrict__ h, const float* __restrict__ cls) {
  h[(size_t)blockIdx.x * TT * DD + threadIdx.x] = cls[threadIdx.x];
}
__global__ void k_copy_cls(float* __restrict__ dst, const float* __restrict__ src) {
  size_t o = (size_t)blockIdx.x * TT * DD + threadIdx.x;
  dst[o] = src[o];
}

// ---------------------------------------------------------------- big GEMM
// MODE 0: feat: C[g + g/16384 + 1] = gelu(A@W + bias)   (A=x, lda=1024, N=512)
// MODE 1: plain: C = A@W                                 (qkv, N=1536)
// MODE 2: proj: h[b][i] += A[b*NPAD + 255 + i]@W + bias  (grid.z = batch)
template <int MODE>
__global__ __launch_bounds__(256) void k_gemm(
    const float* __restrict__ A, const float* __restrict__ W,
    const float* __restrict__ bias, float* __restrict__ C,
    int M, int K, int N, int lda) {
  __shared__ __align__(16) float As[16][128];
  __shared__ __align__(16) float Ws[16][128];
  const int t = threadIdx.x;
  const int tx = t & 15, ty = t >> 4;
  const int rb = blockIdx.x * 128, cbc = blockIdx.y * 128;
  const float* Ab = A;
  float* Cb = C;
  if (MODE == 2) {
    int b = blockIdx.z;
    Ab = A + (size_t)b * NPAD * DD + (size_t)PADF * DD;
    Cb = C + (size_t)b * TT * DD;
  }
  float acc[8][8];
#pragma unroll
  for (int i = 0; i < 8; ++i)
#pragma unroll
    for (int j = 0; j < 8; ++j) acc[i][j] = 0.f;

  const int am = t >> 1, ak = (t & 1) * 8;
  const int wk = t >> 4, wn = (t & 15) * 8;
  for (int k0 = 0; k0 < K; k0 += 16) {
    __syncthreads();
    {
      int row = rb + am;
      float4 v0 = {0, 0, 0, 0}, v1 = {0, 0, 0, 0};
      if (row < M) {
        const float* p = Ab + (size_t)row * lda + k0 + ak;
        v0 = *(const float4*)p;
        v1 = *(const float4*)(p + 4);
      }
      As[ak + 0][am] = v0.x; As[ak + 1][am] = v0.y;
      As[ak + 2][am] = v0.z; As[ak + 3][am] = v0.w;
      As[ak + 4][am] = v1.x; As[ak + 5][am] = v1.y;
      As[ak + 6][am] = v1.z; As[ak + 7][am] = v1.w;
    }
    {
      const float* p = W + (size_t)(k0 + wk) * N + cbc + wn;
      *(float4*)&Ws[wk][wn] = *(const float4*)p;
      *(float4*)&Ws[wk][wn + 4] = *(const float4*)(p + 4);
    }
    __syncthreads();
#pragma unroll
    for (int kk = 0; kk < 16; ++kk) {
      float4 a0 = *(float4*)&As[kk][ty * 4];
      float4 a1 = *(float4*)&As[kk][64 + ty * 4];
      float4 w0 = *(float4*)&Ws[kk][tx * 4];
      float4 w1 = *(float4*)&Ws[kk][64 + tx * 4];
      float av[8] = {a0.x, a0.y, a0.z, a0.w, a1.x, a1.y, a1.z, a1.w};
      float wv[8] = {w0.x, w0.y, w0.z, w0.w, w1.x, w1.y, w1.z, w1.w};
#pragma unroll
      for (int i = 0; i < 8; ++i)
#pragma unroll
        for (int j = 0; j < 8; ++j) acc[i][j] += av[i] * wv[j];
    }
  }
#pragma unroll
  for (int ri = 0; ri < 2; ++ri)
#pragma unroll
    for (int ii = 0; ii < 4; ++ii) {
      int r = rb + ri * 64 + ty * 4 + ii;
      if (r >= M) continue;
      size_t orow;
      if (MODE == 0) {
        int bb = r >> 14;
        orow = (size_t)(r + bb + 1);
      } else {
        orow = (size_t)r;
      }
#pragma unroll
      for (int ci = 0; ci < 2; ++ci) {
        int c = cbc + ci * 64 + tx * 4;
        float4 v;
        v.x = acc[ri * 4 + ii][ci * 4 + 0];
        v.y = acc[ri * 4 + ii][ci * 4 + 1];
        v.z = acc[ri * 4 + ii][ci * 4 + 2];
        v.w = acc[ri * 4 + ii][ci * 4 + 3];
        if (MODE == 0) {
          float4 bi = *(const float4*)(bias + c);
          v.x = gelu_f(v.x + bi.x); v.y = gelu_f(v.y + bi.y);
          v.z = gelu_f(v.z + bi.z); v.w = gelu_f(v.w + bi.w);
          *(float4*)(Cb + orow * DD + c) = v;
        } else if (MODE == 1) {
          *(float4*)(Cb + orow * (size_t)N + c) = v;
        } else {
          float4 bi = *(const float4*)(bias + c);
          float4 old = *(float4*)(Cb + orow * DD + c);
          v.x += bi.x + old.x; v.y += bi.y + old.y;
          v.z += bi.z + old.z; v.w += bi.w + old.w;
          *(float4*)(Cb + orow * DD + c) = v;
        }
      }
    }
}

// ---------------------------------------------------------------- LN + pad
__global__ __launch_bounds__(256) void k_ln_pad(
    float* __restrict__ xp, const float* __restrict__ h,
    const float* __restrict__ gam, const float* __restrict__ bet) {
  int w = threadIdx.x >> 6, lane = threadIdx.x & 63;
  int row = blockIdx.x * 4 + w;
  if (row >= BB * TT) return;
  int b = row / TT, i = row - b * TT;
  const float* src = h + (size_t)row * DD;
  float4 x0 = *(const float4*)(src + lane * 4);
  float4 x1 = *(const float4*)(src + 256 + lane * 4);
  float s = x0.x + x0.y + x0.z + x0.w + x1.x + x1.y + x1.z + x1.w;
  for (int o = 32; o; o >>= 1) s += __shfl_xor(s, o);
  float mu = s * (1.f / 512.f);
  float q = (x0.x - mu) * (x0.x - mu) + (x0.y - mu) * (x0.y - mu) +
            (x0.z - mu) * (x0.z - mu) + (x0.w - mu) * (x0.w - mu) +
            (x1.x - mu) * (x1.x - mu) + (x1.y - mu) * (x1.y - mu) +
            (x1.z - mu) * (x1.z - mu) + (x1.w - mu) * (x1.w - mu);
  for (int o = 32; o; o >>= 1) q += __shfl_xor(q, o);
  float rs = rsqrtf(q * (1.f / 512.f) + 1e-5f);
  float4 g0 = *(const float4*)(gam + lane * 4);
  float4 g1 = *(const float4*)(gam + 256 + lane * 4);
  float4 b0 = *(const float4*)(bet + lane * 4);
  float4 b1 = *(const float4*)(bet + 256 + lane * 4);
  float* dst = xp + ((size_t)b * NPAD + PADF + i) * DD;
  float4 o0, o1;
  o0.x = (x0.x - mu) * rs * g0.x + b0.x;
  o0.y = (x0.y - mu) * rs * g0.y + b0.y;
  o0.z = (x0.z - mu) * rs * g0.z + b0.z;
  o0.w = (x0.w - mu) * rs * g0.w + b0.w;
  o1.x = (x1.x - mu) * rs * g1.x + b1.x;
  o1.y = (x1.y - mu) * rs * g1.y + b1.y;
  o1.z = (x1.z - mu) * rs * g1.z + b1.z;
  o1.w = (x1.w - mu) * rs * g1.w + b1.w;
  *(float4*)(dst + lane * 4) = o0;
  *(float4*)(dst + 256 + lane * 4) = o1;
}

__global__ void k_zero_pad(float* __restrict__ xp) {
  int r = blockIdx.x;  // 0..509
  int b = r / PADF, j = r - b * PADF;
  float* p = xp + ((size_t)b * NPAD + j) * DD;
  p[threadIdx.x * 2] = 0.f;
  p[threadIdx.x * 2 + 1] = 0.f;
}

// ---------------------------------------------------------------- landmarks
__global__ __launch_bounds__(256) void k_landmarks(
    float* __restrict__ ql, float* __restrict__ kl, const float* __restrict__ qkv) {
  int t = threadIdx.x;
  int mi = t >> 6, d = t & 63;
  int blk = blockIdx.x;  // bh*64 + mg
  int bh = blk >> 6, mg = blk & 63;
  int b = bh >> 3, h = bh & 7;
  int m = mg * 4 + mi;
  const float* base = qkv + (size_t)b * NPAD * 1536 + h * 64 + d;
  float sq = 0.f, sk = 0.f;
  int t0 = m * 65;
  for (int j = 0; j < 65; ++j) {
    const float* p = base + (size_t)(t0 + j) * 1536;
    sq += p[0];
    sk += p[512];
  }
  ql[((size_t)bh * 256 + m) * 64 + d] = sq * (0.125f / 65.f);
  kl[((size_t)bh * 256 + m) * 64 + d] = sk * (1.f / 65.f);
}

// ---------------------------------------------------------------- sim2 = ql @ kl^T
__global__ __launch_bounds__(256) void k_sim2(
    float* __restrict__ sim, const float* __restrict__ ql, const float* __restrict__ kl) {
  __shared__ __align__(16) float Aq[64][68];
  __shared__ __align__(16) float Bk[64][68];
  int t = threadIdx.x;
  int tj = blockIdx.x, ti = blockIdx.y, bh = blockIdx.z;
  int r = t >> 2, cc = (t & 3) * 16;
  const float* ap = ql + ((size_t)bh * 256 + ti * 64 + r) * 64 + cc;
  const float* bp = kl + ((size_t)bh * 256 + tj * 64 + r) * 64 + cc;
#pragma unroll
  for (int i = 0; i < 16; i += 4) {
    *(float4*)&Aq[r][cc + i] = *(const float4*)(ap + i);
    *(float4*)&Bk[r][cc + i] = *(const float4*)(bp + i);
  }
  __syncthreads();
  int tx = t & 15, ty = t >> 4;
  float acc[4][4];
#pragma unroll
  for (int i = 0; i < 4; ++i)
#pragma unroll
    for (int j = 0; j < 4; ++j) acc[i][j] = 0.f;
  for (int d = 0; d < 64; d += 4) {
    float4 a4[4], b4[4];
#pragma unroll
    for (int ii = 0; ii < 4; ++ii) a4[ii] = *(float4*)&Aq[ty * 4 + ii][d];
#pragma unroll
    for (int jj = 0; jj < 4; ++jj) b4[jj] = *(float4*)&Bk[tx * 4 + jj][d];
#pragma unroll
    for (int ii = 0; ii < 4; ++ii)
#pragma unroll
      for (int jj = 0; jj < 4; ++jj) acc[ii][jj] += dot4f(a4[ii], b4[jj]);
  }
#pragma unroll
  for (int ii = 0; ii < 4; ++ii)
#pragma unroll
    for (int jj = 0; jj < 4; ++jj)
      sim[((size_t)bh * 256 + ti * 64 + ty * 4 + ii) * 256 + tj * 64 + tx * 4 + jj] =
          acc[ii][jj];
}

// ---------------------------------------------------------------- row softmax (len 256)
__global__ __launch_bounds__(256) void k_softmax256(float* __restrict__ a) {
  int w = threadIdx.x >> 6, lane = threadIdx.x & 63;
  size_t row = (size_t)blockIdx.x * 4 + w;
  float* p = a + row * 256 + lane * 4;
  float4 v = *(float4*)p;
  float m = fmaxf(fmaxf(v.x, v.y), fmaxf(v.z, v.w));
  for (int o = 32; o; o >>= 1) m = fmaxf(m, __shfl_xor(m, o));
  v.x = expf(v.x - m); v.y = expf(v.y - m);
  v.z = expf(v.z - m); v.w = expf(v.w - m);
  float s = v.x + v.y + v.z + v.w;
  for (int o = 32; o; o >>= 1) s += __shfl_xor(s, o);
  float inv = 1.f / s;
  v.x *= inv; v.y *= inv; v.z *= inv; v.w *= inv;
  *(float4*)p = v;
}

// ---------------------------------------------------------------- pinv helpers
__global__ void k_pinv_sums(float* __restrict__ red, const float* __restrict__ a2) {
  int bh = blockIdx.x, t = threadIdx.x;
  const float* Ab = a2 + (size_t)bh * 65536;
  float s = 0.f;
  for (int i = 0; i < 256; ++i) s += fabsf(Ab[(size_t)i * 256 + t]);
  red[bh * 256 + t] = s;  // sum over -2 ("row")
  float c = 0.f;
  const float* rp = Ab + (size_t)t * 256;
  for (int j = 0; j < 256; j += 4) {
    float4 v = *(const float4*)(rp + j);
    c += fabsf(v.x) + fabsf(v.y) + fabsf(v.z) + fabsf(v.w);
  }
  red[4096 + bh * 256 + t] = c;  // sum over -1 ("col")
}

__global__ void k_pinv_scale(float* __restrict__ red) {
  __shared__ float sm[8];
  int t = threadIdx.x;
  float m1 = 0.f, m2 = 0.f;
  for (int k = t; k < 4096; k += 256) {
    m1 = fmaxf(m1, red[k]);
    m2 = fmaxf(m2, red[4096 + k]);
  }
  for (int o = 32; o; o >>= 1) {
    m1 = fmaxf(m1, __shfl_xor(m1, o));
    m2 = fmaxf(m2, __shfl_xor(m2, o));
  }
  int w = t >> 6;
  if ((t & 63) == 0) { sm[w] = m1; sm[4 + w] = m2; }
  __syncthreads();
  if (t == 0) {
    float a = fmaxf(fmaxf(sm[0], sm[1]), fmaxf(sm[2], sm[3]));
    float b = fmaxf(fmaxf(sm[4], sm[5]), fmaxf(sm[6], sm[7]));
    red[8192] = 1.0f / (a * b);
  }
}

__global__ void k_zinit(float* __restrict__ z, const float* __restrict__ a2,
                        const float* __restrict__ red) {
  float s = red[8192];
  int i = blockIdx.x, bh = blockIdx.y, j = threadIdx.x;
  z[((size_t)bh * 256 + i) * 256 + j] = a2[((size_t)bh * 256 + j) * 256 + i] * s;
}

// batched (16) 256x256 @ 256xN; C1 = a1*(A@B) + d1*I ; optional C2 = a2c*(A@B) + d2*I
__global__ __launch_bounds__(256) void k_bmm(
    const float* __restrict__ A, const float* __restrict__ Bm,
    float* __restrict__ C1, float a1, float d1,
    float* __restrict__ C2, float a2c, float d2, int N) {
  __shared__ __align__(16) float As[16][64];
  __shared__ __align__(16) float Bs[16][64];
  int t = threadIdx.x;
  int bh = blockIdx.z;
  int i0 = blockIdx.y * 64, j0 = blockIdx.x * 64;
  const float* Ab = A + (size_t)bh * 65536;
  const float* Bb = Bm + (size_t)bh * 256 * N;
  float acc[4][4];
#pragma unroll
  for (int i = 0; i < 4; ++i)
#pragma unroll
    for (int j = 0; j < 4; ++j) acc[i][j] = 0.f;
  int tx = t & 15, ty = t >> 4;
  for (int k0 = 0; k0 < 256; k0 += 16) {
    __syncthreads();
    {
      int r = t >> 2, kl2 = (t & 3) * 4;
      float4 v = *(const float4*)(Ab + (size_t)(i0 + r) * 256 + k0 + kl2);
      As[kl2 + 0][r] = v.x; As[kl2 + 1][r] = v.y;
      As[kl2 + 2][r] = v.z; As[kl2 + 3][r] = v.w;
    }
    {
      int kr = t >> 4, nl = (t & 15) * 4;
      *(float4*)&Bs[kr][nl] = *(const float4*)(Bb + (size_t)(k0 + kr) * N + j0 + nl);
    }
    __syncthreads();
#pragma unroll
    for (int kk = 0; kk < 16; ++kk) {
      float4 a4 = *(float4*)&As[kk][ty * 4];
      float4 b4 = *(float4*)&Bs[kk][tx * 4];
      float av[4] = {a4.x, a4.y, a4.z, a4.w};
      float bv2[4] = {b4.x, b4.y, b4.z, b4.w};
#pragma unroll
      for (int i = 0; i < 4; ++i)
#pragma unroll
        for (int j = 0; j < 4; ++j) acc[i][j] += av[i] * bv2[j];
    }
  }
#pragma unroll
  for (int ii = 0; ii < 4; ++ii)
#pragma unroll
    for (int jj = 0; jj < 4; ++jj) {
      int i = i0 + ty * 4 + ii, j = j0 + tx * 4 + jj;
      float v = acc[ii][jj];
      size_t off = (size_t)bh * 256 * N + (size_t)i * N + j;
      C1[off] = a1 * v + ((i == j) ? d1 : 0.f);
      if (C2) C2[off] = a2c * v + ((i == j) ? d2 : 0.f);
    }
}

// ---------------------------------------------------------------- a3 @ v (flash over n)
__global__ __launch_bounds__(256) void k_a3v(
    float* __restrict__ bv, const float* __restrict__ ql, const float* __restrict__ qkv) {
  __shared__ __align__(16) float qlS[16][68];
  __shared__ __align__(16) float kS[64][68];
  __shared__ __align__(16) float vS[64][68];
  __shared__ __align__(16) float pS[16][68];
  int t = threadIdx.x;
  int mb = blockIdx.x;  // 0..15
  int bh = blockIdx.y;  // 0..15
  int b = bh >> 3, h = bh & 7;
  {
    int mi = t >> 4, d = (t & 15) * 4;
    *(float4*)&qlS[mi][d] =
        *(const float4*)(ql + ((size_t)bh * 256 + mb * 16 + mi) * 64 + d);
  }
  int m = t >> 4, tx = t & 15;
  float rmax = -INFINITY, rsum = 0.f;
  float4 acc = {0, 0, 0, 0};
  int ldr = t >> 2;
  int ldcc = (t & 3) * 16;
  const float* kbase = qkv + (size_t)b * NPAD * 1536 + 512 + h * 64 + ldcc;
  for (int nt = 0; nt < NPAD; nt += 64) {
    __syncthreads();
    {
      const float* kp = kbase + (size_t)(nt + ldr) * 1536;
#pragma unroll
      for (int i = 0; i < 16; i += 4) {
        *(float4*)&kS[ldr][ldcc + i] = *(const float4*)(kp + i);
        *(float4*)&vS[ldr][ldcc + i] = *(const float4*)(kp + 512 + i);
      }
    }
    __syncthreads();
    float s[4] = {0.f, 0.f, 0.f, 0.f};
    for (int d = 0; d < 64; d += 4) {
      float4 q4 = *(float4*)&qlS[m][d];
#pragma unroll
      for (int j = 0; j < 4; ++j) s[j] += dot4f(q4, *(float4*)&kS[tx + 16 * j][d]);
    }
    float lmax = fmaxf(fmaxf(s[0], s[1]), fmaxf(s[2], s[3]));
    for (int o = 8; o; o >>= 1) lmax = fmaxf(lmax, __shfl_xor(lmax, o));
    float nm = fmaxf(rmax, lmax);
    float corr = expf(rmax - nm);
    float p[4], ls = 0.f;
#pragma unroll
    for (int j = 0; j < 4; ++j) {
      p[j] = expf(s[j] - nm);
      ls += p[j];
    }
    for (int o = 8; o; o >>= 1) ls += __shfl_xor(ls, o);
    rsum = rsum * corr + ls;
    acc.x *= corr; acc.y *= corr; acc.z *= corr; acc.w *= corr;
#pragma unroll
    for (int j = 0; j < 4; ++j) pS[m][tx + 16 * j] = p[j];
    __syncthreads();
    for (int c = 0; c < 64; c += 4) {
      float4 p4 = *(float4*)&pS[m][c];
      float4 v0 = *(float4*)&vS[c + 0][tx * 4];
      float4 v1 = *(float4*)&vS[c + 1][tx * 4];
      float4 v2 = *(float4*)&vS[c + 2][tx * 4];
      float4 v3 = *(float4*)&vS[c + 3][tx * 4];
      acc.x += p4.x * v0.x + p4.y * v1.x + p4.z * v2.x + p4.w * v3.x;
      acc.y += p4.x * v0.y + p4.y * v1.y + p4.z * v2.y + p4.w * v3.y;
      acc.z += p4.x * v0.z + p4.y * v1.z + p4.z * v2.z + p4.w * v3.z;
      acc.w += p4.x * v0.w + p4.y * v1.w + p4.z * v2.w + p4.w * v3.w;
    }
    rmax = nm;
  }
  float inv = 1.0f / rsum;
  float4 outv = {acc.x * inv, acc.y * inv, acc.z * inv, acc.w * inv};
  *(float4*)(bv + ((size_t)bh * 256 + mb * 16 + m) * 64 + tx * 4) = outv;
}

// -------------------------------------------- out = softmax(q@kl^T)@W2 + conv(v)
__global__ __launch_bounds__(256) void k_attn_out(
    float* __restrict__ attout, const float* __restrict__ qkv,
    const float* __restrict__ kl, const float* __restrict__ w2,
    const float* __restrict__ resw) {
  __shared__ __align__(16) float qS[32][68];
  __shared__ __align__(16) float cS[64][68];
  __shared__ __align__(16) float S[32][264];
  __shared__ float w33[40];
  int t = threadIdx.x;
  int tb = blockIdx.x, bh = blockIdx.y;
  int b = bh >> 3, h = bh & 7;
  int n0 = tb * 32;
  {
    int r = t >> 3, d = (t & 7) * 8;
    const float* p = qkv + ((size_t)(b * NPAD) + n0 + r) * 1536 + h * 64 + d;
    float4 v0 = *(const float4*)p, v1 = *(const float4*)(p + 4);
    qS[r][d + 0] = v0.x * 0.125f; qS[r][d + 1] = v0.y * 0.125f;
    qS[r][d + 2] = v0.z * 0.125f; qS[r][d + 3] = v0.w * 0.125f;
    qS[r][d + 4] = v1.x * 0.125f; qS[r][d + 5] = v1.y * 0.125f;
    qS[r][d + 6] = v1.z * 0.125f; qS[r][d + 7] = v1.w * 0.125f;
  }
  if (t < 33) w33[t] = resw[h * 33 + t];
  int tt = t >> 3, jg = t & 7;
  float sc[4][8];
#pragma unroll
  for (int cb = 0; cb < 4; ++cb)
#pragma unroll
    for (int jj = 0; jj < 8; ++jj) sc[cb][jj] = 0.f;
  // Phase A: scores vs 256 landmarks, chunks of 64
#pragma unroll
  for (int cb = 0; cb < 4; ++cb) {
    __syncthreads();
    {
      int r = t >> 2, cc = (t & 3) * 16;
      const float* p = kl + ((size_t)bh * 256 + cb * 64 + r) * 64 + cc;
#pragma unroll
      for (int i = 0; i < 16; i += 4) *(float4*)&cS[r][cc + i] = *(const float4*)(p + i);
    }
    __syncthreads();
    for (int d = 0; d < 64; d += 4) {
      float4 q4 = *(float4*)&qS[tt][d];
#pragma unroll
      for (int jj = 0; jj < 8; ++jj)
        sc[cb][jj] += dot4f(q4, *(float4*)&cS[jg + 8 * jj][d]);
    }
  }
  // Phase B: softmax over the 32 register scores (8 threads per token)
  float lmax = -INFINITY;
#pragma unroll
  for (int cb = 0; cb < 4; ++cb)
#pragma unroll
    for (int jj = 0; jj < 8; ++jj) lmax = fmaxf(lmax, sc[cb][jj]);
  for (int o = 4; o; o >>= 1) lmax = fmaxf(lmax, __shfl_xor(lmax, o));
  float lsum = 0.f;
#pragma unroll
  for (int cb = 0; cb < 4; ++cb)
#pragma unroll
    for (int jj = 0; jj < 8; ++jj) {
      float p = expf(sc[cb][jj] - lmax);
      S[tt][cb * 64 + jg + 8 * jj] = p;
      lsum += p;
    }
  for (int o = 4; o; o >>= 1) lsum += __shfl_xor(lsum, o);
  float invL = 1.0f / lsum;
  // Phase C: @ W2
  int dg = t & 7, d0 = dg * 8;
  float acc[8] = {0.f, 0.f, 0.f, 0.f, 0.f, 0.f, 0.f, 0.f};
  for (int cb = 0; cb < 4; ++cb) {
    __syncthreads();
    {
      int r = t >> 2, cc = (t & 3) * 16;
      const float* p = w2 + ((size_t)bh * 256 + cb * 64 + r) * 64 + cc;
#pragma unroll
      for (int i = 0; i < 16; i += 4) *(float4*)&cS[r][cc + i] = *(const float4*)(p + i);
    }
    __syncthreads();
    for (int c = 0; c < 64; c += 4) {
      float4 p4 = *(float4*)&S[tt][cb * 64 + c];
      float pv[4] = {p4.x, p4.y, p4.z, p4.w};
#pragma unroll
      for (int i = 0; i < 4; ++i) {
        float4 w0 = *(float4*)&cS[c + i][d0];
        float4 w1 = *(float4*)&cS[c + i][d0 + 4];
        acc[0] += pv[i] * w0.x; acc[1] += pv[i] * w0.y;
        acc[2] += pv[i] * w0.z; acc[3] += pv[i] * w0.w;
        acc[4] += pv[i] * w1.x; acc[5] += pv[i] * w1.y;
        acc[6] += pv[i] * w1.z; acc[7] += pv[i] * w1.w;
      }
    }
  }
  // Phase D: depthwise conv residual on v (33 taps, pad 16)
  __syncthreads();
  {
    int r = t >> 2, cc = (t & 3) * 16;
    int seq = n0 - 16 + r;
    if (seq >= 0 && seq < NPAD) {
      const float* p = qkv + ((size_t)(b * NPAD) + seq) * 1536 + 1024 + h * 64 + cc;
#pragma unroll
      for (int i = 0; i < 16; i += 4) *(float4*)&cS[r][cc + i] = *(const float4*)(p + i);
    } else {
      float4 z = {0, 0, 0, 0};
#pragma unroll
      for (int i = 0; i < 16; i += 4) *(float4*)&cS[r][cc + i] = z;
    }
  }
  __syncthreads();
  float cacc[8] = {0.f, 0.f, 0.f, 0.f, 0.f, 0.f, 0.f, 0.f};
  for (int k = 0; k < 33; ++k) {
    float wv = w33[k];
    float4 v0 = *(float4*)&cS[tt + k][d0];
    float4 v1 = *(float4*)&cS[tt + k][d0 + 4];
    cacc[0] += wv * v0.x; cacc[1] += wv * v0.y;
    cacc[2] += wv * v0.z; cacc[3] += wv * v0.w;
    cacc[4] += wv * v1.x; cacc[5] += wv * v1.y;
    cacc[6] += wv * v1.z; cacc[7] += wv * v1.w;
  }
  float* dst = attout + ((size_t)(b * NPAD) + n0 + tt) * DD + h * 64 + d0;
  float4 o0 = {acc[0] * invL + cacc[0], acc[1] * invL + cacc[1],
               acc[2] * invL + cacc[2], acc[3] * invL + cacc[3]};
  float4 o1 = {acc[4] * invL + cacc[4], acc[5] * invL + cacc[5],
               acc[6] * invL + cacc[6], acc[7] * invL + cacc[7]};
  *(float4*)dst = o0;
  *(float4*)(dst + 4) = o1;
}

// ---------------------------------------------------------------- PPEG
__global__ __launch_bounds__(128) void k_ppeg(
    float* __restrict__ hB, const float* __restrict__ hA,
    const float* __restrict__ w7, const float* __restrict__ b7,
    const float* __restrict__ w5, const float* __restrict__ b5,
    const float* __restrict__ w3, const float* __restrict__ b3) {
  __shared__ float wS[83 * 128];
  int t = threadIdx.x;             // 0..127 (channel within group)
  int i = blockIdx.x;              // 0..127
  int cg = blockIdx.y;             // 0..3
  int b = blockIdx.z;              // 0..1
  int c = cg * 128 + t;
  for (int k = 0; k < 49; ++k) wS[k * 128 + t] = w7[c * 49 + k];
  for (int k = 0; k < 25; ++k) wS[(49 + k) * 128 + t] = w5[c * 25 + k];
  for (int k = 0; k < 9; ++k) wS[(74 + k) * 128 + t] = w3[c * 9 + k];
  float bias = b7[c] + b5[c] + b3[c];
  __syncthreads();
  const float* base = hA + (size_t)b * TT * DD + DD + c;
  float* obase = hB + (size_t)b * TT * DD + DD + c;
  for (int j = 0; j < 128; ++j) {
    float acc = bias + base[(size_t)(i * 128 + j) * DD];
    for (int di = -3; di <= 3; ++di) {
      int ii = i + di;
      if ((unsigned)ii >= 128u) continue;
      const float* rowp = base + (size_t)(ii * 128) * DD;
      for (int dj = -3; dj <= 3; ++dj) {
        int jj = j + dj;
        if ((unsigned)jj >= 128u) continue;
        acc += rowp[(size_t)jj * DD] * wS[((di + 3) * 7 + dj + 3) * 128 + t];
      }
    }
    for (int di = -2; di <= 2; ++di) {
      int ii = i + di;
      if ((unsigned)ii >= 128u) continue;
      const float* rowp = base + (size_t)(ii * 128) * DD;
      for (int dj = -2; dj <= 2; ++dj) {
        int jj = j + dj;
        if ((unsigned)jj >= 128u) continue;
        acc += rowp[(size_t)jj * DD] * wS[(49 + (di + 2) * 5 + dj + 2) * 128 + t];
      }
    }
    for (int di = -1; di <= 1; ++di) {
      int ii = i + di;
      if ((unsigned)ii >= 128u) continue;
      const float* rowp = base + (size_t)(ii * 128) * DD;
      for (int dj = -1; dj <= 1; ++dj) {
        int jj = j + dj;
        if ((unsigned)jj >= 128u) continue;
        acc += rowp[(size_t)jj * DD] * wS[(74 + (di + 1) * 3 + dj + 1) * 128 + t];
      }
    }
    obase[(size_t)(i * 128 + j) * DD] = acc;
  }
}

// ---------------------------------------------------------------- final head
__global__ __launch_bounds__(512) void k_final(
    float* __restrict__ out, const float* __restrict__ h,
    const float* __restrict__ g, const float* __restrict__ be,
    const float* __restrict__ cw, const float* __restrict__ cbias) {
  __shared__ float sm[16];
  int t = threadIdx.x;
  for (int b = 0; b < 2; ++b) {
    const float* row = h + (size_t)b * TT * DD;
    float x = row[t];
    float s = x;
    for (int o = 32; o; o >>= 1) s += __shfl_xor(s, o);
    if ((t & 63) == 0) sm[t >> 6] = s;
    __syncthreads();
    float mu = 0.f;
    for (int i = 0; i < 8; ++i) mu += sm[i];
    mu *= (1.f / 512.f);
    __syncthreads();
    float d = x - mu;
    s = d * d;
    for (int o = 32; o; o >>= 1) s += __shfl_xor(s, o);
    if ((t & 63) == 0) sm[t >> 6] = s;
    __syncthreads();
    float var = 0.f;
    for (int i = 0; i < 8; ++i) var += sm[i];
    var *= (1.f / 512.f);
    float rs = rsqrtf(var + 1e-5f);
    __syncthreads();
    float f = d * rs * g[t] + be[t];
    float p0 = f * cw[2 * t], p1 = f * cw[2 * t + 1];
    for (int o = 32; o; o >>= 1) {
      p0 += __shfl_xor(p0, o);
      p1 += __shfl_xor(p1, o);
    }
    if ((t & 63) == 0) {
      sm[t >> 6] = p0;
      sm[8 + (t >> 6)] = p1;
    }
    __syncthreads();
    if (t == 0) {
      float q0 = 0.f, q1 = 0.f;
      for (int i = 0; i < 8; ++i) {
        q0 += sm[i];
        q1 += sm[8 + i];
      }
      out[b * 2 + 0] = q0 + cbias[0];
      out[b * 2 + 1] = q1 + cbias[1];
    }
    __syncthreads();
  }
}

// ---------------------------------------------------------------- host side
static void run_attn(float* h, const float* lng, const float* lnb,
                     const float* wqkv, const float* wout, const float* bout,
                     const float* resw, float* xp, float* qkv, float* ql, float* kl,
                     float* a2, float* z0, float* z1, float* xz, float* yA, float* yB,
                     float* yC, float* bv, float* w2, float* red, hipStream_t stream) {
  k_zero_pad<<<BB * PADF, 256, 0, stream>>>(xp);
  k_ln_pad<<<(BB * TT + 3) / 4, 256, 0, stream>>>(xp, h, lng, lnb);
  k_gemm<1><<<dim3(BB * NPAD / 128, 1536 / 128), 256, 0, stream>>>(
      xp, wqkv, nullptr, qkv, BB * NPAD, DD, 1536, DD);
  k_landmarks<<<1024, 256, 0, stream>>>(ql, kl, qkv);
  k_a3v<<<dim3(16, 16), 256, 0, stream>>>(bv, ql, qkv);
  k_sim2<<<dim3(4, 4, 16), 256, 0, stream>>>(a2, ql, kl);
  k_softmax256<<<1024, 256, 0, stream>>>(a2);
  k_pinv_sums<<<16, 256, 0, stream>>>(red, a2);
  k_pinv_scale<<<1, 256, 0, stream>>>(red);
  k_zinit<<<dim3(256, 16), 256, 0, stream>>>(z0, a2, red);
  float* zc = z0;
  float* zn = z1;
  for (int it = 0; it < 6; ++it) {
    k_bmm<<<dim3(4, 4, 16), 256, 0, stream>>>(a2, zc, xz, 1.f, 0.f, yA, -1.f, 7.f, 256);
    k_bmm<<<dim3(4, 4, 16), 256, 0, stream>>>(xz, yA, yB, -1.f, 15.f, nullptr, 0.f, 0.f, 256);
    k_bmm<<<dim3(4, 4, 16), 256, 0, stream>>>(xz, yB, yC, -1.f, 13.f, nullptr, 0.f, 0.f, 256);
    k_bmm<<<dim3(4, 4, 16), 256, 0, stream>>>(zc, yC, zn, 0.25f, 0.f, nullptr, 0.f, 0.f, 256);
    float* tmp = zc; zc = zn; zn = tmp;
  }
  k_bmm<<<dim3(1, 4, 16), 256, 0, stream>>>(zc, bv, w2, 1.f, 0.f, nullptr, 0.f, 0.f, 64);
  k_attn_out<<<dim3(NPAD / 32, 16), 256, 0, stream>>>(xp, qkv, kl, w2, resw);
  k_gemm<2><<<dim3((TT + 127) / 128, 4, BB), 256, 0, stream>>>(xp, wout, bout, h, TT, DD,
                                                               DD, DD);
}

extern "C" void kernel_launch(void* const* d_in, const int* in_sizes, int n_in,
                              void* d_out, int out_size, void* d_ws, size_t ws_size,
                              hipStream_t stream) {
  const float* x        = (const float*)d_in[0];
  const float* w_feat   = (const float*)d_in[1];
  const float* b_feat   = (const float*)d_in[2];
  const float* cls_tok  = (const float*)d_in[3];
  const float* ln1_g    = (const float*)d_in[4];
  const float* ln1_b    = (const float*)d_in[5];
  const float* qkv1     = (const float*)d_in[6];
  const float* out1_w   = (const float*)d_in[7];
  const float* out1_b   = (const float*)d_in[8];
  const float* res1_w   = (const float*)d_in[9];
  const float* ppeg_w7  = (const float*)d_in[10];
  const float* ppeg_b7  = (const float*)d_in[11];
  const float* ppeg_w5  = (const float*)d_in[12];
  const float* ppeg_b5  = (const float*)d_in[13];
  const float* ppeg_w3  = (const float*)d_in[14];
  const float* ppeg_b3  = (const float*)d_in[15];
  const float* ln2_g    = (const float*)d_in[16];
  const float* ln2_b    = (const float*)d_in[17];
  const float* qkv2     = (const float*)d_in[18];
  const float* out2_w   = (const float*)d_in[19];
  const float* out2_b   = (const float*)d_in[20];
  const float* res2_w   = (const float*)d_in[21];
  const float* lnf_g    = (const float*)d_in[22];
  const float* lnf_b    = (const float*)d_in[23];
  const float* cls_w    = (const float*)d_in[24];
  const float* cls_b    = (const float*)d_in[25];

  float* ws = (float*)d_ws;
  size_t off = 0;
  float* hA  = ws + off; off += (size_t)BB * TT * DD;        // 16,778,240
  float* hB  = ws + off; off += (size_t)BB * TT * DD;
  float* xp  = ws + off; off += (size_t)BB * NPAD * DD;      // also attout
  float* qkv = ws + off; off += (size_t)BB * NPAD * 3 * DD;
  float* ql  = ws + off; off += (size_t)BB * HH * 256 * 64;
  float* kl  = ws + off; off += (size_t)BB * HH * 256 * 64;
  float* a2  = ws + off; off += (size_t)16 * 65536;
  float* z0  = ws + off; off += (size_t)16 * 65536;
  float* z1  = ws + off; off += (size_t)16 * 65536;
  float* xz  = ws + off; off += (size_t)16 * 65536;
  float* yA  = ws + off; off += (size_t)16 * 65536;
  float* yB  = ws + off; off += (size_t)16 * 65536;
  float* yC  = ws + off; off += (size_t)16 * 65536;
  float* bv  = ws + off; off += (size_t)BB * HH * 256 * 64;
  float* w2  = ws + off; off += (size_t)BB * HH * 256 * 64;
  float* red = ws + off; off += 8448;

  // Stage 1: h = gelu(x @ w_feat + b_feat), prepend cls token
  k_set_cls<<<2, 512, 0, stream>>>(hA, cls_tok);
  k_gemm<0><<<dim3(32768 / 128, 512 / 128), 256, 0, stream>>>(x, w_feat, b_feat, hA,
                                                              32768, 1024, 512, 1024);
  // Attention 1 (residual in-place on hA)
  run_attn(hA, ln1_g, ln1_b, qkv1, out1_w, out1_b, res1_w, xp, qkv, ql, kl, a2, z0, z1,
           xz, yA, yB, yC, bv, w2, red, stream);
  // PPEG: hB = ppeg(hA)
  k_copy_cls<<<2, 512, 0, stream>>>(hB, hA);
  k_ppeg<<<dim3(128, 4, 2), 128, 0, stream>>>(hB, hA, ppeg_w7, ppeg_b7, ppeg_w5, ppeg_b5,
                                              ppeg_w3, ppeg_b3);
  // Attention 2 (residual in-place on hB)
  run_attn(hB, ln2_g, ln2_b, qkv2, out2_w, out2_b, res2_w, xp, qkv, ql, kl, a2, z0, z1,
           xz, yA, yB, yC, bv, w2, red, stream);
  // Final: LN(cls) @ cls_w + cls_b
  k_final<<<1, 512, 0, stream>>>((float*)d_out, hB, lnf_g, lnf_b, cls_w, cls_b);
}

// Round 2
// 7158.944 us; speedup vs baseline: 1.5032x; 1.5032x over previous
//
#include <hip/hip_runtime.h>
#include <cstdint>
#include <cstddef>

#define BB 2
#define TT 16385
#define NPAD 16640
#define DD 512
#define HH 8
#define DHH 64
#define MLAND 256
#define PADF 255
#define NBH 2

__device__ __forceinline__ float dot4f(const float4 a, const float4 b) {
  return a.x * b.x + a.y * b.y + a.z * b.z + a.w * b.w;
}

__device__ __forceinline__ float gelu_f(float v) {
  float c = 0.7978845608028654f * (v + 0.044715f * v * v * v);
  return 0.5f * v * (1.0f + tanhf(c));
}

// ---------------------------------------------------------------- cls rows
__global__ void k_set_cls(float* __restrict__ h, const float* __restrict__ cls) {
  h[(size_t)blockIdx.x * TT * DD + threadIdx.x] = cls[threadIdx.x];
}
__global__ void k_copy_cls(float* __restrict__ dst, const float* __restrict__ src) {
  size_t o = (size_t)blockIdx.x * TT * DD + threadIdx.x;
  dst[o] = src[o];
}

// ---------------------------------------------------------------- big GEMM
// MODE 0: feat: C[g + g/16384 + 1] = gelu(A@W + bias)   (A=x, lda=1024, N=512)
// MODE 1: plain: C = A@W                                 (qkv, N=1536)
// MODE 2: proj: h[b][i] += A[b*NPAD + 255 + i]@W + bias  (grid.z = batch)
template <int MODE>
__global__ __launch_bounds__(256) void k_gemm(
    const float* __restrict__ A, const float* __restrict__ W,
    const float* __restrict__ bias, float* __restrict__ C,
    int M, int K, int N, int lda) {
  __shared__ __align__(16) float As[16][128];
  __shared__ __align__(16) float Ws[16][128];
  const int t = threadIdx.x;
  const int tx = t & 15, ty = t >> 4;
  const int rb = blockIdx.x * 128, cbc = blockIdx.y * 128;
  const float* Ab = A;
  float* Cb = C;
  if (MODE == 2) {
    int b = blockIdx.z;
    Ab = A + (size_t)b * NPAD * DD + (size_t)PADF * DD;
    Cb = C + (size_t)b * TT * DD;
  }
  float acc[8][8];
#pragma unroll
  for (int i = 0; i < 8; ++i)
#pragma unroll
    for (int j = 0; j < 8; ++j) acc[i][j] = 0.f;

  const int am = t >> 1, ak = (t & 1) * 8;
  const int wk = t >> 4, wn = (t & 15) * 8;
  for (int k0 = 0; k0 < K; k0 += 16) {
    __syncthreads();
    {
      int row = rb + am;
      float4 v0 = {0, 0, 0, 0}, v1 = {0, 0, 0, 0};
      if (row < M) {
        const float* p = Ab + (size_t)row * lda + k0 + ak;
        v0 = *(const float4*)p;
        v1 = *(const float4*)(p + 4);
      }
      As[ak + 0][am] = v0.x; As[ak + 1][am] = v0.y;
      As[ak + 2][am] = v0.z; As[ak + 3][am] = v0.w;
      As[ak + 4][am] = v1.x; As[ak + 5][am] = v1.y;
      As[ak + 6][am] = v1.z; As[ak + 7][am] = v1.w;
    }
    {
      const float* p = W + (size_t)(k0 + wk) * N + cbc + wn;
      *(float4*)&Ws[wk][wn] = *(const float4*)p;
      *(float4*)&Ws[wk][wn + 4] = *(const float4*)(p + 4);
    }
    __syncthreads();
#pragma unroll
    for (int kk = 0; kk < 16; ++kk) {
      float4 a0 = *(float4*)&As[kk][ty * 4];
      float4 a1 = *(float4*)&As[kk][64 + ty * 4];
      float4 w0 = *(float4*)&Ws[kk][tx * 4];
      float4 w1 = *(float4*)&Ws[kk][64 + tx * 4];
      float av[8] = {a0.x, a0.y, a0.z, a0.w, a1.x, a1.y, a1.z, a1.w};
      float wv[8] = {w0.x, w0.y, w0.z, w0.w, w1.x, w1.y, w1.z, w1.w};
#pragma unroll
      for (int i = 0; i < 8; ++i)
#pragma unroll
        for (int j = 0; j < 8; ++j) acc[i][j] += av[i] * wv[j];
    }
  }
#pragma unroll
  for (int ri = 0; ri < 2; ++ri)
#pragma unroll
    for (int ii = 0; ii < 4; ++ii) {
      int r = rb + ri * 64 + ty * 4 + ii;
      if (r >= M) continue;
      size_t orow;
      if (MODE == 0) {
        int bb = r >> 14;
        orow = (size_t)(r + bb + 1);
      } else {
        orow = (size_t)r;
      }
#pragma unroll
      for (int ci = 0; ci < 2; ++ci) {
        int c = cbc + ci * 64 + tx * 4;
        float4 v;
        v.x = acc[ri * 4 + ii][ci * 4 + 0];
        v.y = acc[ri * 4 + ii][ci * 4 + 1];
        v.z = acc[ri * 4 + ii][ci * 4 + 2];
        v.w = acc[ri * 4 + ii][ci * 4 + 3];
        if (MODE == 0) {
          float4 bi = *(const float4*)(bias + c);
          v.x = gelu_f(v.x + bi.x); v.y = gelu_f(v.y + bi.y);
          v.z = gelu_f(v.z + bi.z); v.w = gelu_f(v.w + bi.w);
          *(float4*)(Cb + orow * DD + c) = v;
        } else if (MODE == 1) {
          *(float4*)(Cb + orow * (size_t)N + c) = v;
        } else {
          float4 bi = *(const float4*)(bias + c);
          float4 old = *(float4*)(Cb + orow * DD + c);
          v.x += bi.x + old.x; v.y += bi.y + old.y;
          v.z += bi.z + old.z; v.w += bi.w + old.w;
          *(float4*)(Cb + orow * DD + c) = v;
        }
      }
    }
}

// ---------------------------------------------------------------- LN + pad
__global__ __launch_bounds__(256) void k_ln_pad(
    float* __restrict__ xp, const float* __restrict__ h,
    const float* __restrict__ gam, const float* __restrict__ bet) {
  int w = threadIdx.x >> 6, lane = threadIdx.x & 63;
  int row = blockIdx.x * 4 + w;
  if (row >= BB * TT) return;
  int b = row / TT, i = row - b * TT;
  const float* src = h + (size_t)row * DD;
  float4 x0 = *(const float4*)(src + lane * 4);
  float4 x1 = *(const float4*)(src + 256 + lane * 4);
  float s = x0.x + x0.y + x0.z + x0.w + x1.x + x1.y + x1.z + x1.w;
  for (int o = 32; o; o >>= 1) s += __shfl_xor(s, o);
  float mu = s * (1.f / 512.f);
  float q = (x0.x - mu) * (x0.x - mu) + (x0.y - mu) * (x0.y - mu) +
            (x0.z - mu) * (x0.z - mu) + (x0.w - mu) * (x0.w - mu) +
            (x1.x - mu) * (x1.x - mu) + (x1.y - mu) * (x1.y - mu) +
            (x1.z - mu) * (x1.z - mu) + (x1.w - mu) * (x1.w - mu);
  for (int o = 32; o; o >>= 1) q += __shfl_xor(q, o);
  float rs = rsqrtf(q * (1.f / 512.f) + 1e-5f);
  float4 g0 = *(const float4*)(gam + lane * 4);
  float4 g1 = *(const float4*)(gam + 256 + lane * 4);
  float4 b0 = *(const float4*)(bet + lane * 4);
  float4 b1 = *(const float4*)(bet + 256 + lane * 4);
  float* dst = xp + ((size_t)b * NPAD + PADF + i) * DD;
  float4 o0, o1;
  o0.x = (x0.x - mu) * rs * g0.x + b0.x;
  o0.y = (x0.y - mu) * rs * g0.y + b0.y;
  o0.z = (x0.z - mu) * rs * g0.z + b0.z;
  o0.w = (x0.w - mu) * rs * g0.w + b0.w;
  o1.x = (x1.x - mu) * rs * g1.x + b1.x;
  o1.y = (x1.y - mu) * rs * g1.y + b1.y;
  o1.z = (x1.z - mu) * rs * g1.z + b1.z;
  o1.w = (x1.w - mu) * rs * g1.w + b1.w;
  *(float4*)(dst + lane * 4) = o0;
  *(float4*)(dst + 256 + lane * 4) = o1;
}

__global__ void k_zero_pad(float* __restrict__ xp) {
  int r = blockIdx.x;  // 0..509
  int b = r / PADF, j = r - b * PADF;
  float* p = xp + ((size_t)b * NPAD + j) * DD;
  p[threadIdx.x * 2] = 0.f;
  p[threadIdx.x * 2 + 1] = 0.f;
}

// ---------------------------------------------------------------- landmarks
__global__ __launch_bounds__(256) void k_landmarks(
    float* __restrict__ ql, float* __restrict__ kl, const float* __restrict__ qkv) {
  int t = threadIdx.x;
  int mi = t >> 6, d = t & 63;
  int blk = blockIdx.x;  // bh*64 + mg
  int bh = blk >> 6, mg = blk & 63;
  int b = bh >> 3, h = bh & 7;
  int m = mg * 4 + mi;
  const float* base = qkv + (size_t)b * NPAD * 1536 + h * 64 + d;
  float sq = 0.f, sk = 0.f;
  int t0 = m * 65;
  for (int j = 0; j < 65; ++j) {
    const float* p = base + (size_t)(t0 + j) * 1536;
    sq += p[0];
    sk += p[512];
  }
  ql[((size_t)bh * 256 + m) * 64 + d] = sq * (0.125f / 65.f);
  kl[((size_t)bh * 256 + m) * 64 + d] = sk * (1.f / 65.f);
}

// ---------------------------------------------------------------- sim2 = ql @ kl^T
__global__ __launch_bounds__(256) void k_sim2(
    float* __restrict__ sim, const float* __restrict__ ql, const float* __restrict__ kl) {
  __shared__ __align__(16) float Aq[64][68];
  __shared__ __align__(16) float Bk[64][68];
  int t = threadIdx.x;
  int tj = blockIdx.x, ti = blockIdx.y, bh = blockIdx.z;
  int r = t >> 2, cc = (t & 3) * 16;
  const float* ap = ql + ((size_t)bh * 256 + ti * 64 + r) * 64 + cc;
  const float* bp = kl + ((size_t)bh * 256 + tj * 64 + r) * 64 + cc;
#pragma unroll
  for (int i = 0; i < 16; i += 4) {
    *(float4*)&Aq[r][cc + i] = *(const float4*)(ap + i);
    *(float4*)&Bk[r][cc + i] = *(const float4*)(bp + i);
  }
  __syncthreads();
  int tx = t & 15, ty = t >> 4;
  float acc[4][4];
#pragma unroll
  for (int i = 0; i < 4; ++i)
#pragma unroll
    for (int j = 0; j < 4; ++j) acc[i][j] = 0.f;
  for (int d = 0; d < 64; d += 4) {
    float4 a4[4], b4[4];
#pragma unroll
    for (int ii = 0; ii < 4; ++ii) a4[ii] = *(float4*)&Aq[ty * 4 + ii][d];
#pragma unroll
    for (int jj = 0; jj < 4; ++jj) b4[jj] = *(float4*)&Bk[tx * 4 + jj][d];
#pragma unroll
    for (int ii = 0; ii < 4; ++ii)
#pragma unroll
      for (int jj = 0; jj < 4; ++jj) acc[ii][jj] += dot4f(a4[ii], b4[jj]);
  }
#pragma unroll
  for (int ii = 0; ii < 4; ++ii)
#pragma unroll
    for (int jj = 0; jj < 4; ++jj)
      sim[((size_t)bh * 256 + ti * 64 + ty * 4 + ii) * 256 + tj * 64 + tx * 4 + jj] =
          acc[ii][jj];
}

// ---------------------------------------------------------------- row softmax (len 256)
__global__ __launch_bounds__(256) void k_softmax256(float* __restrict__ a) {
  int w = threadIdx.x >> 6, lane = threadIdx.x & 63;
  size_t row = (size_t)blockIdx.x * 4 + w;
  float* p = a + row * 256 + lane * 4;
  float4 v = *(float4*)p;
  float m = fmaxf(fmaxf(v.x, v.y), fmaxf(v.z, v.w));
  for (int o = 32; o; o >>= 1) m = fmaxf(m, __shfl_xor(m, o));
  v.x = expf(v.x - m); v.y = expf(v.y - m);
  v.z = expf(v.z - m); v.w = expf(v.w - m);
  float s = v.x + v.y + v.z + v.w;
  for (int o = 32; o; o >>= 1) s += __shfl_xor(s, o);
  float inv = 1.f / s;
  v.x *= inv; v.y *= inv; v.z *= inv; v.w *= inv;
  *(float4*)p = v;
}

// ---------------------------------------------------------------- pinv helpers
__global__ void k_pinv_sums(float* __restrict__ red, const float* __restrict__ a2) {
  int bh = blockIdx.x, t = threadIdx.x;
  const float* Ab = a2 + (size_t)bh * 65536;
  float s = 0.f;
  for (int i = 0; i < 256; ++i) s += fabsf(Ab[(size_t)i * 256 + t]);
  red[bh * 256 + t] = s;  // sum over -2 ("row")
  float c = 0.f;
  const float* rp = Ab + (size_t)t * 256;
  for (int j = 0; j < 256; j += 4) {
    float4 v = *(const float4*)(rp + j);
    c += fabsf(v.x) + fabsf(v.y) + fabsf(v.z) + fabsf(v.w);
  }
  red[4096 + bh * 256 + t] = c;  // sum over -1 ("col")
}

__global__ void k_pinv_scale(float* __restrict__ red) {
  __shared__ float sm[8];
  int t = threadIdx.x;
  float m1 = 0.f, m2 = 0.f;
  for (int k = t; k < 4096; k += 256) {
    m1 = fmaxf(m1, red[k]);
    m2 = fmaxf(m2, red[4096 + k]);
  }
  for (int o = 32; o; o >>= 1) {
    m1 = fmaxf(m1, __shfl_xor(m1, o));
    m2 = fmaxf(m2, __shfl_xor(m2, o));
  }
  int w = t >> 6;
  if ((t & 63) == 0) { sm[w] = m1; sm[4 + w] = m2; }
  __syncthreads();
  if (t == 0) {
    float a = fmaxf(fmaxf(sm[0], sm[1]), fmaxf(sm[2], sm[3]));
    float b = fmaxf(fmaxf(sm[4], sm[5]), fmaxf(sm[6], sm[7]));
    red[8192] = 1.0f / (a * b);
  }
}

__global__ void k_zinit(float* __restrict__ z, const float* __restrict__ a2,
                        const float* __restrict__ red) {
  float s = red[8192];
  int i = blockIdx.x, bh = blockIdx.y, j = threadIdx.x;
  z[((size_t)bh * 256 + i) * 256 + j] = a2[((size_t)bh * 256 + j) * 256 + i] * s;
}

// batched (16) 256x256 @ 256xN; C1 = a1*(A@B) + d1*I ; optional C2 = a2c*(A@B) + d2*I
__global__ __launch_bounds__(256) void k_bmm(
    const float* __restrict__ A, const float* __restrict__ Bm,
    float* __restrict__ C1, float a1, float d1,
    float* __restrict__ C2, float a2c, float d2, int N) {
  __shared__ __align__(16) float As[16][64];
  __shared__ __align__(16) float Bs[16][64];
  int t = threadIdx.x;
  int bh = blockIdx.z;
  int i0 = blockIdx.y * 64, j0 = blockIdx.x * 64;
  const float* Ab = A + (size_t)bh * 65536;
  const float* Bb = Bm + (size_t)bh * 256 * N;
  float acc[4][4];
#pragma unroll
  for (int i = 0; i < 4; ++i)
#pragma unroll
    for (int j = 0; j < 4; ++j) acc[i][j] = 0.f;
  int tx = t & 15, ty = t >> 4;
  for (int k0 = 0; k0 < 256; k0 += 16) {
    __syncthreads();
    {
      int r = t >> 2, kl2 = (t & 3) * 4;
      float4 v = *(const float4*)(Ab + (size_t)(i0 + r) * 256 + k0 + kl2);
      As[kl2 + 0][r] = v.x; As[kl2 + 1][r] = v.y;
      As[kl2 + 2][r] = v.z; As[kl2 + 3][r] = v.w;
    }
    {
      int kr = t >> 4, nl = (t & 15) * 4;
      *(float4*)&Bs[kr][nl] = *(const float4*)(Bb + (size_t)(k0 + kr) * N + j0 + nl);
    }
    __syncthreads();
#pragma unroll
    for (int kk = 0; kk < 16; ++kk) {
      float4 a4 = *(float4*)&As[kk][ty * 4];
      float4 b4 = *(float4*)&Bs[kk][tx * 4];
      float av[4] = {a4.x, a4.y, a4.z, a4.w};
      float bv2[4] = {b4.x, b4.y, b4.z, b4.w};
#pragma unroll
      for (int i = 0; i < 4; ++i)
#pragma unroll
        for (int j = 0; j < 4; ++j) acc[i][j] += av[i] * bv2[j];
    }
  }
#pragma unroll
  for (int ii = 0; ii < 4; ++ii)
#pragma unroll
    for (int jj = 0; jj < 4; ++jj) {
      int i = i0 + ty * 4 + ii, j = j0 + tx * 4 + jj;
      float v = acc[ii][jj];
      size_t off = (size_t)bh * 256 * N + (size_t)i * N + j;
      C1[off] = a1 * v + ((i == j) ? d1 : 0.f);
      if (C2) C2[off] = a2c * v + ((i == j) ? d2 : 0.f);
    }
}

// ---------------------------------------------------------------- a3 @ v (flash over n)
__global__ __launch_bounds__(256) void k_a3v(
    float* __restrict__ bv, const float* __restrict__ ql, const float* __restrict__ qkv) {
  __shared__ __align__(16) float qlS[16][68];
  __shared__ __align__(16) float kS[64][68];
  __shared__ __align__(16) float vS[64][68];
  __shared__ __align__(16) float pS[16][68];
  int t = threadIdx.x;
  int mb = blockIdx.x;  // 0..15
  int bh = blockIdx.y;  // 0..15
  int b = bh >> 3, h = bh & 7;
  {
    int mi = t >> 4, d = (t & 15) * 4;
    *(float4*)&qlS[mi][d] =
        *(const float4*)(ql + ((size_t)bh * 256 + mb * 16 + mi) * 64 + d);
  }
  int m = t >> 4, tx = t & 15;
  float rmax = -INFINITY, rsum = 0.f;
  float4 acc = {0, 0, 0, 0};
  int ldr = t >> 2;
  int ldcc = (t & 3) * 16;
  const float* kbase = qkv + (size_t)b * NPAD * 1536 + 512 + h * 64 + ldcc;
  for (int nt = 0; nt < NPAD; nt += 64) {
    __syncthreads();
    {
      const float* kp = kbase + (size_t)(nt + ldr) * 1536;
#pragma unroll
      for (int i = 0; i < 16; i += 4) {
        *(float4*)&kS[ldr][ldcc + i] = *(const float4*)(kp + i);
        *(float4*)&vS[ldr][ldcc + i] = *(const float4*)(kp + 512 + i);
      }
    }
    __syncthreads();
    float s[4] = {0.f, 0.f, 0.f, 0.f};
    for (int d = 0; d < 64; d += 4) {
      float4 q4 = *(float4*)&qlS[m][d];
#pragma unroll
      for (int j = 0; j < 4; ++j) s[j] += dot4f(q4, *(float4*)&kS[tx + 16 * j][d]);
    }
    float lmax = fmaxf(fmaxf(s[0], s[1]), fmaxf(s[2], s[3]));
    for (int o = 8; o; o >>= 1) lmax = fmaxf(lmax, __shfl_xor(lmax, o));
    float nm = fmaxf(rmax, lmax);
    float corr = expf(rmax - nm);
    float p[4], ls = 0.f;
#pragma unroll
    for (int j = 0; j < 4; ++j) {
      p[j] = expf(s[j] - nm);
      ls += p[j];
    }
    for (int o = 8; o; o >>= 1) ls += __shfl_xor(ls, o);
    rsum = rsum * corr + ls;
    acc.x *= corr; acc.y *= corr; acc.z *= corr; acc.w *= corr;
#pragma unroll
    for (int j = 0; j < 4; ++j) pS[m][tx + 16 * j] = p[j];
    __syncthreads();
    for (int c = 0; c < 64; c += 4) {
      float4 p4 = *(float4*)&pS[m][c];
      float4 v0 = *(float4*)&vS[c + 0][tx * 4];
      float4 v1 = *(float4*)&vS[c + 1][tx * 4];
      float4 v2 = *(float4*)&vS[c + 2][tx * 4];
      float4 v3 = *(float4*)&vS[c + 3][tx * 4];
      acc.x += p4.x * v0.x + p4.y * v1.x + p4.z * v2.x + p4.w * v3.x;
      acc.y += p4.x * v0.y + p4.y * v1.y + p4.z * v2.y + p4.w * v3.y;
      acc.z += p4.x * v0.z + p4.y * v1.z + p4.z * v2.z + p4.w * v3.z;
      acc.w += p4.x * v0.w + p4.y * v1.w + p4.z * v2.w + p4.w * v3.w;
    }
    rmax = nm;
  }
  float inv = 1.0f / rsum;
  float4 outv = {acc.x * inv, acc.y * inv, acc.z * inv, acc.w * inv};
  *(float4*)(bv + ((size_t)bh * 256 + mb * 16 + m) * 64 + tx * 4) = outv;
}

// ---------------------------------------------------------------- scores S = (0.125*q) @ kl^T
// grid (NPAD/64, 4, NBH); S layout [bhl][NPAD][256]
__global__ __launch_bounds__(256) void k_score(
    float* __restrict__ S, const float* __restrict__ qkv,
    const float* __restrict__ kl, int bh0) {
  __shared__ __align__(16) float Aq[64][68];
  __shared__ __align__(16) float Bk[64][68];
  int t = threadIdx.x;
  int ti = blockIdx.x, tj = blockIdx.y;
  int bhl = blockIdx.z;
  int bh = bh0 + bhl;
  int b = bh >> 3, h = bh & 7;
  int r = t >> 2, cc = (t & 3) * 16;
  {
    const float* ap = qkv + ((size_t)b * NPAD + ti * 64 + r) * 1536 + h * 64 + cc;
    const float* bp = kl + ((size_t)bh * 256 + tj * 64 + r) * 64 + cc;
#pragma unroll
    for (int i = 0; i < 16; i += 4) {
      float4 qa = *(const float4*)(ap + i);
      qa.x *= 0.125f; qa.y *= 0.125f; qa.z *= 0.125f; qa.w *= 0.125f;
      *(float4*)&Aq[r][cc + i] = qa;
      *(float4*)&Bk[r][cc + i] = *(const float4*)(bp + i);
    }
  }
  __syncthreads();
  int tx = t & 15, ty = t >> 4;
  float acc[4][4];
#pragma unroll
  for (int i = 0; i < 4; ++i)
#pragma unroll
    for (int j = 0; j < 4; ++j) acc[i][j] = 0.f;
  for (int d = 0; d < 64; d += 4) {
    float4 a4[4], b4[4];
#pragma unroll
    for (int ii = 0; ii < 4; ++ii) a4[ii] = *(float4*)&Aq[ty * 4 + ii][d];
#pragma unroll
    for (int jj = 0; jj < 4; ++jj) b4[jj] = *(float4*)&Bk[tx * 4 + jj][d];
#pragma unroll
    for (int ii = 0; ii < 4; ++ii)
#pragma unroll
      for (int jj = 0; jj < 4; ++jj) acc[ii][jj] += dot4f(a4[ii], b4[jj]);
  }
#pragma unroll
  for (int ii = 0; ii < 4; ++ii) {
    float4 v;
    v.x = acc[ii][0]; v.y = acc[ii][1]; v.z = acc[ii][2]; v.w = acc[ii][3];
    *(float4*)(S + ((size_t)bhl * NPAD + ti * 64 + ty * 4 + ii) * 256 + tj * 64 +
               tx * 4) = v;
  }
}

// --------------------------- out = softmax(S) @ w2 + conv(v), 32 tokens/block
// grid (NPAD/32, NBH)
__global__ __launch_bounds__(256) void k_pv(
    float* __restrict__ attout, const float* __restrict__ S,
    const float* __restrict__ qkv, const float* __restrict__ w2,
    const float* __restrict__ resw, int bh0) {
  __shared__ __align__(16) float pT[256][36];
  __shared__ __align__(16) float cS[64][68];
  __shared__ float w33[33];
  int t = threadIdx.x;
  int tb = blockIdx.x;   // 0..519
  int bhl = blockIdx.y;  // 0..NBH-1
  int bh = bh0 + bhl;
  int b = bh >> 3, h = bh & 7;
  int n0 = tb * 32;
  if (t < 33) w33[t] = resw[h * 33 + t];
  // stage raw scores transposed: pT[lm][token]
  {
    int r = t >> 3;          // token 0..31
    int seg = (t & 7) * 32;  // lm segment
    const float* sp = S + ((size_t)bhl * NPAD + n0 + r) * 256 + seg;
#pragma unroll
    for (int k = 0; k < 32; k += 4) {
      float4 v = *(const float4*)(sp + k);
      pT[seg + k + 0][r] = v.x;
      pT[seg + k + 1][r] = v.y;
      pT[seg + k + 2][r] = v.z;
      pT[seg + k + 3][r] = v.w;
    }
  }
  __syncthreads();
  // softmax per token (a column of pT); 8 lanes per token
  {
    int tt = t >> 3, g = t & 7;
    float v[32];
    float m = -INFINITY;
#pragma unroll
    for (int k = 0; k < 32; ++k) {
      v[k] = pT[g + 8 * k][tt];
      m = fmaxf(m, v[k]);
    }
    for (int o = 4; o; o >>= 1) m = fmaxf(m, __shfl_xor(m, o));
    float s = 0.f;
#pragma unroll
    for (int k = 0; k < 32; ++k) {
      v[k] = expf(v[k] - m);
      s += v[k];
    }
    for (int o = 4; o; o >>= 1) s += __shfl_xor(s, o);
    float inv = 1.f / s;
#pragma unroll
    for (int k = 0; k < 32; ++k) pT[g + 8 * k][tt] = v[k] * inv;
  }
  // PV: thread = (ty: 4 tokens, tx: 2 cols)
  int ty = t >> 5, tx = t & 31;
  float acc[4][2] = {{0.f, 0.f}, {0.f, 0.f}, {0.f, 0.f}, {0.f, 0.f}};
  for (int cb = 0; cb < 4; ++cb) {
    __syncthreads();
    {
      int r = t >> 2, cc = (t & 3) * 16;
      const float* p = w2 + ((size_t)bh * 256 + cb * 64 + r) * 64 + cc;
#pragma unroll
      for (int i = 0; i < 16; i += 4)
        *(float4*)&cS[r][cc + i] = *(const float4*)(p + i);
    }
    __syncthreads();
#pragma unroll 4
    for (int l = 0; l < 64; ++l) {
      float4 p4 = *(float4*)&pT[cb * 64 + l][ty * 4];
      float2 wv = *(float2*)&cS[l][tx * 2];
      acc[0][0] += p4.x * wv.x; acc[0][1] += p4.x * wv.y;
      acc[1][0] += p4.y * wv.x; acc[1][1] += p4.y * wv.y;
      acc[2][0] += p4.z * wv.x; acc[2][1] += p4.z * wv.y;
      acc[3][0] += p4.w * wv.x; acc[3][1] += p4.w * wv.y;
    }
  }
  // conv residual: stage v rows n0-16 .. n0+47
  __syncthreads();
  {
    int r = t >> 2, cc = (t & 3) * 16;
    int seq = n0 - 16 + r;
    if (seq >= 0 && seq < NPAD) {
      const float* p = qkv + ((size_t)b * NPAD + seq) * 1536 + 1024 + h * 64 + cc;
#pragma unroll
      for (int i = 0; i < 16; i += 4)
        *(float4*)&cS[r][cc + i] = *(const float4*)(p + i);
    } else {
      float4 z = {0, 0, 0, 0};
#pragma unroll
      for (int i = 0; i < 16; i += 4) *(float4*)&cS[r][cc + i] = z;
    }
  }
  __syncthreads();
  float cacc[4][2] = {{0.f, 0.f}, {0.f, 0.f}, {0.f, 0.f}, {0.f, 0.f}};
  for (int k = 0; k < 33; ++k) {
    float wv = w33[k];
#pragma unroll
    for (int i = 0; i < 4; ++i) {
      float2 v2 = *(float2*)&cS[4 * ty + i + k][tx * 2];
      cacc[i][0] += wv * v2.x;
      cacc[i][1] += wv * v2.y;
    }
  }
#pragma unroll
  for (int i = 0; i < 4; ++i) {
    float2 o;
    o.x = acc[i][0] + cacc[i][0];
    o.y = acc[i][1] + cacc[i][1];
    *(float2*)(attout + ((size_t)b * NPAD + n0 + 4 * ty + i) * DD + h * 64 + tx * 2) = o;
  }
}

// ---------------------------------------------------------------- PPEG (combined 7x7)
// y = f + conv7(f)+b7 + conv5(f)+b5 + conv3(f)+b3  -> single 7x7 kernel (supports nest)
// grid (128*4, 4, 2): blockIdx.x = i*4 + jb
__global__ __launch_bounds__(128) void k_ppeg(
    float* __restrict__ hB, const float* __restrict__ hA,
    const float* __restrict__ w7, const float* __restrict__ b7,
    const float* __restrict__ w5, const float* __restrict__ b5,
    const float* __restrict__ w3, const float* __restrict__ b3) {
  __shared__ float cw[49][128];
  int t = threadIdx.x;
  int i = blockIdx.x >> 2;
  int j0 = (blockIdx.x & 3) * 32;
  int cg = blockIdx.y, b = blockIdx.z;
  int c = cg * 128 + t;
#pragma unroll
  for (int k = 0; k < 49; ++k) cw[k][t] = w7[c * 49 + k];
#pragma unroll
  for (int di = 0; di < 5; ++di)
#pragma unroll
    for (int dj = 0; dj < 5; ++dj)
      cw[(di + 1) * 7 + dj + 1][t] += w5[c * 25 + di * 5 + dj];
#pragma unroll
  for (int di = 0; di < 3; ++di)
#pragma unroll
    for (int dj = 0; dj < 3; ++dj)
      cw[(di + 2) * 7 + dj + 2][t] += w3[c * 9 + di * 3 + dj];
  cw[24][t] += 1.0f;  // identity tap
  float bias = b7[c] + b5[c] + b3[c];
  const float* base = hA + (size_t)b * TT * DD + DD + c;
  float* obase = hB + (size_t)b * TT * DD + DD + c;
  float acc[32];
#pragma unroll
  for (int j = 0; j < 32; ++j) acc[j] = bias;
  for (int di = 0; di < 7; ++di) {
    int ii = i + di - 3;
    if ((unsigned)ii >= 128u) continue;
    float win[38];
#pragma unroll
    for (int w = 0; w < 38; ++w) {
      int col = j0 - 3 + w;
      win[w] = ((unsigned)col < 128u) ? base[(size_t)(ii * 128 + col) * DD] : 0.f;
    }
#pragma unroll
    for (int dj = 0; dj < 7; ++dj) {
      float wv = cw[di * 7 + dj][t];
#pragma unroll
      for (int j = 0; j < 32; ++j) acc[j] += win[j + dj] * wv;
    }
  }
#pragma unroll
  for (int j = 0; j < 32; ++j) obase[(size_t)(i * 128 + j0 + j) * DD] = acc[j];
}

// ---------------------------------------------------------------- final head
__global__ __launch_bounds__(512) void k_final(
    float* __restrict__ out, const float* __restrict__ h,
    const float* __restrict__ g, const float* __restrict__ be,
    const float* __restrict__ cw, const float* __restrict__ cbias) {
  __shared__ float sm[16];
  int t = threadIdx.x;
  for (int b = 0; b < 2; ++b) {
    const float* row = h + (size_t)b * TT * DD;
    float x = row[t];
    float s = x;
    for (int o = 32; o; o >>= 1) s += __shfl_xor(s, o);
    if ((t & 63) == 0) sm[t >> 6] = s;
    __syncthreads();
    float mu = 0.f;
    for (int i = 0; i < 8; ++i) mu += sm[i];
    mu *= (1.f / 512.f);
    __syncthreads();
    float d = x - mu;
    s = d * d;
    for (int o = 32; o; o >>= 1) s += __shfl_xor(s, o);
    if ((t & 63) == 0) sm[t >> 6] = s;
    __syncthreads();
    float var = 0.f;
    for (int i = 0; i < 8; ++i) var += sm[i];
    var *= (1.f / 512.f);
    float rs = rsqrtf(var + 1e-5f);
    __syncthreads();
    float f = d * rs * g[t] + be[t];
    float p0 = f * cw[2 * t], p1 = f * cw[2 * t + 1];
    for (int o = 32; o; o >>= 1) {
      p0 += __shfl_xor(p0, o);
      p1 += __shfl_xor(p1, o);
    }
    if ((t & 63) == 0) {
      sm[t >> 6] = p0;
      sm[8 + (t >> 6)] = p1;
    }
    __syncthreads();
    if (t == 0) {
      float q0 = 0.f, q1 = 0.f;
      for (int i = 0; i < 8; ++i) {
        q0 += sm[i];
        q1 += sm[8 + i];
      }
      out[b * 2 + 0] = q0 + cbias[0];
      out[b * 2 + 1] = q1 + cbias[1];
    }
    __syncthreads();
  }
}

// ---------------------------------------------------------------- host side
static void run_attn(float* h, const float* lng, const float* lnb,
                     const float* wqkv, const float* wout, const float* bout,
                     const float* resw, float* xp, float* qkv, float* ql, float* kl,
                     float* a2, float* z0, float* z1, float* xz, float* yA, float* yB,
                     float* yC, float* bv, float* w2, float* red, float* Sbuf,
                     hipStream_t stream) {
  k_zero_pad<<<BB * PADF, 256, 0, stream>>>(xp);
  k_ln_pad<<<(BB * TT + 3) / 4, 256, 0, stream>>>(xp, h, lng, lnb);
  k_gemm<1><<<dim3(BB * NPAD / 128, 1536 / 128), 256, 0, stream>>>(
      xp, wqkv, nullptr, qkv, BB * NPAD, DD, 1536, DD);
  k_landmarks<<<1024, 256, 0, stream>>>(ql, kl, qkv);
  k_a3v<<<dim3(16, 16), 256, 0, stream>>>(bv, ql, qkv);
  k_sim2<<<dim3(4, 4, 16), 256, 0, stream>>>(a2, ql, kl);
  k_softmax256<<<1024, 256, 0, stream>>>(a2);
  k_pinv_sums<<<16, 256, 0, stream>>>(red, a2);
  k_pinv_scale<<<1, 256, 0, stream>>>(red);
  k_zinit<<<dim3(256, 16), 256, 0, stream>>>(z0, a2, red);
  float* zc = z0;
  float* zn = z1;
  for (int it = 0; it < 6; ++it) {
    k_bmm<<<dim3(4, 4, 16), 256, 0, stream>>>(a2, zc, xz, 1.f, 0.f, yA, -1.f, 7.f, 256);
    k_bmm<<<dim3(4, 4, 16), 256, 0, stream>>>(xz, yA, yB, -1.f, 15.f, nullptr, 0.f, 0.f, 256);
    k_bmm<<<dim3(4, 4, 16), 256, 0, stream>>>(xz, yB, yC, -1.f, 13.f, nullptr, 0.f, 0.f, 256);
    k_bmm<<<dim3(4, 4, 16), 256, 0, stream>>>(zc, yC, zn, 0.25f, 0.f, nullptr, 0.f, 0.f, 256);
    float* tmp = zc; zc = zn; zn = tmp;
  }
  k_bmm<<<dim3(1, 4, 16), 256, 0, stream>>>(zc, bv, w2, 1.f, 0.f, nullptr, 0.f, 0.f, 64);
  for (int bh0 = 0; bh0 < 16; bh0 += NBH) {
    k_score<<<dim3(NPAD / 64, 4, NBH), 256, 0, stream>>>(Sbuf, qkv, kl, bh0);
    k_pv<<<dim3(NPAD / 32, NBH), 256, 0, stream>>>(xp, Sbuf, qkv, w2, resw, bh0);
  }
  k_gemm<2><<<dim3((TT + 127) / 128, 4, BB), 256, 0, stream>>>(xp, wout, bout, h, TT, DD,
                                                               DD, DD);
}

extern "C" void kernel_launch(void* const* d_in, const int* in_sizes, int n_in,
                              void* d_out, int out_size, void* d_ws, size_t ws_size,
                              hipStream_t stream) {
  const float* x        = (const float*)d_in[0];
  const float* w_feat   = (const float*)d_in[1];
  const float* b_feat   = (const float*)d_in[2];
  const float* cls_tok  = (const float*)d_in[3];
  const float* ln1_g    = (const float*)d_in[4];
  const float* ln1_b    = (const float*)d_in[5];
  const float* qkv1     = (const float*)d_in[6];
  const float* out1_w   = (const float*)d_in[7];
  const float* out1_b   = (const float*)d_in[8];
  const float* res1_w   = (const float*)d_in[9];
  const float* ppeg_w7  = (const float*)d_in[10];
  const float* ppeg_b7  = (const float*)d_in[11];
  const float* ppeg_w5  = (const float*)d_in[12];
  const float* ppeg_b5  = (const float*)d_in[13];
  const float* ppeg_w3  = (const float*)d_in[14];
  const float* ppeg_b3  = (const float*)d_in[15];
  const float* ln2_g    = (const float*)d_in[16];
  const float* ln2_b    = (const float*)d_in[17];
  const float* qkv2     = (const float*)d_in[18];
  const float* out2_w   = (const float*)d_in[19];
  const float* out2_b   = (const float*)d_in[20];
  const float* res2_w   = (const float*)d_in[21];
  const float* lnf_g    = (const float*)d_in[22];
  const float* lnf_b    = (const float*)d_in[23];
  const float* cls_w    = (const float*)d_in[24];
  const float* cls_b    = (const float*)d_in[25];

  float* ws = (float*)d_ws;
  size_t off = 0;
  float* hA  = ws + off; off += (size_t)BB * TT * DD;        // 16,778,240
  float* hB  = ws + off; off += (size_t)BB * TT * DD;
  float* xp  = ws + off; off += (size_t)BB * NPAD * DD;      // also attout
  float* qkv = ws + off; off += (size_t)BB * NPAD * 3 * DD;
  float* ql  = ws + off; off += (size_t)BB * HH * 256 * 64;
  float* kl  = ws + off; off += (size_t)BB * HH * 256 * 64;
  float* a2  = ws + off; off += (size_t)16 * 65536;
  float* z0  = ws + off; off += (size_t)16 * 65536;
  float* z1  = ws + off; off += (size_t)16 * 65536;
  float* xz  = ws + off; off += (size_t)16 * 65536;
  float* yA  = ws + off; off += (size_t)16 * 65536;
  float* yB  = ws + off; off += (size_t)16 * 65536;
  float* yC  = ws + off; off += (size_t)16 * 65536;
  float* bv  = ws + off; off += (size_t)BB * HH * 256 * 64;
  float* w2  = ws + off; off += (size_t)BB * HH * 256 * 64;
  float* red = ws + off; off += 8448;

  // Stage 1: h = gelu(x @ w_feat + b_feat), prepend cls token
  k_set_cls<<<2, 512, 0, stream>>>(hA, cls_tok);
  k_gemm<0><<<dim3(32768 / 128, 512 / 128), 256, 0, stream>>>(x, w_feat, b_feat, hA,
                                                              32768, 1024, 512, 1024);
  // Attention 1 (residual in-place on hA; hB is dead -> use as score scratch)
  run_attn(hA, ln1_g, ln1_b, qkv1, out1_w, out1_b, res1_w, xp, qkv, ql, kl, a2, z0, z1,
           xz, yA, yB, yC, bv, w2, red, hB, stream);
  // PPEG: hB = ppeg(hA)
  k_copy_cls<<<2, 512, 0, stream>>>(hB, hA);
  k_ppeg<<<dim3(512, 4, 2), 128, 0, stream>>>(hB, hA, ppeg_w7, ppeg_b7, ppeg_w5, ppeg_b5,
                                              ppeg_w3, ppeg_b3);
  // Attention 2 (residual in-place on hB; hA is dead -> use as score scratch)
  run_attn(hB, ln2_g, ln2_b, qkv2, out2_w, out2_b, res2_w, xp, qkv, ql, kl, a2, z0, z1,
           xz, yA, yB, yC, bv, w2, red, hA, stream);
  // Final: LN(cls) @ cls_w + cls_b
  k_final<<<1, 512, 0, stream>>>((float*)d_out, hB, lnf_g, lnf_b, cls_w, cls_b);
}

// Round 3
// 6110.815 us; speedup vs baseline: 1.7611x; 1.1715x over previous
//
#include <hip/hip_runtime.h>
#include <cstdint>
#include <cstddef>

#define BB 2
#define TT 16385
#define NPAD 16640
#define DD 512
#define HH 8
#define DHH 64
#define MLAND 256
#define PADF 255
#define NBH 2
#define A3KC 5
#define A3CH 3328

__device__ __forceinline__ float dot4f(const float4 a, const float4 b) {
  return a.x * b.x + a.y * b.y + a.z * b.z + a.w * b.w;
}

__device__ __forceinline__ float gelu_f(float v) {
  float c = 0.7978845608028654f * (v + 0.044715f * v * v * v);
  return 0.5f * v * (1.0f + tanhf(c));
}

// ---------------------------------------------------------------- cls rows
__global__ void k_set_cls(float* __restrict__ h, const float* __restrict__ cls) {
  h[(size_t)blockIdx.x * TT * DD + threadIdx.x] = cls[threadIdx.x];
}
__global__ void k_copy_cls(float* __restrict__ dst, const float* __restrict__ src) {
  size_t o = (size_t)blockIdx.x * TT * DD + threadIdx.x;
  dst[o] = src[o];
}

// ---------------------------------------------------------------- big GEMM
// MODE 0: feat: C[g + g/16384 + 1] = gelu(A@W + bias)   (A=x, lda=1024, N=512)
// MODE 1: plain: C = A@W                                 (qkv, N=1536)
// MODE 2: proj: h[b][i] += A[b*NPAD + 255 + i]@W + bias  (grid.z = batch)
template <int MODE>
__global__ __launch_bounds__(256) void k_gemm(
    const float* __restrict__ A, const float* __restrict__ W,
    const float* __restrict__ bias, float* __restrict__ C,
    int M, int K, int N, int lda) {
  __shared__ __align__(16) float As[16][128];
  __shared__ __align__(16) float Ws[16][128];
  const int t = threadIdx.x;
  const int tx = t & 15, ty = t >> 4;
  const int rb = blockIdx.x * 128, cbc = blockIdx.y * 128;
  const float* Ab = A;
  float* Cb = C;
  if (MODE == 2) {
    int b = blockIdx.z;
    Ab = A + (size_t)b * NPAD * DD + (size_t)PADF * DD;
    Cb = C + (size_t)b * TT * DD;
  }
  float acc[8][8];
#pragma unroll
  for (int i = 0; i < 8; ++i)
#pragma unroll
    for (int j = 0; j < 8; ++j) acc[i][j] = 0.f;

  const int am = t >> 1, ak = (t & 1) * 8;
  const int wk = t >> 4, wn = (t & 15) * 8;
  for (int k0 = 0; k0 < K; k0 += 16) {
    __syncthreads();
    {
      int row = rb + am;
      float4 v0 = {0, 0, 0, 0}, v1 = {0, 0, 0, 0};
      if (row < M) {
        const float* p = Ab + (size_t)row * lda + k0 + ak;
        v0 = *(const float4*)p;
        v1 = *(const float4*)(p + 4);
      }
      As[ak + 0][am] = v0.x; As[ak + 1][am] = v0.y;
      As[ak + 2][am] = v0.z; As[ak + 3][am] = v0.w;
      As[ak + 4][am] = v1.x; As[ak + 5][am] = v1.y;
      As[ak + 6][am] = v1.z; As[ak + 7][am] = v1.w;
    }
    {
      const float* p = W + (size_t)(k0 + wk) * N + cbc + wn;
      *(float4*)&Ws[wk][wn] = *(const float4*)p;
      *(float4*)&Ws[wk][wn + 4] = *(const float4*)(p + 4);
    }
    __syncthreads();
#pragma unroll
    for (int kk = 0; kk < 16; ++kk) {
      float4 a0 = *(float4*)&As[kk][ty * 4];
      float4 a1 = *(float4*)&As[kk][64 + ty * 4];
      float4 w0 = *(float4*)&Ws[kk][tx * 4];
      float4 w1 = *(float4*)&Ws[kk][64 + tx * 4];
      float av[8] = {a0.x, a0.y, a0.z, a0.w, a1.x, a1.y, a1.z, a1.w};
      float wv[8] = {w0.x, w0.y, w0.z, w0.w, w1.x, w1.y, w1.z, w1.w};
#pragma unroll
      for (int i = 0; i < 8; ++i)
#pragma unroll
        for (int j = 0; j < 8; ++j) acc[i][j] += av[i] * wv[j];
    }
  }
#pragma unroll
  for (int ri = 0; ri < 2; ++ri)
#pragma unroll
    for (int ii = 0; ii < 4; ++ii) {
      int r = rb + ri * 64 + ty * 4 + ii;
      if (r >= M) continue;
      size_t orow;
      if (MODE == 0) {
        int bb = r >> 14;
        orow = (size_t)(r + bb + 1);
      } else {
        orow = (size_t)r;
      }
#pragma unroll
      for (int ci = 0; ci < 2; ++ci) {
        int c = cbc + ci * 64 + tx * 4;
        float4 v;
        v.x = acc[ri * 4 + ii][ci * 4 + 0];
        v.y = acc[ri * 4 + ii][ci * 4 + 1];
        v.z = acc[ri * 4 + ii][ci * 4 + 2];
        v.w = acc[ri * 4 + ii][ci * 4 + 3];
        if (MODE == 0) {
          float4 bi = *(const float4*)(bias + c);
          v.x = gelu_f(v.x + bi.x); v.y = gelu_f(v.y + bi.y);
          v.z = gelu_f(v.z + bi.z); v.w = gelu_f(v.w + bi.w);
          *(float4*)(Cb + orow * DD + c) = v;
        } else if (MODE == 1) {
          *(float4*)(Cb + orow * (size_t)N + c) = v;
        } else {
          float4 bi = *(const float4*)(bias + c);
          float4 old = *(float4*)(Cb + orow * DD + c);
          v.x += bi.x + old.x; v.y += bi.y + old.y;
          v.z += bi.z + old.z; v.w += bi.w + old.w;
          *(float4*)(Cb + orow * DD + c) = v;
        }
      }
    }
}

// ---------------------------------------------------------------- LN + pad
__global__ __launch_bounds__(256) void k_ln_pad(
    float* __restrict__ xp, const float* __restrict__ h,
    const float* __restrict__ gam, const float* __restrict__ bet) {
  int w = threadIdx.x >> 6, lane = threadIdx.x & 63;
  int row = blockIdx.x * 4 + w;
  if (row >= BB * TT) return;
  int b = row / TT, i = row - b * TT;
  const float* src = h + (size_t)row * DD;
  float4 x0 = *(const float4*)(src + lane * 4);
  float4 x1 = *(const float4*)(src + 256 + lane * 4);
  float s = x0.x + x0.y + x0.z + x0.w + x1.x + x1.y + x1.z + x1.w;
  for (int o = 32; o; o >>= 1) s += __shfl_xor(s, o);
  float mu = s * (1.f / 512.f);
  float q = (x0.x - mu) * (x0.x - mu) + (x0.y - mu) * (x0.y - mu) +
            (x0.z - mu) * (x0.z - mu) + (x0.w - mu) * (x0.w - mu) +
            (x1.x - mu) * (x1.x - mu) + (x1.y - mu) * (x1.y - mu) +
            (x1.z - mu) * (x1.z - mu) + (x1.w - mu) * (x1.w - mu);
  for (int o = 32; o; o >>= 1) q += __shfl_xor(q, o);
  float rs = rsqrtf(q * (1.f / 512.f) + 1e-5f);
  float4 g0 = *(const float4*)(gam + lane * 4);
  float4 g1 = *(const float4*)(gam + 256 + lane * 4);
  float4 b0 = *(const float4*)(bet + lane * 4);
  float4 b1 = *(const float4*)(bet + 256 + lane * 4);
  float* dst = xp + ((size_t)b * NPAD + PADF + i) * DD;
  float4 o0, o1;
  o0.x = (x0.x - mu) * rs * g0.x + b0.x;
  o0.y = (x0.y - mu) * rs * g0.y + b0.y;
  o0.z = (x0.z - mu) * rs * g0.z + b0.z;
  o0.w = (x0.w - mu) * rs * g0.w + b0.w;
  o1.x = (x1.x - mu) * rs * g1.x + b1.x;
  o1.y = (x1.y - mu) * rs * g1.y + b1.y;
  o1.z = (x1.z - mu) * rs * g1.z + b1.z;
  o1.w = (x1.w - mu) * rs * g1.w + b1.w;
  *(float4*)(dst + lane * 4) = o0;
  *(float4*)(dst + 256 + lane * 4) = o1;
}

__global__ void k_zero_pad(float* __restrict__ xp) {
  int r = blockIdx.x;  // 0..509
  int b = r / PADF, j = r - b * PADF;
  float* p = xp + ((size_t)b * NPAD + j) * DD;
  p[threadIdx.x * 2] = 0.f;
  p[threadIdx.x * 2 + 1] = 0.f;
}

// ---------------------------------------------------------------- landmarks
__global__ __launch_bounds__(256) void k_landmarks(
    float* __restrict__ ql, float* __restrict__ kl, const float* __restrict__ qkv) {
  int t = threadIdx.x;
  int mi = t >> 6, d = t & 63;
  int blk = blockIdx.x;  // bh*64 + mg
  int bh = blk >> 6, mg = blk & 63;
  int b = bh >> 3, h = bh & 7;
  int m = mg * 4 + mi;
  const float* base = qkv + (size_t)b * NPAD * 1536 + h * 64 + d;
  float sq = 0.f, sk = 0.f;
  int t0 = m * 65;
  for (int j = 0; j < 65; ++j) {
    const float* p = base + (size_t)(t0 + j) * 1536;
    sq += p[0];
    sk += p[512];
  }
  ql[((size_t)bh * 256 + m) * 64 + d] = sq * (0.125f / 65.f);
  kl[((size_t)bh * 256 + m) * 64 + d] = sk * (1.f / 65.f);
}

// ---------------------------------------------------------------- sim2 = ql @ kl^T
__global__ __launch_bounds__(256) void k_sim2(
    float* __restrict__ sim, const float* __restrict__ ql, const float* __restrict__ kl) {
  __shared__ __align__(16) float Aq[64][68];
  __shared__ __align__(16) float Bk[64][68];
  int t = threadIdx.x;
  int tj = blockIdx.x, ti = blockIdx.y, bh = blockIdx.z;
  int r = t >> 2, cc = (t & 3) * 16;
  const float* ap = ql + ((size_t)bh * 256 + ti * 64 + r) * 64 + cc;
  const float* bp = kl + ((size_t)bh * 256 + tj * 64 + r) * 64 + cc;
#pragma unroll
  for (int i = 0; i < 16; i += 4) {
    *(float4*)&Aq[r][cc + i] = *(const float4*)(ap + i);
    *(float4*)&Bk[r][cc + i] = *(const float4*)(bp + i);
  }
  __syncthreads();
  int tx = t & 15, ty = t >> 4;
  float acc[4][4];
#pragma unroll
  for (int i = 0; i < 4; ++i)
#pragma unroll
    for (int j = 0; j < 4; ++j) acc[i][j] = 0.f;
  for (int d = 0; d < 64; d += 4) {
    float4 a4[4], b4[4];
#pragma unroll
    for (int ii = 0; ii < 4; ++ii) a4[ii] = *(float4*)&Aq[ty * 4 + ii][d];
#pragma unroll
    for (int jj = 0; jj < 4; ++jj) b4[jj] = *(float4*)&Bk[tx * 4 + jj][d];
#pragma unroll
    for (int ii = 0; ii < 4; ++ii)
#pragma unroll
      for (int jj = 0; jj < 4; ++jj) acc[ii][jj] += dot4f(a4[ii], b4[jj]);
  }
#pragma unroll
  for (int ii = 0; ii < 4; ++ii)
#pragma unroll
    for (int jj = 0; jj < 4; ++jj)
      sim[((size_t)bh * 256 + ti * 64 + ty * 4 + ii) * 256 + tj * 64 + tx * 4 + jj] =
          acc[ii][jj];
}

// ---------------------------------------------------------------- row softmax (len 256)
__global__ __launch_bounds__(256) void k_softmax256(float* __restrict__ a) {
  int w = threadIdx.x >> 6, lane = threadIdx.x & 63;
  size_t row = (size_t)blockIdx.x * 4 + w;
  float* p = a + row * 256 + lane * 4;
  float4 v = *(float4*)p;
  float m = fmaxf(fmaxf(v.x, v.y), fmaxf(v.z, v.w));
  for (int o = 32; o; o >>= 1) m = fmaxf(m, __shfl_xor(m, o));
  v.x = expf(v.x - m); v.y = expf(v.y - m);
  v.z = expf(v.z - m); v.w = expf(v.w - m);
  float s = v.x + v.y + v.z + v.w;
  for (int o = 32; o; o >>= 1) s += __shfl_xor(s, o);
  float inv = 1.f / s;
  v.x *= inv; v.y *= inv; v.z *= inv; v.w *= inv;
  *(float4*)p = v;
}

// ---------------------------------------------------------------- pinv helpers
__global__ void k_pinv_sums(float* __restrict__ red, const float* __restrict__ a2) {
  int bh = blockIdx.x, t = threadIdx.x;
  const float* Ab = a2 + (size_t)bh * 65536;
  float s = 0.f;
  for (int i = 0; i < 256; ++i) s += fabsf(Ab[(size_t)i * 256 + t]);
  red[bh * 256 + t] = s;  // sum over -2 ("row")
  float c = 0.f;
  const float* rp = Ab + (size_t)t * 256;
  for (int j = 0; j < 256; j += 4) {
    float4 v = *(const float4*)(rp + j);
    c += fabsf(v.x) + fabsf(v.y) + fabsf(v.z) + fabsf(v.w);
  }
  red[4096 + bh * 256 + t] = c;  // sum over -1 ("col")
}

__global__ void k_pinv_scale(float* __restrict__ red) {
  __shared__ float sm[8];
  int t = threadIdx.x;
  float m1 = 0.f, m2 = 0.f;
  for (int k = t; k < 4096; k += 256) {
    m1 = fmaxf(m1, red[k]);
    m2 = fmaxf(m2, red[4096 + k]);
  }
  for (int o = 32; o; o >>= 1) {
    m1 = fmaxf(m1, __shfl_xor(m1, o));
    m2 = fmaxf(m2, __shfl_xor(m2, o));
  }
  int w = t >> 6;
  if ((t & 63) == 0) { sm[w] = m1; sm[4 + w] = m2; }
  __syncthreads();
  if (t == 0) {
    float a = fmaxf(fmaxf(sm[0], sm[1]), fmaxf(sm[2], sm[3]));
    float b = fmaxf(fmaxf(sm[4], sm[5]), fmaxf(sm[6], sm[7]));
    red[8192] = 1.0f / (a * b);
  }
}

__global__ void k_zinit(float* __restrict__ z, const float* __restrict__ a2,
                        const float* __restrict__ red) {
  float s = red[8192];
  int i = blockIdx.x, bh = blockIdx.y, j = threadIdx.x;
  z[((size_t)bh * 256 + i) * 256 + j] = a2[((size_t)bh * 256 + j) * 256 + i] * s;
}

// batched (16) 256x256 @ 256xN; C1 = a1*(A@B) + d1*I ; optional C2 = a2c*(A@B) + d2*I
__global__ __launch_bounds__(256) void k_bmm(
    const float* __restrict__ A, const float* __restrict__ Bm,
    float* __restrict__ C1, float a1, float d1,
    float* __restrict__ C2, float a2c, float d2, int N) {
  __shared__ __align__(16) float As[16][64];
  __shared__ __align__(16) float Bs[16][64];
  int t = threadIdx.x;
  int bh = blockIdx.z;
  int i0 = blockIdx.y * 64, j0 = blockIdx.x * 64;
  const float* Ab = A + (size_t)bh * 65536;
  const float* Bb = Bm + (size_t)bh * 256 * N;
  float acc[4][4];
#pragma unroll
  for (int i = 0; i < 4; ++i)
#pragma unroll
    for (int j = 0; j < 4; ++j) acc[i][j] = 0.f;
  int tx = t & 15, ty = t >> 4;
  for (int k0 = 0; k0 < 256; k0 += 16) {
    __syncthreads();
    {
      int r = t >> 2, kl2 = (t & 3) * 4;
      float4 v = *(const float4*)(Ab + (size_t)(i0 + r) * 256 + k0 + kl2);
      As[kl2 + 0][r] = v.x; As[kl2 + 1][r] = v.y;
      As[kl2 + 2][r] = v.z; As[kl2 + 3][r] = v.w;
    }
    {
      int kr = t >> 4, nl = (t & 15) * 4;
      *(float4*)&Bs[kr][nl] = *(const float4*)(Bb + (size_t)(k0 + kr) * N + j0 + nl);
    }
    __syncthreads();
#pragma unroll
    for (int kk = 0; kk < 16; ++kk) {
      float4 a4 = *(float4*)&As[kk][ty * 4];
      float4 b4 = *(float4*)&Bs[kk][tx * 4];
      float av[4] = {a4.x, a4.y, a4.z, a4.w};
      float bv2[4] = {b4.x, b4.y, b4.z, b4.w};
#pragma unroll
      for (int i = 0; i < 4; ++i)
#pragma unroll
        for (int j = 0; j < 4; ++j) acc[i][j] += av[i] * bv2[j];
    }
  }
#pragma unroll
  for (int ii = 0; ii < 4; ++ii)
#pragma unroll
    for (int jj = 0; jj < 4; ++jj) {
      int i = i0 + ty * 4 + ii, j = j0 + tx * 4 + jj;
      float v = acc[ii][jj];
      size_t off = (size_t)bh * 256 * N + (size_t)i * N + j;
      C1[off] = a1 * v + ((i == j) ? d1 : 0.f);
      if (C2) C2[off] = a2c * v + ((i == j) ? d2 : 0.f);
    }
}

// -------------------------- a3 @ v (split-K flash partials over key chunks)
// grid (16 mb, 16 bh, A3KC kc); partial out: pacc[kc][bh][m][64], pml[kc][bh][m][2]
__global__ __launch_bounds__(256) void k_a3v(
    float* __restrict__ pacc, float* __restrict__ pml,
    const float* __restrict__ ql, const float* __restrict__ qkv) {
  __shared__ __align__(16) float qlS[16][68];
  __shared__ __align__(16) float kS[64][68];
  __shared__ __align__(16) float vS[64][68];
  __shared__ __align__(16) float pS[16][68];
  int t = threadIdx.x;
  int mb = blockIdx.x;  // 0..15
  int bh = blockIdx.y;  // 0..15
  int kc = blockIdx.z;  // 0..A3KC-1
  int b = bh >> 3, h = bh & 7;
  {
    int mi = t >> 4, d = (t & 15) * 4;
    *(float4*)&qlS[mi][d] =
        *(const float4*)(ql + ((size_t)bh * 256 + mb * 16 + mi) * 64 + d);
  }
  int m = t >> 4, tx = t & 15;
  float rmax = -INFINITY, rsum = 0.f;
  float4 acc = {0, 0, 0, 0};
  int ldr = t >> 2;
  int ldcc = (t & 3) * 16;
  const float* kbase = qkv + (size_t)b * NPAD * 1536 + 512 + h * 64 + ldcc;
  int nt0 = kc * A3CH;
  for (int it = 0; it < A3CH / 64; ++it) {
    int nt = nt0 + it * 64;
    __syncthreads();
    {
      const float* kp = kbase + (size_t)(nt + ldr) * 1536;
#pragma unroll
      for (int i = 0; i < 16; i += 4) {
        *(float4*)&kS[ldr][ldcc + i] = *(const float4*)(kp + i);
        *(float4*)&vS[ldr][ldcc + i] = *(const float4*)(kp + 512 + i);
      }
    }
    __syncthreads();
    float s[4] = {0.f, 0.f, 0.f, 0.f};
    for (int d = 0; d < 64; d += 4) {
      float4 q4 = *(float4*)&qlS[m][d];
#pragma unroll
      for (int j = 0; j < 4; ++j) s[j] += dot4f(q4, *(float4*)&kS[tx + 16 * j][d]);
    }
    float lmax = fmaxf(fmaxf(s[0], s[1]), fmaxf(s[2], s[3]));
    for (int o = 8; o; o >>= 1) lmax = fmaxf(lmax, __shfl_xor(lmax, o));
    float nm = fmaxf(rmax, lmax);
    float corr = expf(rmax - nm);
    float p[4], ls = 0.f;
#pragma unroll
    for (int j = 0; j < 4; ++j) {
      p[j] = expf(s[j] - nm);
      ls += p[j];
    }
    for (int o = 8; o; o >>= 1) ls += __shfl_xor(ls, o);
    rsum = rsum * corr + ls;
    acc.x *= corr; acc.y *= corr; acc.z *= corr; acc.w *= corr;
#pragma unroll
    for (int j = 0; j < 4; ++j) pS[m][tx + 16 * j] = p[j];
    __syncthreads();
    for (int c = 0; c < 64; c += 4) {
      float4 p4 = *(float4*)&pS[m][c];
      float4 v0 = *(float4*)&vS[c + 0][tx * 4];
      float4 v1 = *(float4*)&vS[c + 1][tx * 4];
      float4 v2 = *(float4*)&vS[c + 2][tx * 4];
      float4 v3 = *(float4*)&vS[c + 3][tx * 4];
      acc.x += p4.x * v0.x + p4.y * v1.x + p4.z * v2.x + p4.w * v3.x;
      acc.y += p4.x * v0.y + p4.y * v1.y + p4.z * v2.y + p4.w * v3.y;
      acc.z += p4.x * v0.z + p4.y * v1.z + p4.z * v2.z + p4.w * v3.z;
      acc.w += p4.x * v0.w + p4.y * v1.w + p4.z * v2.w + p4.w * v3.w;
    }
    rmax = nm;
  }
  size_t prow = ((size_t)kc * 16 + bh) * 256 + mb * 16 + m;
  *(float4*)(pacc + prow * 64 + tx * 4) = acc;
  if (tx == 0) {
    pml[prow * 2] = rmax;
    pml[prow * 2 + 1] = rsum;
  }
}

// combine A3KC partials -> bv[bh*256+m][64]; grid 4096, block 64
__global__ __launch_bounds__(64) void k_a3v_red(
    float* __restrict__ bv, const float* __restrict__ pacc,
    const float* __restrict__ pml) {
  int row = blockIdx.x;  // bh*256 + m
  int d = threadIdx.x;   // 0..63
  float M = -INFINITY;
#pragma unroll
  for (int c = 0; c < A3KC; ++c)
    M = fmaxf(M, pml[((size_t)c * 4096 + row) * 2]);
  float L = 0.f, A = 0.f;
#pragma unroll
  for (int c = 0; c < A3KC; ++c) {
    size_t pr = (size_t)c * 4096 + row;
    float w = expf(pml[pr * 2] - M);
    L += pml[pr * 2 + 1] * w;
    A += pacc[pr * 64 + d] * w;
  }
  bv[(size_t)row * 64 + d] = A / L;
}

// ---------------------------------------------------------------- scores S = (0.125*q) @ kl^T
// grid (NPAD/64, 4, NBH); S layout [bhl][NPAD][256]
__global__ __launch_bounds__(256) void k_score(
    float* __restrict__ S, const float* __restrict__ qkv,
    const float* __restrict__ kl, int bh0) {
  __shared__ __align__(16) float Aq[64][68];
  __shared__ __align__(16) float Bk[64][68];
  int t = threadIdx.x;
  int ti = blockIdx.x, tj = blockIdx.y;
  int bhl = blockIdx.z;
  int bh = bh0 + bhl;
  int b = bh >> 3, h = bh & 7;
  int r = t >> 2, cc = (t & 3) * 16;
  {
    const float* ap = qkv + ((size_t)b * NPAD + ti * 64 + r) * 1536 + h * 64 + cc;
    const float* bp = kl + ((size_t)bh * 256 + tj * 64 + r) * 64 + cc;
#pragma unroll
    for (int i = 0; i < 16; i += 4) {
      float4 qa = *(const float4*)(ap + i);
      qa.x *= 0.125f; qa.y *= 0.125f; qa.z *= 0.125f; qa.w *= 0.125f;
      *(float4*)&Aq[r][cc + i] = qa;
      *(float4*)&Bk[r][cc + i] = *(const float4*)(bp + i);
    }
  }
  __syncthreads();
  int tx = t & 15, ty = t >> 4;
  float acc[4][4];
#pragma unroll
  for (int i = 0; i < 4; ++i)
#pragma unroll
    for (int j = 0; j < 4; ++j) acc[i][j] = 0.f;
  for (int d = 0; d < 64; d += 4) {
    float4 a4[4], b4[4];
#pragma unroll
    for (int ii = 0; ii < 4; ++ii) a4[ii] = *(float4*)&Aq[ty * 4 + ii][d];
#pragma unroll
    for (int jj = 0; jj < 4; ++jj) b4[jj] = *(float4*)&Bk[tx * 4 + jj][d];
#pragma unroll
    for (int ii = 0; ii < 4; ++ii)
#pragma unroll
      for (int jj = 0; jj < 4; ++jj) acc[ii][jj] += dot4f(a4[ii], b4[jj]);
  }
#pragma unroll
  for (int ii = 0; ii < 4; ++ii) {
    float4 v;
    v.x = acc[ii][0]; v.y = acc[ii][1]; v.z = acc[ii][2]; v.w = acc[ii][3];
    *(float4*)(S + ((size_t)bhl * NPAD + ti * 64 + ty * 4 + ii) * 256 + tj * 64 +
               tx * 4) = v;
  }
}

// --------------------------- out = softmax(S) @ w2 + conv(v), 32 tokens/block
// grid (NPAD/32, NBH)
__global__ __launch_bounds__(256) void k_pv(
    float* __restrict__ attout, const float* __restrict__ S,
    const float* __restrict__ qkv, const float* __restrict__ w2,
    const float* __restrict__ resw, int bh0) {
  __shared__ __align__(16) float pT[256][36];
  __shared__ __align__(16) float cS[64][68];
  __shared__ float w33[33];
  int t = threadIdx.x;
  int tb = blockIdx.x;   // 0..519
  int bhl = blockIdx.y;  // 0..NBH-1
  int bh = bh0 + bhl;
  int b = bh >> 3, h = bh & 7;
  int n0 = tb * 32;
  if (t < 33) w33[t] = resw[h * 33 + t];
  // stage raw scores transposed: pT[lm][token]
  {
    int r = t >> 3;          // token 0..31
    int seg = (t & 7) * 32;  // lm segment
    const float* sp = S + ((size_t)bhl * NPAD + n0 + r) * 256 + seg;
#pragma unroll
    for (int k = 0; k < 32; k += 4) {
      float4 v = *(const float4*)(sp + k);
      pT[seg + k + 0][r] = v.x;
      pT[seg + k + 1][r] = v.y;
      pT[seg + k + 2][r] = v.z;
      pT[seg + k + 3][r] = v.w;
    }
  }
  __syncthreads();
  // softmax per token (a column of pT); 8 lanes per token
  {
    int tt = t >> 3, g = t & 7;
    float v[32];
    float m = -INFINITY;
#pragma unroll
    for (int k = 0; k < 32; ++k) {
      v[k] = pT[g + 8 * k][tt];
      m = fmaxf(m, v[k]);
    }
    for (int o = 4; o; o >>= 1) m = fmaxf(m, __shfl_xor(m, o));
    float s = 0.f;
#pragma unroll
    for (int k = 0; k < 32; ++k) {
      v[k] = expf(v[k] - m);
      s += v[k];
    }
    for (int o = 4; o; o >>= 1) s += __shfl_xor(s, o);
    float inv = 1.f / s;
#pragma unroll
    for (int k = 0; k < 32; ++k) pT[g + 8 * k][tt] = v[k] * inv;
  }
  // PV: thread = (ty: 4 tokens, tx: 2 cols)
  int ty = t >> 5, tx = t & 31;
  float acc[4][2] = {{0.f, 0.f}, {0.f, 0.f}, {0.f, 0.f}, {0.f, 0.f}};
  for (int cb = 0; cb < 4; ++cb) {
    __syncthreads();
    {
      int r = t >> 2, cc = (t & 3) * 16;
      const float* p = w2 + ((size_t)bh * 256 + cb * 64 + r) * 64 + cc;
#pragma unroll
      for (int i = 0; i < 16; i += 4)
        *(float4*)&cS[r][cc + i] = *(const float4*)(p + i);
    }
    __syncthreads();
#pragma unroll 4
    for (int l = 0; l < 64; ++l) {
      float4 p4 = *(float4*)&pT[cb * 64 + l][ty * 4];
      float2 wv = *(float2*)&cS[l][tx * 2];
      acc[0][0] += p4.x * wv.x; acc[0][1] += p4.x * wv.y;
      acc[1][0] += p4.y * wv.x; acc[1][1] += p4.y * wv.y;
      acc[2][0] += p4.z * wv.x; acc[2][1] += p4.z * wv.y;
      acc[3][0] += p4.w * wv.x; acc[3][1] += p4.w * wv.y;
    }
  }
  // conv residual: stage v rows n0-16 .. n0+47
  __syncthreads();
  {
    int r = t >> 2, cc = (t & 3) * 16;
    int seq = n0 - 16 + r;
    if (seq >= 0 && seq < NPAD) {
      const float* p = qkv + ((size_t)b * NPAD + seq) * 1536 + 1024 + h * 64 + cc;
#pragma unroll
      for (int i = 0; i < 16; i += 4)
        *(float4*)&cS[r][cc + i] = *(const float4*)(p + i);
    } else {
      float4 z = {0, 0, 0, 0};
#pragma unroll
      for (int i = 0; i < 16; i += 4) *(float4*)&cS[r][cc + i] = z;
    }
  }
  __syncthreads();
  float cacc[4][2] = {{0.f, 0.f}, {0.f, 0.f}, {0.f, 0.f}, {0.f, 0.f}};
  for (int k = 0; k < 33; ++k) {
    float wv = w33[k];
#pragma unroll
    for (int i = 0; i < 4; ++i) {
      float2 v2 = *(float2*)&cS[4 * ty + i + k][tx * 2];
      cacc[i][0] += wv * v2.x;
      cacc[i][1] += wv * v2.y;
    }
  }
#pragma unroll
  for (int i = 0; i < 4; ++i) {
    float2 o;
    o.x = acc[i][0] + cacc[i][0];
    o.y = acc[i][1] + cacc[i][1];
    *(float2*)(attout + ((size_t)b * NPAD + n0 + 4 * ty + i) * DD + h * 64 + tx * 2) = o;
  }
}

// ---------------------------------------------------------------- PPEG (combined 7x7)
// y = f + conv7(f)+b7 + conv5(f)+b5 + conv3(f)+b3  -> single 7x7 kernel (supports nest)
// grid (128*4, 4, 2): blockIdx.x = i*4 + jb
__global__ __launch_bounds__(128) void k_ppeg(
    float* __restrict__ hB, const float* __restrict__ hA,
    const float* __restrict__ w7, const float* __restrict__ b7,
    const float* __restrict__ w5, const float* __restrict__ b5,
    const float* __restrict__ w3, const float* __restrict__ b3) {
  __shared__ float cw[49][128];
  int t = threadIdx.x;
  int i = blockIdx.x >> 2;
  int j0 = (blockIdx.x & 3) * 32;
  int cg = blockIdx.y, b = blockIdx.z;
  int c = cg * 128 + t;
#pragma unroll
  for (int k = 0; k < 49; ++k) cw[k][t] = w7[c * 49 + k];
#pragma unroll
  for (int di = 0; di < 5; ++di)
#pragma unroll
    for (int dj = 0; dj < 5; ++dj)
      cw[(di + 1) * 7 + dj + 1][t] += w5[c * 25 + di * 5 + dj];
#pragma unroll
  for (int di = 0; di < 3; ++di)
#pragma unroll
    for (int dj = 0; dj < 3; ++dj)
      cw[(di + 2) * 7 + dj + 2][t] += w3[c * 9 + di * 3 + dj];
  cw[24][t] += 1.0f;  // identity tap
  float bias = b7[c] + b5[c] + b3[c];
  const float* base = hA + (size_t)b * TT * DD + DD + c;
  float* obase = hB + (size_t)b * TT * DD + DD + c;
  float acc[32];
#pragma unroll
  for (int j = 0; j < 32; ++j) acc[j] = bias;
  for (int di = 0; di < 7; ++di) {
    int ii = i + di - 3;
    if ((unsigned)ii >= 128u) continue;
    float win[38];
#pragma unroll
    for (int w = 0; w < 38; ++w) {
      int col = j0 - 3 + w;
      win[w] = ((unsigned)col < 128u) ? base[(size_t)(ii * 128 + col) * DD] : 0.f;
    }
#pragma unroll
    for (int dj = 0; dj < 7; ++dj) {
      float wv = cw[di * 7 + dj][t];
#pragma unroll
      for (int j = 0; j < 32; ++j) acc[j] += win[j + dj] * wv;
    }
  }
#pragma unroll
  for (int j = 0; j < 32; ++j) obase[(size_t)(i * 128 + j0 + j) * DD] = acc[j];
}

// ---------------------------------------------------------------- final head
__global__ __launch_bounds__(512) void k_final(
    float* __restrict__ out, const float* __restrict__ h,
    const float* __restrict__ g, const float* __restrict__ be,
    const float* __restrict__ cw, const float* __restrict__ cbias) {
  __shared__ float sm[16];
  int t = threadIdx.x;
  for (int b = 0; b < 2; ++b) {
    const float* row = h + (size_t)b * TT * DD;
    float x = row[t];
    float s = x;
    for (int o = 32; o; o >>= 1) s += __shfl_xor(s, o);
    if ((t & 63) == 0) sm[t >> 6] = s;
    __syncthreads();
    float mu = 0.f;
    for (int i = 0; i < 8; ++i) mu += sm[i];
    mu *= (1.f / 512.f);
    __syncthreads();
    float d = x - mu;
    s = d * d;
    for (int o = 32; o; o >>= 1) s += __shfl_xor(s, o);
    if ((t & 63) == 0) sm[t >> 6] = s;
    __syncthreads();
    float var = 0.f;
    for (int i = 0; i < 8; ++i) var += sm[i];
    var *= (1.f / 512.f);
    float rs = rsqrtf(var + 1e-5f);
    __syncthreads();
    float f = d * rs * g[t] + be[t];
    float p0 = f * cw[2 * t], p1 = f * cw[2 * t + 1];
    for (int o = 32; o; o >>= 1) {
      p0 += __shfl_xor(p0, o);
      p1 += __shfl_xor(p1, o);
    }
    if ((t & 63) == 0) {
      sm[t >> 6] = p0;
      sm[8 + (t >> 6)] = p1;
    }
    __syncthreads();
    if (t == 0) {
      float q0 = 0.f, q1 = 0.f;
      for (int i = 0; i < 8; ++i) {
        q0 += sm[i];
        q1 += sm[8 + i];
      }
      out[b * 2 + 0] = q0 + cbias[0];
      out[b * 2 + 1] = q1 + cbias[1];
    }
    __syncthreads();
  }
}

// ---------------------------------------------------------------- host side
static void run_attn(float* h, const float* lng, const float* lnb,
                     const float* wqkv, const float* wout, const float* bout,
                     const float* resw, float* xp, float* qkv, float* ql, float* kl,
                     float* a2, float* z0, float* z1, float* xz, float* yA, float* yB,
                     float* yC, float* bv, float* w2, float* red, float* Sbuf,
                     hipStream_t stream) {
  k_zero_pad<<<BB * PADF, 256, 0, stream>>>(xp);
  k_ln_pad<<<(BB * TT + 3) / 4, 256, 0, stream>>>(xp, h, lng, lnb);
  k_gemm<1><<<dim3(BB * NPAD / 128, 1536 / 128), 256, 0, stream>>>(
      xp, wqkv, nullptr, qkv, BB * NPAD, DD, 1536, DD);
  k_landmarks<<<1024, 256, 0, stream>>>(ql, kl, qkv);
  // split-K flash partials live in the dead Sbuf region
  float* pacc = Sbuf;
  float* pml = Sbuf + (size_t)A3KC * 4096 * 64;
  k_a3v<<<dim3(16, 16, A3KC), 256, 0, stream>>>(pacc, pml, ql, qkv);
  k_a3v_red<<<4096, 64, 0, stream>>>(bv, pacc, pml);
  k_sim2<<<dim3(4, 4, 16), 256, 0, stream>>>(a2, ql, kl);
  k_softmax256<<<1024, 256, 0, stream>>>(a2);
  k_pinv_sums<<<16, 256, 0, stream>>>(red, a2);
  k_pinv_scale<<<1, 256, 0, stream>>>(red);
  k_zinit<<<dim3(256, 16), 256, 0, stream>>>(z0, a2, red);
  float* zc = z0;
  float* zn = z1;
  for (int it = 0; it < 6; ++it) {
    k_bmm<<<dim3(4, 4, 16), 256, 0, stream>>>(a2, zc, xz, 1.f, 0.f, yA, -1.f, 7.f, 256);
    k_bmm<<<dim3(4, 4, 16), 256, 0, stream>>>(xz, yA, yB, -1.f, 15.f, nullptr, 0.f, 0.f, 256);
    k_bmm<<<dim3(4, 4, 16), 256, 0, stream>>>(xz, yB, yC, -1.f, 13.f, nullptr, 0.f, 0.f, 256);
    k_bmm<<<dim3(4, 4, 16), 256, 0, stream>>>(zc, yC, zn, 0.25f, 0.f, nullptr, 0.f, 0.f, 256);
    float* tmp = zc; zc = zn; zn = tmp;
  }
  k_bmm<<<dim3(1, 4, 16), 256, 0, stream>>>(zc, bv, w2, 1.f, 0.f, nullptr, 0.f, 0.f, 64);
  for (int bh0 = 0; bh0 < 16; bh0 += NBH) {
    k_score<<<dim3(NPAD / 64, 4, NBH), 256, 0, stream>>>(Sbuf, qkv, kl, bh0);
    k_pv<<<dim3(NPAD / 32, NBH), 256, 0, stream>>>(xp, Sbuf, qkv, w2, resw, bh0);
  }
  k_gemm<2><<<dim3((TT + 127) / 128, 4, BB), 256, 0, stream>>>(xp, wout, bout, h, TT, DD,
                                                               DD, DD);
}

extern "C" void kernel_launch(void* const* d_in, const int* in_sizes, int n_in,
                              void* d_out, int out_size, void* d_ws, size_t ws_size,
                              hipStream_t stream) {
  const float* x        = (const float*)d_in[0];
  const float* w_feat   = (const float*)d_in[1];
  const float* b_feat   = (const float*)d_in[2];
  const float* cls_tok  = (const float*)d_in[3];
  const float* ln1_g    = (const float*)d_in[4];
  const float* ln1_b    = (const float*)d_in[5];
  const float* qkv1     = (const float*)d_in[6];
  const float* out1_w   = (const float*)d_in[7];
  const float* out1_b   = (const float*)d_in[8];
  const float* res1_w   = (const float*)d_in[9];
  const float* ppeg_w7  = (const float*)d_in[10];
  const float* ppeg_b7  = (const float*)d_in[11];
  const float* ppeg_w5  = (const float*)d_in[12];
  const float* ppeg_b5  = (const float*)d_in[13];
  const float* ppeg_w3  = (const float*)d_in[14];
  const float* ppeg_b3  = (const float*)d_in[15];
  const float* ln2_g    = (const float*)d_in[16];
  const float* ln2_b    = (const float*)d_in[17];
  const float* qkv2     = (const float*)d_in[18];
  const float* out2_w   = (const float*)d_in[19];
  const float* out2_b   = (const float*)d_in[20];
  const float* res2_w   = (const float*)d_in[21];
  const float* lnf_g    = (const float*)d_in[22];
  const float* lnf_b    = (const float*)d_in[23];
  const float* cls_w    = (const float*)d_in[24];
  const float* cls_b    = (const float*)d_in[25];

  float* ws = (float*)d_ws;
  size_t off = 0;
  float* hA  = ws + off; off += (size_t)BB * TT * DD;        // 16,778,240
  float* hB  = ws + off; off += (size_t)BB * TT * DD;
  float* xp  = ws + off; off += (size_t)BB * NPAD * DD;      // also attout
  float* qkv = ws + off; off += (size_t)BB * NPAD * 3 * DD;
  float* ql  = ws + off; off += (size_t)BB * HH * 256 * 64;
  float* kl  = ws + off; off += (size_t)BB * HH * 256 * 64;
  float* a2  = ws + off; off += (size_t)16 * 65536;
  float* z0  = ws + off; off += (size_t)16 * 65536;
  float* z1  = ws + off; off += (size_t)16 * 65536;
  float* xz  = ws + off; off += (size_t)16 * 65536;
  float* yA  = ws + off; off += (size_t)16 * 65536;
  float* yB  = ws + off; off += (size_t)16 * 65536;
  float* yC  = ws + off; off += (size_t)16 * 65536;
  float* bv  = ws + off; off += (size_t)BB * HH * 256 * 64;
  float* w2  = ws + off; off += (size_t)BB * HH * 256 * 64;
  float* red = ws + off; off += 8448;

  // Stage 1: h = gelu(x @ w_feat + b_feat), prepend cls token
  k_set_cls<<<2, 512, 0, stream>>>(hA, cls_tok);
  k_gemm<0><<<dim3(32768 / 128, 512 / 128), 256, 0, stream>>>(x, w_feat, b_feat, hA,
                                                              32768, 1024, 512, 1024);
  // Attention 1 (residual in-place on hA; hB is dead -> use as scratch)
  run_attn(hA, ln1_g, ln1_b, qkv1, out1_w, out1_b, res1_w, xp, qkv, ql, kl, a2, z0, z1,
           xz, yA, yB, yC, bv, w2, red, hB, stream);
  // PPEG: hB = ppeg(hA)
  k_copy_cls<<<2, 512, 0, stream>>>(hB, hA);
  k_ppeg<<<dim3(512, 4, 2), 128, 0, stream>>>(hB, hA, ppeg_w7, ppeg_b7, ppeg_w5, ppeg_b5,
                                              ppeg_w3, ppeg_b3);
  // Attention 2 (residual in-place on hB; hA is dead -> use as scratch)
  run_attn(hB, ln2_g, ln2_b, qkv2, out2_w, out2_b, res2_w, xp, qkv, ql, kl, a2, z0, z1,
           xz, yA, yB, yC, bv, w2, red, hA, stream);
  // Final: LN(cls) @ cls_w + cls_b
  k_final<<<1, 512, 0, stream>>>((float*)d_out, hB, lnf_g, lnf_b, cls_w, cls_b);
}

// Round 4
// 4510.408 us; speedup vs baseline: 2.3860x; 1.3548x over previous
//
#include <hip/hip_runtime.h>
#include <cstdint>
#include <cstddef>

#define BB 2
#define TT 16385
#define NPAD 16640
#define DD 512
#define HH 8
#define DHH 64
#define MLAND 256
#define PADF 255
#define NBH 2
#define A3KC 10
#define A3CH 1664

typedef __attribute__((ext_vector_type(8))) short bf16x8;
typedef __attribute__((ext_vector_type(4))) float f32x4;

__device__ __forceinline__ float dot4f(const float4 a, const float4 b) {
  return a.x * b.x + a.y * b.y + a.z * b.z + a.w * b.w;
}

__device__ __forceinline__ float gelu_f(float v) {
  float c = 0.7978845608028654f * (v + 0.044715f * v * v * v);
  return 0.5f * v * (1.0f + tanhf(c));
}

// split a,b into bf16 hi (packed) and bf16 lo (packed), RNE
__device__ __forceinline__ void split2(float a, float b, unsigned& hi, unsigned& lo) {
  unsigned ua = __float_as_uint(a);
  unsigned ha = (ua + 0x7FFFu + ((ua >> 16) & 1u)) & 0xFFFF0000u;
  unsigned ub = __float_as_uint(b);
  unsigned hb = (ub + 0x7FFFu + ((ub >> 16) & 1u)) & 0xFFFF0000u;
  float la = a - __uint_as_float(ha);
  float lb = b - __uint_as_float(hb);
  hi = (ha >> 16) | hb;
  unsigned ula = __float_as_uint(la);
  unsigned pa = (ula + 0x7FFFu + ((ula >> 16) & 1u)) >> 16;
  unsigned ulb = __float_as_uint(lb);
  unsigned pb = (ulb + 0x7FFFu + ((ulb >> 16) & 1u)) & 0xFFFF0000u;
  lo = pa | pb;
}

// ---------------------------------------------------------------- cls rows
__global__ void k_set_cls(float* __restrict__ h, const float* __restrict__ cls) {
  h[(size_t)blockIdx.x * TT * DD + threadIdx.x] = cls[threadIdx.x];
}
__global__ void k_copy_cls(float* __restrict__ dst, const float* __restrict__ src) {
  size_t o = (size_t)blockIdx.x * TT * DD + threadIdx.x;
  dst[o] = src[o];
}

// ------------------------------------------------ W[K][N] -> Wt hi/lo [N][K]
__global__ __launch_bounds__(256) void k_cvt_wt(
    const float* __restrict__ W, unsigned short* __restrict__ Wth,
    unsigned short* __restrict__ Wtl, int K, int N) {
  __shared__ float tile[32][33];
  int kb = blockIdx.x * 32, nb = blockIdx.y * 32;
  int t = threadIdx.x;
  int tr = t >> 3, tc4 = (t & 7) * 4;
  float4 v = *(const float4*)(W + (size_t)(kb + tr) * N + nb + tc4);
  tile[tr][tc4 + 0] = v.x;
  tile[tr][tc4 + 1] = v.y;
  tile[tr][tc4 + 2] = v.z;
  tile[tr][tc4 + 3] = v.w;
  __syncthreads();
  int n = nb + tr;
  ushort4 hs, ls;
  unsigned short hv[4], lv[4];
#pragma unroll
  for (int j = 0; j < 4; ++j) {
    float a = tile[tc4 + j][tr];
    unsigned ua = __float_as_uint(a);
    unsigned ha = (ua + 0x7FFFu + ((ua >> 16) & 1u)) & 0xFFFF0000u;
    float lo = a - __uint_as_float(ha);
    unsigned ul = __float_as_uint(lo);
    unsigned hl = (ul + 0x7FFFu + ((ul >> 16) & 1u)) >> 16;
    hv[j] = (unsigned short)(ha >> 16);
    lv[j] = (unsigned short)hl;
  }
  hs = make_ushort4(hv[0], hv[1], hv[2], hv[3]);
  ls = make_ushort4(lv[0], lv[1], lv[2], lv[3]);
  *(ushort4*)(Wth + (size_t)n * K + kb + tc4) = hs;
  *(ushort4*)(Wtl + (size_t)n * K + kb + tc4) = ls;
}

// ------------------------------------------ split-bf16 MFMA GEMM, 128x128 tile
// MODE 0: feat: C[r + r/16384 + 1] = gelu(A@W + bias)
// MODE 1: plain: C = A@W (N=1536)
// MODE 2: proj: h[b][r] += A[b*NPAD+255+r]@W + bias (grid.z = batch)
template <int MODE>
__global__ __launch_bounds__(256) void k_gemm_mfma(
    const float* __restrict__ A, const unsigned short* __restrict__ Wth,
    const unsigned short* __restrict__ Wtl, const float* __restrict__ bias,
    float* __restrict__ C, int M, int K, int N, int lda) {
  __shared__ short Ash[128][32];
  __shared__ short Asl[128][32];
  __shared__ short Bsh[128][32];
  __shared__ short Bsl[128][32];
  const int t = threadIdx.x;
  const int rb = blockIdx.x * 128, cb = blockIdx.y * 128;
  const float* Ab = A;
  float* Cb = C;
  if (MODE == 2) {
    int b = blockIdx.z;
    Ab = A + (size_t)b * NPAD * DD + (size_t)PADF * DD;
    Cb = C + (size_t)b * TT * DD;
  }
  const int lane = t & 63, wv = t >> 6;
  const int wr = wv >> 1, wc = wv & 1;
  const int fr = lane & 15, kg = lane >> 4;
  const int srow = t >> 1, skh = (t & 1) * 16;

  f32x4 acc[4][4];
  f32x4 zero4 = {0.f, 0.f, 0.f, 0.f};
#pragma unroll
  for (int i = 0; i < 4; ++i)
#pragma unroll
    for (int j = 0; j < 4; ++j) acc[i][j] = zero4;

  for (int k0 = 0; k0 < K; k0 += 32) {
    __syncthreads();
    {  // stage A with hi/lo split
      int grow = rb + srow;
      float4 f0 = {0, 0, 0, 0}, f1 = {0, 0, 0, 0}, f2 = {0, 0, 0, 0}, f3 = {0, 0, 0, 0};
      if (grow < M) {
        const float* p = Ab + (size_t)grow * lda + k0 + skh;
        f0 = *(const float4*)p;
        f1 = *(const float4*)(p + 4);
        f2 = *(const float4*)(p + 8);
        f3 = *(const float4*)(p + 12);
      }
      unsigned h0, h1, h2, h3, h4, h5, h6, h7;
      unsigned l0, l1, l2, l3, l4, l5, l6, l7;
      split2(f0.x, f0.y, h0, l0);
      split2(f0.z, f0.w, h1, l1);
      split2(f1.x, f1.y, h2, l2);
      split2(f1.z, f1.w, h3, l3);
      split2(f2.x, f2.y, h4, l4);
      split2(f2.z, f2.w, h5, l5);
      split2(f3.x, f3.y, h6, l6);
      split2(f3.z, f3.w, h7, l7);
      *(uint4*)&Ash[srow][skh] = make_uint4(h0, h1, h2, h3);
      *(uint4*)&Ash[srow][skh + 8] = make_uint4(h4, h5, h6, h7);
      *(uint4*)&Asl[srow][skh] = make_uint4(l0, l1, l2, l3);
      *(uint4*)&Asl[srow][skh + 8] = make_uint4(l4, l5, l6, l7);
    }
    {  // stage B (pre-split planes, row-major [N][K])
      int lc = t >> 1;
      const unsigned short* ph = Wth + (size_t)(cb + lc) * K + k0 + skh;
      const unsigned short* pl = Wtl + (size_t)(cb + lc) * K + k0 + skh;
      *(uint4*)&Bsh[lc][skh] = *(const uint4*)ph;
      *(uint4*)&Bsh[lc][skh + 8] = *(const uint4*)(ph + 8);
      *(uint4*)&Bsl[lc][skh] = *(const uint4*)pl;
      *(uint4*)&Bsl[lc][skh + 8] = *(const uint4*)(pl + 8);
    }
    __syncthreads();
    bf16x8 ah[4], al[4], bh[4], bl[4];
#pragma unroll
    for (int mf = 0; mf < 4; ++mf) {
      ah[mf] = *(const bf16x8*)&Ash[wr * 64 + mf * 16 + fr][kg * 8];
      al[mf] = *(const bf16x8*)&Asl[wr * 64 + mf * 16 + fr][kg * 8];
    }
#pragma unroll
    for (int nf = 0; nf < 4; ++nf) {
      bh[nf] = *(const bf16x8*)&Bsh[wc * 64 + nf * 16 + fr][kg * 8];
      bl[nf] = *(const bf16x8*)&Bsl[wc * 64 + nf * 16 + fr][kg * 8];
    }
#pragma unroll
    for (int mf = 0; mf < 4; ++mf)
#pragma unroll
      for (int nf = 0; nf < 4; ++nf) {
        acc[mf][nf] =
            __builtin_amdgcn_mfma_f32_16x16x32_bf16(ah[mf], bh[nf], acc[mf][nf], 0, 0, 0);
        acc[mf][nf] =
            __builtin_amdgcn_mfma_f32_16x16x32_bf16(al[mf], bh[nf], acc[mf][nf], 0, 0, 0);
        acc[mf][nf] =
            __builtin_amdgcn_mfma_f32_16x16x32_bf16(ah[mf], bl[nf], acc[mf][nf], 0, 0, 0);
      }
  }
  // epilogue: C frag layout col=lane&15, row=(lane>>4)*4+r
#pragma unroll
  for (int mf = 0; mf < 4; ++mf) {
#pragma unroll
    for (int r = 0; r < 4; ++r) {
      int row = rb + wr * 64 + mf * 16 + kg * 4 + r;
      if (MODE == 2 && row >= M) continue;
      size_t orow = (MODE == 0) ? (size_t)(row + (row >> 14) + 1) : (size_t)row;
#pragma unroll
      for (int nf = 0; nf < 4; ++nf) {
        int col = cb + wc * 64 + nf * 16 + fr;
        float v = acc[mf][nf][r];
        if (MODE == 0) {
          Cb[orow * DD + col] = gelu_f(v + bias[col]);
        } else if (MODE == 1) {
          Cb[orow * (size_t)N + col] = v;
        } else {
          float old = Cb[orow * DD + col];
          Cb[orow * DD + col] = old + v + bias[col];
        }
      }
    }
  }
}

// ---------------------------------------------------------------- LN + pad
__global__ __launch_bounds__(256) void k_ln_pad(
    float* __restrict__ xp, const float* __restrict__ h,
    const float* __restrict__ gam, const float* __restrict__ bet) {
  int w = threadIdx.x >> 6, lane = threadIdx.x & 63;
  int row = blockIdx.x * 4 + w;
  if (row >= BB * TT) return;
  int b = row / TT, i = row - b * TT;
  const float* src = h + (size_t)row * DD;
  float4 x0 = *(const float4*)(src + lane * 4);
  float4 x1 = *(const float4*)(src + 256 + lane * 4);
  float s = x0.x + x0.y + x0.z + x0.w + x1.x + x1.y + x1.z + x1.w;
  for (int o = 32; o; o >>= 1) s += __shfl_xor(s, o);
  float mu = s * (1.f / 512.f);
  float q = (x0.x - mu) * (x0.x - mu) + (x0.y - mu) * (x0.y - mu) +
            (x0.z - mu) * (x0.z - mu) + (x0.w - mu) * (x0.w - mu) +
            (x1.x - mu) * (x1.x - mu) + (x1.y - mu) * (x1.y - mu) +
            (x1.z - mu) * (x1.z - mu) + (x1.w - mu) * (x1.w - mu);
  for (int o = 32; o; o >>= 1) q += __shfl_xor(q, o);
  float rs = rsqrtf(q * (1.f / 512.f) + 1e-5f);
  float4 g0 = *(const float4*)(gam + lane * 4);
  float4 g1 = *(const float4*)(gam + 256 + lane * 4);
  float4 b0 = *(const float4*)(bet + lane * 4);
  float4 b1 = *(const float4*)(bet + 256 + lane * 4);
  float* dst = xp + ((size_t)b * NPAD + PADF + i) * DD;
  float4 o0, o1;
  o0.x = (x0.x - mu) * rs * g0.x + b0.x;
  o0.y = (x0.y - mu) * rs * g0.y + b0.y;
  o0.z = (x0.z - mu) * rs * g0.z + b0.z;
  o0.w = (x0.w - mu) * rs * g0.w + b0.w;
  o1.x = (x1.x - mu) * rs * g1.x + b1.x;
  o1.y = (x1.y - mu) * rs * g1.y + b1.y;
  o1.z = (x1.z - mu) * rs * g1.z + b1.z;
  o1.w = (x1.w - mu) * rs * g1.w + b1.w;
  *(float4*)(dst + lane * 4) = o0;
  *(float4*)(dst + 256 + lane * 4) = o1;
}

__global__ void k_zero_pad(float* __restrict__ xp) {
  int r = blockIdx.x;
  int b = r / PADF, j = r - b * PADF;
  float* p = xp + ((size_t)b * NPAD + j) * DD;
  p[threadIdx.x * 2] = 0.f;
  p[threadIdx.x * 2 + 1] = 0.f;
}

// ---------------------------------------------------------------- landmarks
__global__ __launch_bounds__(256) void k_landmarks(
    float* __restrict__ ql, float* __restrict__ kl, const float* __restrict__ qkv) {
  int t = threadIdx.x;
  int mi = t >> 6, d = t & 63;
  int blk = blockIdx.x;
  int bh = blk >> 6, mg = blk & 63;
  int b = bh >> 3, h = bh & 7;
  int m = mg * 4 + mi;
  const float* base = qkv + (size_t)b * NPAD * 1536 + h * 64 + d;
  float sq = 0.f, sk = 0.f;
  int t0 = m * 65;
  for (int j = 0; j < 65; ++j) {
    const float* p = base + (size_t)(t0 + j) * 1536;
    sq += p[0];
    sk += p[512];
  }
  ql[((size_t)bh * 256 + m) * 64 + d] = sq * (0.125f / 65.f);
  kl[((size_t)bh * 256 + m) * 64 + d] = sk * (1.f / 65.f);
}

// ---------------------------------------------------------------- sim2 = ql @ kl^T
__global__ __launch_bounds__(256) void k_sim2(
    float* __restrict__ sim, const float* __restrict__ ql, const float* __restrict__ kl) {
  __shared__ __align__(16) float Aq[64][68];
  __shared__ __align__(16) float Bk[64][68];
  int t = threadIdx.x;
  int tj = blockIdx.x, ti = blockIdx.y, bh = blockIdx.z;
  int r = t >> 2, cc = (t & 3) * 16;
  const float* ap = ql + ((size_t)bh * 256 + ti * 64 + r) * 64 + cc;
  const float* bp = kl + ((size_t)bh * 256 + tj * 64 + r) * 64 + cc;
#pragma unroll
  for (int i = 0; i < 16; i += 4) {
    *(float4*)&Aq[r][cc + i] = *(const float4*)(ap + i);
    *(float4*)&Bk[r][cc + i] = *(const float4*)(bp + i);
  }
  __syncthreads();
  int tx = t & 15, ty = t >> 4;
  float acc[4][4];
#pragma unroll
  for (int i = 0; i < 4; ++i)
#pragma unroll
    for (int j = 0; j < 4; ++j) acc[i][j] = 0.f;
  for (int d = 0; d < 64; d += 4) {
    float4 a4[4], b4[4];
#pragma unroll
    for (int ii = 0; ii < 4; ++ii) a4[ii] = *(float4*)&Aq[ty * 4 + ii][d];
#pragma unroll
    for (int jj = 0; jj < 4; ++jj) b4[jj] = *(float4*)&Bk[tx * 4 + jj][d];
#pragma unroll
    for (int ii = 0; ii < 4; ++ii)
#pragma unroll
      for (int jj = 0; jj < 4; ++jj) acc[ii][jj] += dot4f(a4[ii], b4[jj]);
  }
#pragma unroll
  for (int ii = 0; ii < 4; ++ii)
#pragma unroll
    for (int jj = 0; jj < 4; ++jj)
      sim[((size_t)bh * 256 + ti * 64 + ty * 4 + ii) * 256 + tj * 64 + tx * 4 + jj] =
          acc[ii][jj];
}

// ---------------------------------------------------------------- row softmax (len 256)
__global__ __launch_bounds__(256) void k_softmax256(float* __restrict__ a) {
  int w = threadIdx.x >> 6, lane = threadIdx.x & 63;
  size_t row = (size_t)blockIdx.x * 4 + w;
  float* p = a + row * 256 + lane * 4;
  float4 v = *(float4*)p;
  float m = fmaxf(fmaxf(v.x, v.y), fmaxf(v.z, v.w));
  for (int o = 32; o; o >>= 1) m = fmaxf(m, __shfl_xor(m, o));
  v.x = expf(v.x - m); v.y = expf(v.y - m);
  v.z = expf(v.z - m); v.w = expf(v.w - m);
  float s = v.x + v.y + v.z + v.w;
  for (int o = 32; o; o >>= 1) s += __shfl_xor(s, o);
  float inv = 1.f / s;
  v.x *= inv; v.y *= inv; v.z *= inv; v.w *= inv;
  *(float4*)p = v;
}

// ---------------------------------------------------------------- pinv helpers
__global__ void k_pinv_sums(float* __restrict__ red, const float* __restrict__ a2) {
  int bh = blockIdx.x, t = threadIdx.x;
  const float* Ab = a2 + (size_t)bh * 65536;
  float s = 0.f;
  for (int i = 0; i < 256; ++i) s += fabsf(Ab[(size_t)i * 256 + t]);
  red[bh * 256 + t] = s;
  float c = 0.f;
  const float* rp = Ab + (size_t)t * 256;
  for (int j = 0; j < 256; j += 4) {
    float4 v = *(const float4*)(rp + j);
    c += fabsf(v.x) + fabsf(v.y) + fabsf(v.z) + fabsf(v.w);
  }
  red[4096 + bh * 256 + t] = c;
}

__global__ void k_pinv_scale(float* __restrict__ red) {
  __shared__ float sm[8];
  int t = threadIdx.x;
  float m1 = 0.f, m2 = 0.f;
  for (int k = t; k < 4096; k += 256) {
    m1 = fmaxf(m1, red[k]);
    m2 = fmaxf(m2, red[4096 + k]);
  }
  for (int o = 32; o; o >>= 1) {
    m1 = fmaxf(m1, __shfl_xor(m1, o));
    m2 = fmaxf(m2, __shfl_xor(m2, o));
  }
  int w = t >> 6;
  if ((t & 63) == 0) { sm[w] = m1; sm[4 + w] = m2; }
  __syncthreads();
  if (t == 0) {
    float a = fmaxf(fmaxf(sm[0], sm[1]), fmaxf(sm[2], sm[3]));
    float b = fmaxf(fmaxf(sm[4], sm[5]), fmaxf(sm[6], sm[7]));
    red[8192] = 1.0f / (a * b);
  }
}

__global__ void k_zinit(float* __restrict__ z, const float* __restrict__ a2,
                        const float* __restrict__ red) {
  float s = red[8192];
  int i = blockIdx.x, bh = blockIdx.y, j = threadIdx.x;
  z[((size_t)bh * 256 + i) * 256 + j] = a2[((size_t)bh * 256 + j) * 256 + i] * s;
}

// batched (16) 256x256 @ 256xN; C1 = a1*(A@B) + d1*I ; optional C2
__global__ __launch_bounds__(256) void k_bmm(
    const float* __restrict__ A, const float* __restrict__ Bm,
    float* __restrict__ C1, float a1, float d1,
    float* __restrict__ C2, float a2c, float d2, int N) {
  __shared__ __align__(16) float As[16][64];
  __shared__ __align__(16) float Bs[16][64];
  int t = threadIdx.x;
  int bh = blockIdx.z;
  int i0 = blockIdx.y * 64, j0 = blockIdx.x * 64;
  const float* Ab = A + (size_t)bh * 65536;
  const float* Bb = Bm + (size_t)bh * 256 * N;
  float acc[4][4];
#pragma unroll
  for (int i = 0; i < 4; ++i)
#pragma unroll
    for (int j = 0; j < 4; ++j) acc[i][j] = 0.f;
  int tx = t & 15, ty = t >> 4;
  for (int k0 = 0; k0 < 256; k0 += 16) {
    __syncthreads();
    {
      int r = t >> 2, kl2 = (t & 3) * 4;
      float4 v = *(const float4*)(Ab + (size_t)(i0 + r) * 256 + k0 + kl2);
      As[kl2 + 0][r] = v.x; As[kl2 + 1][r] = v.y;
      As[kl2 + 2][r] = v.z; As[kl2 + 3][r] = v.w;
    }
    {
      int kr = t >> 4, nl = (t & 15) * 4;
      *(float4*)&Bs[kr][nl] = *(const float4*)(Bb + (size_t)(k0 + kr) * N + j0 + nl);
    }
    __syncthreads();
#pragma unroll
    for (int kk = 0; kk < 16; ++kk) {
      float4 a4 = *(float4*)&As[kk][ty * 4];
      float4 b4 = *(float4*)&Bs[kk][tx * 4];
      float av[4] = {a4.x, a4.y, a4.z, a4.w};
      float bv2[4] = {b4.x, b4.y, b4.z, b4.w};
#pragma unroll
      for (int i = 0; i < 4; ++i)
#pragma unroll
        for (int j = 0; j < 4; ++j) acc[i][j] += av[i] * bv2[j];
    }
  }
#pragma unroll
  for (int ii = 0; ii < 4; ++ii)
#pragma unroll
    for (int jj = 0; jj < 4; ++jj) {
      int i = i0 + ty * 4 + ii, j = j0 + tx * 4 + jj;
      float v = acc[ii][jj];
      size_t off = (size_t)bh * 256 * N + (size_t)i * N + j;
      C1[off] = a1 * v + ((i == j) ? d1 : 0.f);
      if (C2) C2[off] = a2c * v + ((i == j) ? d2 : 0.f);
    }
}

// -------------------------- a3 @ v (split-K flash partials over key chunks)
__global__ __launch_bounds__(256) void k_a3v(
    float* __restrict__ pacc, float* __restrict__ pml,
    const float* __restrict__ ql, const float* __restrict__ qkv) {
  __shared__ __align__(16) float qlS[16][68];
  __shared__ __align__(16) float kS[64][68];
  __shared__ __align__(16) float vS[64][68];
  __shared__ __align__(16) float pS[16][68];
  int t = threadIdx.x;
  int mb = blockIdx.x;
  int bh = blockIdx.y;
  int kc = blockIdx.z;
  int b = bh >> 3, h = bh & 7;
  {
    int mi = t >> 4, d = (t & 15) * 4;
    *(float4*)&qlS[mi][d] =
        *(const float4*)(ql + ((size_t)bh * 256 + mb * 16 + mi) * 64 + d);
  }
  int m = t >> 4, tx = t & 15;
  float rmax = -INFINITY, rsum = 0.f;
  float4 acc = {0, 0, 0, 0};
  int ldr = t >> 2;
  int ldcc = (t & 3) * 16;
  const float* kbase = qkv + (size_t)b * NPAD * 1536 + 512 + h * 64 + ldcc;
  int nt0 = kc * A3CH;
  for (int it = 0; it < A3CH / 64; ++it) {
    int nt = nt0 + it * 64;
    __syncthreads();
    {
      const float* kp = kbase + (size_t)(nt + ldr) * 1536;
#pragma unroll
      for (int i = 0; i < 16; i += 4) {
        *(float4*)&kS[ldr][ldcc + i] = *(const float4*)(kp + i);
        *(float4*)&vS[ldr][ldcc + i] = *(const float4*)(kp + 512 + i);
      }
    }
    __syncthreads();
    float s[4] = {0.f, 0.f, 0.f, 0.f};
    for (int d = 0; d < 64; d += 4) {
      float4 q4 = *(float4*)&qlS[m][d];
#pragma unroll
      for (int j = 0; j < 4; ++j) s[j] += dot4f(q4, *(float4*)&kS[tx + 16 * j][d]);
    }
    float lmax = fmaxf(fmaxf(s[0], s[1]), fmaxf(s[2], s[3]));
    for (int o = 8; o; o >>= 1) lmax = fmaxf(lmax, __shfl_xor(lmax, o));
    float nm = fmaxf(rmax, lmax);
    float corr = expf(rmax - nm);
    float p[4], ls = 0.f;
#pragma unroll
    for (int j = 0; j < 4; ++j) {
      p[j] = expf(s[j] - nm);
      ls += p[j];
    }
    for (int o = 8; o; o >>= 1) ls += __shfl_xor(ls, o);
    rsum = rsum * corr + ls;
    acc.x *= corr; acc.y *= corr; acc.z *= corr; acc.w *= corr;
#pragma unroll
    for (int j = 0; j < 4; ++j) pS[m][tx + 16 * j] = p[j];
    __syncthreads();
    for (int c = 0; c < 64; c += 4) {
      float4 p4 = *(float4*)&pS[m][c];
      float4 v0 = *(float4*)&vS[c + 0][tx * 4];
      float4 v1 = *(float4*)&vS[c + 1][tx * 4];
      float4 v2 = *(float4*)&vS[c + 2][tx * 4];
      float4 v3 = *(float4*)&vS[c + 3][tx * 4];
      acc.x += p4.x * v0.x + p4.y * v1.x + p4.z * v2.x + p4.w * v3.x;
      acc.y += p4.x * v0.y + p4.y * v1.y + p4.z * v2.y + p4.w * v3.y;
      acc.z += p4.x * v0.z + p4.y * v1.z + p4.z * v2.z + p4.w * v3.z;
      acc.w += p4.x * v0.w + p4.y * v1.w + p4.z * v2.w + p4.w * v3.w;
    }
    rmax = nm;
  }
  size_t prow = ((size_t)kc * 16 + bh) * 256 + mb * 16 + m;
  *(float4*)(pacc + prow * 64 + tx * 4) = acc;
  if (tx == 0) {
    pml[prow * 2] = rmax;
    pml[prow * 2 + 1] = rsum;
  }
}

__global__ __launch_bounds__(64) void k_a3v_red(
    float* __restrict__ bv, const float* __restrict__ pacc,
    const float* __restrict__ pml) {
  int row = blockIdx.x;
  int d = threadIdx.x;
  float M = -INFINITY;
#pragma unroll
  for (int c = 0; c < A3KC; ++c)
    M = fmaxf(M, pml[((size_t)c * 4096 + row) * 2]);
  float L = 0.f, A = 0.f;
#pragma unroll
  for (int c = 0; c < A3KC; ++c) {
    size_t pr = (size_t)c * 4096 + row;
    float w = expf(pml[pr * 2] - M);
    L += pml[pr * 2 + 1] * w;
    A += pacc[pr * 64 + d] * w;
  }
  bv[(size_t)row * 64 + d] = A / L;
}

// ---------------------------------------------------------------- scores S
__global__ __launch_bounds__(256) void k_score(
    float* __restrict__ S, const float* __restrict__ qkv,
    const float* __restrict__ kl, int bh0) {
  __shared__ __align__(16) float Aq[64][68];
  __shared__ __align__(16) float Bk[64][68];
  int t = threadIdx.x;
  int ti = blockIdx.x, tj = blockIdx.y;
  int bhl = blockIdx.z;
  int bh = bh0 + bhl;
  int b = bh >> 3, h = bh & 7;
  int r = t >> 2, cc = (t & 3) * 16;
  {
    const float* ap = qkv + ((size_t)b * NPAD + ti * 64 + r) * 1536 + h * 64 + cc;
    const float* bp = kl + ((size_t)bh * 256 + tj * 64 + r) * 64 + cc;
#pragma unroll
    for (int i = 0; i < 16; i += 4) {
      float4 qa = *(const float4*)(ap + i);
      qa.x *= 0.125f; qa.y *= 0.125f; qa.z *= 0.125f; qa.w *= 0.125f;
      *(float4*)&Aq[r][cc + i] = qa;
      *(float4*)&Bk[r][cc + i] = *(const float4*)(bp + i);
    }
  }
  __syncthreads();
  int tx = t & 15, ty = t >> 4;
  float acc[4][4];
#pragma unroll
  for (int i = 0; i < 4; ++i)
#pragma unroll
    for (int j = 0; j < 4; ++j) acc[i][j] = 0.f;
  for (int d = 0; d < 64; d += 4) {
    float4 a4[4], b4[4];
#pragma unroll
    for (int ii = 0; ii < 4; ++ii) a4[ii] = *(float4*)&Aq[ty * 4 + ii][d];
#pragma unroll
    for (int jj = 0; jj < 4; ++jj) b4[jj] = *(float4*)&Bk[tx * 4 + jj][d];
#pragma unroll
    for (int ii = 0; ii < 4; ++ii)
#pragma unroll
      for (int jj = 0; jj < 4; ++jj) acc[ii][jj] += dot4f(a4[ii], b4[jj]);
  }
#pragma unroll
  for (int ii = 0; ii < 4; ++ii) {
    float4 v;
    v.x = acc[ii][0]; v.y = acc[ii][1]; v.z = acc[ii][2]; v.w = acc[ii][3];
    *(float4*)(S + ((size_t)bhl * NPAD + ti * 64 + ty * 4 + ii) * 256 + tj * 64 +
               tx * 4) = v;
  }
}

// --------------------------- out = softmax(S) @ w2 + conv(v), 32 tokens/block
__global__ __launch_bounds__(256) void k_pv(
    float* __restrict__ attout, const float* __restrict__ S,
    const float* __restrict__ qkv, const float* __restrict__ w2,
    const float* __restrict__ resw, int bh0) {
  __shared__ __align__(16) float pT[256][36];
  __shared__ __align__(16) float cS[64][68];
  __shared__ float w33[33];
  int t = threadIdx.x;
  int tb = blockIdx.x;
  int bhl = blockIdx.y;
  int bh = bh0 + bhl;
  int b = bh >> 3, h = bh & 7;
  int n0 = tb * 32;
  if (t < 33) w33[t] = resw[h * 33 + t];
  {
    int r = t >> 3;
    int seg = (t & 7) * 32;
    const float* sp = S + ((size_t)bhl * NPAD + n0 + r) * 256 + seg;
#pragma unroll
    for (int k = 0; k < 32; k += 4) {
      float4 v = *(const float4*)(sp + k);
      pT[seg + k + 0][r] = v.x;
      pT[seg + k + 1][r] = v.y;
      pT[seg + k + 2][r] = v.z;
      pT[seg + k + 3][r] = v.w;
    }
  }
  __syncthreads();
  {
    int tt = t >> 3, g = t & 7;
    float v[32];
    float m = -INFINITY;
#pragma unroll
    for (int k = 0; k < 32; ++k) {
      v[k] = pT[g + 8 * k][tt];
      m = fmaxf(m, v[k]);
    }
    for (int o = 4; o; o >>= 1) m = fmaxf(m, __shfl_xor(m, o));
    float s = 0.f;
#pragma unroll
    for (int k = 0; k < 32; ++k) {
      v[k] = expf(v[k] - m);
      s += v[k];
    }
    for (int o = 4; o; o >>= 1) s += __shfl_xor(s, o);
    float inv = 1.f / s;
#pragma unroll
    for (int k = 0; k < 32; ++k) pT[g + 8 * k][tt] = v[k] * inv;
  }
  int ty = t >> 5, tx = t & 31;
  float acc[4][2] = {{0.f, 0.f}, {0.f, 0.f}, {0.f, 0.f}, {0.f, 0.f}};
  for (int cb = 0; cb < 4; ++cb) {
    __syncthreads();
    {
      int r = t >> 2, cc = (t & 3) * 16;
      const float* p = w2 + ((size_t)bh * 256 + cb * 64 + r) * 64 + cc;
#pragma unroll
      for (int i = 0; i < 16; i += 4)
        *(float4*)&cS[r][cc + i] = *(const float4*)(p + i);
    }
    __syncthreads();
#pragma unroll 4
    for (int l = 0; l < 64; ++l) {
      float4 p4 = *(float4*)&pT[cb * 64 + l][ty * 4];
      float2 wv = *(float2*)&cS[l][tx * 2];
      acc[0][0] += p4.x * wv.x; acc[0][1] += p4.x * wv.y;
      acc[1][0] += p4.y * wv.x; acc[1][1] += p4.y * wv.y;
      acc[2][0] += p4.z * wv.x; acc[2][1] += p4.z * wv.y;
      acc[3][0] += p4.w * wv.x; acc[3][1] += p4.w * wv.y;
    }
  }
  __syncthreads();
  {
    int r = t >> 2, cc = (t & 3) * 16;
    int seq = n0 - 16 + r;
    if (seq >= 0 && seq < NPAD) {
      const float* p = qkv + ((size_t)b * NPAD + seq) * 1536 + 1024 + h * 64 + cc;
#pragma unroll
      for (int i = 0; i < 16; i += 4)
        *(float4*)&cS[r][cc + i] = *(const float4*)(p + i);
    } else {
      float4 z = {0, 0, 0, 0};
#pragma unroll
      for (int i = 0; i < 16; i += 4) *(float4*)&cS[r][cc + i] = z;
    }
  }
  __syncthreads();
  float cacc[4][2] = {{0.f, 0.f}, {0.f, 0.f}, {0.f, 0.f}, {0.f, 0.f}};
  for (int k = 0; k < 33; ++k) {
    float wv = w33[k];
#pragma unroll
    for (int i = 0; i < 4; ++i) {
      float2 v2 = *(float2*)&cS[4 * ty + i + k][tx * 2];
      cacc[i][0] += wv * v2.x;
      cacc[i][1] += wv * v2.y;
    }
  }
#pragma unroll
  for (int i = 0; i < 4; ++i) {
    float2 o;
    o.x = acc[i][0] + cacc[i][0];
    o.y = acc[i][1] + cacc[i][1];
    *(float2*)(attout + ((size_t)b * NPAD + n0 + 4 * ty + i) * DD + h * 64 + tx * 2) = o;
  }
}

// ---------------------------------------------------------------- PPEG (combined 7x7)
__global__ __launch_bounds__(128) void k_ppeg(
    float* __restrict__ hB, const float* __restrict__ hA,
    const float* __restrict__ w7, const float* __restrict__ b7,
    const float* __restrict__ w5, const float* __restrict__ b5,
    const float* __restrict__ w3, const float* __restrict__ b3) {
  __shared__ float cw[49][128];
  int t = threadIdx.x;
  int i = blockIdx.x >> 2;
  int j0 = (blockIdx.x & 3) * 32;
  int cg = blockIdx.y, b = blockIdx.z;
  int c = cg * 128 + t;
#pragma unroll
  for (int k = 0; k < 49; ++k) cw[k][t] = w7[c * 49 + k];
#pragma unroll
  for (int di = 0; di < 5; ++di)
#pragma unroll
    for (int dj = 0; dj < 5; ++dj)
      cw[(di + 1) * 7 + dj + 1][t] += w5[c * 25 + di * 5 + dj];
#pragma unroll
  for (int di = 0; di < 3; ++di)
#pragma unroll
    for (int dj = 0; dj < 3; ++dj)
      cw[(di + 2) * 7 + dj + 2][t] += w3[c * 9 + di * 3 + dj];
  cw[24][t] += 1.0f;
  float bias = b7[c] + b5[c] + b3[c];
  const float* base = hA + (size_t)b * TT * DD + DD + c;
  float* obase = hB + (size_t)b * TT * DD + DD + c;
  float acc[32];
#pragma unroll
  for (int j = 0; j < 32; ++j) acc[j] = bias;
  for (int di = 0; di < 7; ++di) {
    int ii = i + di - 3;
    if ((unsigned)ii >= 128u) continue;
    float win[38];
#pragma unroll
    for (int w = 0; w < 38; ++w) {
      int col = j0 - 3 + w;
      win[w] = ((unsigned)col < 128u) ? base[(size_t)(ii * 128 + col) * DD] : 0.f;
    }
#pragma unroll
    for (int dj = 0; dj < 7; ++dj) {
      float wv = cw[di * 7 + dj][t];
#pragma unroll
      for (int j = 0; j < 32; ++j) acc[j] += win[j + dj] * wv;
    }
  }
#pragma unroll
  for (int j = 0; j < 32; ++j) obase[(size_t)(i * 128 + j0 + j) * DD] = acc[j];
}

// ---------------------------------------------------------------- final head
__global__ __launch_bounds__(512) void k_final(
    float* __restrict__ out, const float* __restrict__ h,
    const float* __restrict__ g, const float* __restrict__ be,
    const float* __restrict__ cw, const float* __restrict__ cbias) {
  __shared__ float sm[16];
  int t = threadIdx.x;
  for (int b = 0; b < 2; ++b) {
    const float* row = h + (size_t)b * TT * DD;
    float x = row[t];
    float s = x;
    for (int o = 32; o; o >>= 1) s += __shfl_xor(s, o);
    if ((t & 63) == 0) sm[t >> 6] = s;
    __syncthreads();
    float mu = 0.f;
    for (int i = 0; i < 8; ++i) mu += sm[i];
    mu *= (1.f / 512.f);
    __syncthreads();
    float d = x - mu;
    s = d * d;
    for (int o = 32; o; o >>= 1) s += __shfl_xor(s, o);
    if ((t & 63) == 0) sm[t >> 6] = s;
    __syncthreads();
    float var = 0.f;
    for (int i = 0; i < 8; ++i) var += sm[i];
    var *= (1.f / 512.f);
    float rs = rsqrtf(var + 1e-5f);
    __syncthreads();
    float f = d * rs * g[t] + be[t];
    float p0 = f * cw[2 * t], p1 = f * cw[2 * t + 1];
    for (int o = 32; o; o >>= 1) {
      p0 += __shfl_xor(p0, o);
      p1 += __shfl_xor(p1, o);
    }
    if ((t & 63) == 0) {
      sm[t >> 6] = p0;
      sm[8 + (t >> 6)] = p1;
    }
    __syncthreads();
    if (t == 0) {
      float q0 = 0.f, q1 = 0.f;
      for (int i = 0; i < 8; ++i) {
        q0 += sm[i];
        q1 += sm[8 + i];
      }
      out[b * 2 + 0] = q0 + cbias[0];
      out[b * 2 + 1] = q1 + cbias[1];
    }
    __syncthreads();
  }
}

// ---------------------------------------------------------------- host side
static void run_attn(float* h, const float* lng, const float* lnb,
                     const float* wqkv, const float* wout, const float* bout,
                     const float* resw, float* xp, float* qkv, float* ql, float* kl,
                     float* a2, float* z0, float* z1, float* xz, float* yA, float* yB,
                     float* yC, float* bv, float* w2, float* red, float* Sbuf,
                     unsigned short* wth, unsigned short* wtl, hipStream_t stream) {
  k_zero_pad<<<BB * PADF, 256, 0, stream>>>(xp);
  k_ln_pad<<<(BB * TT + 3) / 4, 256, 0, stream>>>(xp, h, lng, lnb);
  k_cvt_wt<<<dim3(DD / 32, 1536 / 32), 256, 0, stream>>>(wqkv, wth, wtl, DD, 1536);
  k_gemm_mfma<1><<<dim3(BB * NPAD / 128, 1536 / 128), 256, 0, stream>>>(
      xp, wth, wtl, nullptr, qkv, BB * NPAD, DD, 1536, DD);
  k_landmarks<<<1024, 256, 0, stream>>>(ql, kl, qkv);
  float* pacc = Sbuf;
  float* pml = Sbuf + (size_t)A3KC * 4096 * 64;
  k_a3v<<<dim3(16, 16, A3KC), 256, 0, stream>>>(pacc, pml, ql, qkv);
  k_a3v_red<<<4096, 64, 0, stream>>>(bv, pacc, pml);
  k_sim2<<<dim3(4, 4, 16), 256, 0, stream>>>(a2, ql, kl);
  k_softmax256<<<1024, 256, 0, stream>>>(a2);
  k_pinv_sums<<<16, 256, 0, stream>>>(red, a2);
  k_pinv_scale<<<1, 256, 0, stream>>>(red);
  k_zinit<<<dim3(256, 16), 256, 0, stream>>>(z0, a2, red);
  float* zc = z0;
  float* zn = z1;
  for (int it = 0; it < 6; ++it) {
    k_bmm<<<dim3(4, 4, 16), 256, 0, stream>>>(a2, zc, xz, 1.f, 0.f, yA, -1.f, 7.f, 256);
    k_bmm<<<dim3(4, 4, 16), 256, 0, stream>>>(xz, yA, yB, -1.f, 15.f, nullptr, 0.f, 0.f, 256);
    k_bmm<<<dim3(4, 4, 16), 256, 0, stream>>>(xz, yB, yC, -1.f, 13.f, nullptr, 0.f, 0.f, 256);
    k_bmm<<<dim3(4, 4, 16), 256, 0, stream>>>(zc, yC, zn, 0.25f, 0.f, nullptr, 0.f, 0.f, 256);
    float* tmp = zc; zc = zn; zn = tmp;
  }
  k_bmm<<<dim3(1, 4, 16), 256, 0, stream>>>(zc, bv, w2, 1.f, 0.f, nullptr, 0.f, 0.f, 64);
  for (int bh0 = 0; bh0 < 16; bh0 += NBH) {
    k_score<<<dim3(NPAD / 64, 4, NBH), 256, 0, stream>>>(Sbuf, qkv, kl, bh0);
    k_pv<<<dim3(NPAD / 32, NBH), 256, 0, stream>>>(xp, Sbuf, qkv, w2, resw, bh0);
  }
  k_cvt_wt<<<dim3(DD / 32, DD / 32), 256, 0, stream>>>(wout, wth, wtl, DD, DD);
  k_gemm_mfma<2><<<dim3(129, 4, BB), 256, 0, stream>>>(xp, wth, wtl, bout, h, TT, DD,
                                                       DD, DD);
}

extern "C" void kernel_launch(void* const* d_in, const int* in_sizes, int n_in,
                              void* d_out, int out_size, void* d_ws, size_t ws_size,
                              hipStream_t stream) {
  const float* x        = (const float*)d_in[0];
  const float* w_feat   = (const float*)d_in[1];
  const float* b_feat   = (const float*)d_in[2];
  const float* cls_tok  = (const float*)d_in[3];
  const float* ln1_g    = (const float*)d_in[4];
  const float* ln1_b    = (const float*)d_in[5];
  const float* qkv1     = (const float*)d_in[6];
  const float* out1_w   = (const float*)d_in[7];
  const float* out1_b   = (const float*)d_in[8];
  const float* res1_w   = (const float*)d_in[9];
  const float* ppeg_w7  = (const float*)d_in[10];
  const float* ppeg_b7  = (const float*)d_in[11];
  const float* ppeg_w5  = (const float*)d_in[12];
  const float* ppeg_b5  = (const float*)d_in[13];
  const float* ppeg_w3  = (const float*)d_in[14];
  const float* ppeg_b3  = (const float*)d_in[15];
  const float* ln2_g    = (const float*)d_in[16];
  const float* ln2_b    = (const float*)d_in[17];
  const float* qkv2     = (const float*)d_in[18];
  const float* out2_w   = (const float*)d_in[19];
  const float* out2_b   = (const float*)d_in[20];
  const float* res2_w   = (const float*)d_in[21];
  const float* lnf_g    = (const float*)d_in[22];
  const float* lnf_b    = (const float*)d_in[23];
  const float* cls_w    = (const float*)d_in[24];
  const float* cls_b    = (const float*)d_in[25];

  float* ws = (float*)d_ws;
  size_t off = 0;
  float* hA  = ws + off; off += (size_t)BB * TT * DD;
  float* hB  = ws + off; off += (size_t)BB * TT * DD;
  float* xp  = ws + off; off += (size_t)BB * NPAD * DD;
  float* qkv = ws + off; off += (size_t)BB * NPAD * 3 * DD;
  float* ql  = ws + off; off += (size_t)BB * HH * 256 * 64;
  float* kl  = ws + off; off += (size_t)BB * HH * 256 * 64;
  float* a2  = ws + off; off += (size_t)16 * 65536;
  float* z0  = ws + off; off += (size_t)16 * 65536;
  float* z1  = ws + off; off += (size_t)16 * 65536;
  float* xz  = ws + off; off += (size_t)16 * 65536;
  float* yA  = ws + off; off += (size_t)16 * 65536;
  float* yB  = ws + off; off += (size_t)16 * 65536;
  float* yC  = ws + off; off += (size_t)16 * 65536;
  float* bv  = ws + off; off += (size_t)BB * HH * 256 * 64;
  float* w2  = ws + off; off += (size_t)BB * HH * 256 * 64;
  float* red = ws + off; off += 8448;
  unsigned short* wth = (unsigned short*)(ws + off); off += 393216;  // 786432 shorts
  unsigned short* wtl = (unsigned short*)(ws + off); off += 393216;

  // Stage 1: h = gelu(x @ w_feat + b_feat), prepend cls token
  k_set_cls<<<2, 512, 0, stream>>>(hA, cls_tok);
  k_cvt_wt<<<dim3(1024 / 32, DD / 32), 256, 0, stream>>>(w_feat, wth, wtl, 1024, DD);
  k_gemm_mfma<0><<<dim3(32768 / 128, DD / 128), 256, 0, stream>>>(
      x, wth, wtl, b_feat, hA, 32768, 1024, DD, 1024);
  // Attention 1 (residual in-place on hA; hB is dead -> scratch)
  run_attn(hA, ln1_g, ln1_b, qkv1, out1_w, out1_b, res1_w, xp, qkv, ql, kl, a2, z0, z1,
           xz, yA, yB, yC, bv, w2, red, hB, wth, wtl, stream);
  // PPEG: hB = ppeg(hA)
  k_copy_cls<<<2, 512, 0, stream>>>(hB, hA);
  k_ppeg<<<dim3(512, 4, 2), 128, 0, stream>>>(hB, hA, ppeg_w7, ppeg_b7, ppeg_w5, ppeg_b5,
                                              ppeg_w3, ppeg_b3);
  // Attention 2 (residual in-place on hB; hA is dead -> scratch)
  run_attn(hB, ln2_g, ln2_b, qkv2, out2_w, out2_b, res2_w, xp, qkv, ql, kl, a2, z0, z1,
           xz, yA, yB, yC, bv, w2, red, hA, wth, wtl, stream);
  // Final: LN(cls) @ cls_w + cls_b
  k_final<<<1, 512, 0, stream>>>((float*)d_out, hB, lnf_g, lnf_b, cls_w, cls_b);
}

// Round 6
// 3161.927 us; speedup vs baseline: 3.4035x; 1.4265x over previous
//
#include <hip/hip_runtime.h>
#include <cstdint>
#include <cstddef>

#define BB 2
#define TT 16385
#define NPAD 16640
#define DD 512
#define HH 8
#define DHH 64
#define MLAND 256
#define PADF 255
#define NBH 2
#define A3KC 26
#define A3CH 640

typedef __attribute__((ext_vector_type(8))) short bf16x8;
typedef __attribute__((ext_vector_type(4))) float f32x4;

__device__ __forceinline__ float dot4f(const float4 a, const float4 b) {
  return a.x * b.x + a.y * b.y + a.z * b.z + a.w * b.w;
}

__device__ __forceinline__ float gelu_f(float v) {
  float c = 0.7978845608028654f * (v + 0.044715f * v * v * v);
  return 0.5f * v * (1.0f + tanhf(c));
}

// split a,b into bf16 hi (packed) and bf16 lo (packed), RNE
__device__ __forceinline__ void split2(float a, float b, unsigned& hi, unsigned& lo) {
  unsigned ua = __float_as_uint(a);
  unsigned ha = (ua + 0x7FFFu + ((ua >> 16) & 1u)) & 0xFFFF0000u;
  unsigned ub = __float_as_uint(b);
  unsigned hb = (ub + 0x7FFFu + ((ub >> 16) & 1u)) & 0xFFFF0000u;
  float la = a - __uint_as_float(ha);
  float lb = b - __uint_as_float(hb);
  hi = (ha >> 16) | hb;
  unsigned ula = __float_as_uint(la);
  unsigned pa = (ula + 0x7FFFu + ((ula >> 16) & 1u)) >> 16;
  unsigned ulb = __float_as_uint(lb);
  unsigned pb = (ulb + 0x7FFFu + ((ulb >> 16) & 1u)) & 0xFFFF0000u;
  lo = pa | pb;
}

// pack two floats to 2xbf16 in a u32 (RNE)
__device__ __forceinline__ unsigned pk_bf16(float a, float b) {
  unsigned ua = __float_as_uint(a);
  ua = (ua + 0x7FFFu + ((ua >> 16) & 1u)) >> 16;
  unsigned ub = __float_as_uint(b);
  ub = (ub + 0x7FFFu + ((ub >> 16) & 1u)) & 0xFFFF0000u;
  return ua | ub;
}
__device__ __forceinline__ unsigned short bf16_1(float a) {
  unsigned ua = __float_as_uint(a);
  return (unsigned short)((ua + 0x7FFFu + ((ua >> 16) & 1u)) >> 16);
}

// ---------------------------------------------------------------- cls rows
__global__ void k_set_cls(float* __restrict__ h, const float* __restrict__ cls) {
  h[(size_t)blockIdx.x * TT * DD + threadIdx.x] = cls[threadIdx.x];
}
__global__ void k_copy_cls(float* __restrict__ dst, const float* __restrict__ src) {
  size_t o = (size_t)blockIdx.x * TT * DD + threadIdx.x;
  dst[o] = src[o];
}

// ------------------------------------------------ W[K][N] -> Wt hi/lo [N][K]
__global__ __launch_bounds__(256) void k_cvt_wt(
    const float* __restrict__ W, unsigned short* __restrict__ Wth,
    unsigned short* __restrict__ Wtl, int K, int N) {
  __shared__ float tile[32][33];
  int kb = blockIdx.x * 32, nb = blockIdx.y * 32;
  int t = threadIdx.x;
  int tr = t >> 3, tc4 = (t & 7) * 4;
  float4 v = *(const float4*)(W + (size_t)(kb + tr) * N + nb + tc4);
  tile[tr][tc4 + 0] = v.x;
  tile[tr][tc4 + 1] = v.y;
  tile[tr][tc4 + 2] = v.z;
  tile[tr][tc4 + 3] = v.w;
  __syncthreads();
  int n = nb + tr;
  ushort4 hs, ls;
  unsigned short hv[4], lv[4];
#pragma unroll
  for (int j = 0; j < 4; ++j) {
    float a = tile[tc4 + j][tr];
    unsigned ua = __float_as_uint(a);
    unsigned ha = (ua + 0x7FFFu + ((ua >> 16) & 1u)) & 0xFFFF0000u;
    float lo = a - __uint_as_float(ha);
    unsigned ul = __float_as_uint(lo);
    unsigned hl = (ul + 0x7FFFu + ((ul >> 16) & 1u)) >> 16;
    hv[j] = (unsigned short)(ha >> 16);
    lv[j] = (unsigned short)hl;
  }
  hs = make_ushort4(hv[0], hv[1], hv[2], hv[3]);
  ls = make_ushort4(lv[0], lv[1], lv[2], lv[3]);
  *(ushort4*)(Wth + (size_t)n * K + kb + tc4) = hs;
  *(ushort4*)(Wtl + (size_t)n * K + kb + tc4) = ls;
}

// ------------------------------------------ split-bf16 MFMA GEMM, 128x128 tile
// MODE 0: feat: C[r + r/16384 + 1] = gelu(A@W + bias)
// MODE 1: plain: C = A@W (N=1536)
// MODE 2: proj: h[b][r] += A[b*NPAD+255+r]@W + bias (grid.z = batch)
template <int MODE>
__global__ __launch_bounds__(256) void k_gemm_mfma(
    const float* __restrict__ A, const unsigned short* __restrict__ Wth,
    const unsigned short* __restrict__ Wtl, const float* __restrict__ bias,
    float* __restrict__ C, int M, int K, int N, int lda) {
  __shared__ short Ash[128][32];
  __shared__ short Asl[128][32];
  __shared__ short Bsh[128][32];
  __shared__ short Bsl[128][32];
  const int t = threadIdx.x;
  const int rb = blockIdx.x * 128, cb = blockIdx.y * 128;
  const float* Ab = A;
  float* Cb = C;
  if (MODE == 2) {
    int b = blockIdx.z;
    Ab = A + (size_t)b * NPAD * DD + (size_t)PADF * DD;
    Cb = C + (size_t)b * TT * DD;
  }
  const int lane = t & 63, wv = t >> 6;
  const int wr = wv >> 1, wc = wv & 1;
  const int fr = lane & 15, kg = lane >> 4;
  const int srow = t >> 1, skh = (t & 1) * 16;

  f32x4 acc[4][4];
  f32x4 zero4 = {0.f, 0.f, 0.f, 0.f};
#pragma unroll
  for (int i = 0; i < 4; ++i)
#pragma unroll
    for (int j = 0; j < 4; ++j) acc[i][j] = zero4;

  for (int k0 = 0; k0 < K; k0 += 32) {
    __syncthreads();
    {  // stage A with hi/lo split
      int grow = rb + srow;
      float4 f0 = {0, 0, 0, 0}, f1 = {0, 0, 0, 0}, f2 = {0, 0, 0, 0}, f3 = {0, 0, 0, 0};
      if (grow < M) {
        const float* p = Ab + (size_t)grow * lda + k0 + skh;
        f0 = *(const float4*)p;
        f1 = *(const float4*)(p + 4);
        f2 = *(const float4*)(p + 8);
        f3 = *(const float4*)(p + 12);
      }
      unsigned h0, h1, h2, h3, h4, h5, h6, h7;
      unsigned l0, l1, l2, l3, l4, l5, l6, l7;
      split2(f0.x, f0.y, h0, l0);
      split2(f0.z, f0.w, h1, l1);
      split2(f1.x, f1.y, h2, l2);
      split2(f1.z, f1.w, h3, l3);
      split2(f2.x, f2.y, h4, l4);
      split2(f2.z, f2.w, h5, l5);
      split2(f3.x, f3.y, h6, l6);
      split2(f3.z, f3.w, h7, l7);
      *(uint4*)&Ash[srow][skh] = make_uint4(h0, h1, h2, h3);
      *(uint4*)&Ash[srow][skh + 8] = make_uint4(h4, h5, h6, h7);
      *(uint4*)&Asl[srow][skh] = make_uint4(l0, l1, l2, l3);
      *(uint4*)&Asl[srow][skh + 8] = make_uint4(l4, l5, l6, l7);
    }
    {  // stage B (pre-split planes, row-major [N][K])
      int lc = t >> 1;
      const unsigned short* ph = Wth + (size_t)(cb + lc) * K + k0 + skh;
      const unsigned short* pl = Wtl + (size_t)(cb + lc) * K + k0 + skh;
      *(uint4*)&Bsh[lc][skh] = *(const uint4*)ph;
      *(uint4*)&Bsh[lc][skh + 8] = *(const uint4*)(ph + 8);
      *(uint4*)&Bsl[lc][skh] = *(const uint4*)pl;
      *(uint4*)&Bsl[lc][skh + 8] = *(const uint4*)(pl + 8);
    }
    __syncthreads();
    bf16x8 ah[4], al[4], bh[4], bl[4];
#pragma unroll
    for (int mf = 0; mf < 4; ++mf) {
      ah[mf] = *(const bf16x8*)&Ash[wr * 64 + mf * 16 + fr][kg * 8];
      al[mf] = *(const bf16x8*)&Asl[wr * 64 + mf * 16 + fr][kg * 8];
    }
#pragma unroll
    for (int nf = 0; nf < 4; ++nf) {
      bh[nf] = *(const bf16x8*)&Bsh[wc * 64 + nf * 16 + fr][kg * 8];
      bl[nf] = *(const bf16x8*)&Bsl[wc * 64 + nf * 16 + fr][kg * 8];
    }
#pragma unroll
    for (int mf = 0; mf < 4; ++mf)
#pragma unroll
      for (int nf = 0; nf < 4; ++nf) {
        acc[mf][nf] =
            __builtin_amdgcn_mfma_f32_16x16x32_bf16(ah[mf], bh[nf], acc[mf][nf], 0, 0, 0);
        acc[mf][nf] =
            __builtin_amdgcn_mfma_f32_16x16x32_bf16(al[mf], bh[nf], acc[mf][nf], 0, 0, 0);
        acc[mf][nf] =
            __builtin_amdgcn_mfma_f32_16x16x32_bf16(ah[mf], bl[nf], acc[mf][nf], 0, 0, 0);
      }
  }
  // epilogue: C frag layout col=lane&15, row=(lane>>4)*4+r
#pragma unroll
  for (int mf = 0; mf < 4; ++mf) {
#pragma unroll
    for (int r = 0; r < 4; ++r) {
      int row = rb + wr * 64 + mf * 16 + kg * 4 + r;
      if (MODE == 2 && row >= M) continue;
      size_t orow = (MODE == 0) ? (size_t)(row + (row >> 14) + 1) : (size_t)row;
#pragma unroll
      for (int nf = 0; nf < 4; ++nf) {
        int col = cb + wc * 64 + nf * 16 + fr;
        float v = acc[mf][nf][r];
        if (MODE == 0) {
          Cb[orow * DD + col] = gelu_f(v + bias[col]);
        } else if (MODE == 1) {
          Cb[orow * (size_t)N + col] = v;
        } else {
          float old = Cb[orow * DD + col];
          Cb[orow * DD + col] = old + v + bias[col];
        }
      }
    }
  }
}

// ---------------------------------------------------------------- LN + pad
__global__ __launch_bounds__(256) void k_ln_pad(
    float* __restrict__ xp, const float* __restrict__ h,
    const float* __restrict__ gam, const float* __restrict__ bet) {
  int w = threadIdx.x >> 6, lane = threadIdx.x & 63;
  int row = blockIdx.x * 4 + w;
  if (row >= BB * TT) return;
  int b = row / TT, i = row - b * TT;
  const float* src = h + (size_t)row * DD;
  float4 x0 = *(const float4*)(src + lane * 4);
  float4 x1 = *(const float4*)(src + 256 + lane * 4);
  float s = x0.x + x0.y + x0.z + x0.w + x1.x + x1.y + x1.z + x1.w;
  for (int o = 32; o; o >>= 1) s += __shfl_xor(s, o);
  float mu = s * (1.f / 512.f);
  float q = (x0.x - mu) * (x0.x - mu) + (x0.y - mu) * (x0.y - mu) +
            (x0.z - mu) * (x0.z - mu) + (x0.w - mu) * (x0.w - mu) +
            (x1.x - mu) * (x1.x - mu) + (x1.y - mu) * (x1.y - mu) +
            (x1.z - mu) * (x1.z - mu) + (x1.w - mu) * (x1.w - mu);
  for (int o = 32; o; o >>= 1) q += __shfl_xor(q, o);
  float rs = rsqrtf(q * (1.f / 512.f) + 1e-5f);
  float4 g0 = *(const float4*)(gam + lane * 4);
  float4 g1 = *(const float4*)(gam + 256 + lane * 4);
  float4 b0 = *(const float4*)(bet + lane * 4);
  float4 b1 = *(const float4*)(bet + 256 + lane * 4);
  float* dst = xp + ((size_t)b * NPAD + PADF + i) * DD;
  float4 o0, o1;
  o0.x = (x0.x - mu) * rs * g0.x + b0.x;
  o0.y = (x0.y - mu) * rs * g0.y + b0.y;
  o0.z = (x0.z - mu) * rs * g0.z + b0.z;
  o0.w = (x0.w - mu) * rs * g0.w + b0.w;
  o1.x = (x1.x - mu) * rs * g1.x + b1.x;
  o1.y = (x1.y - mu) * rs * g1.y + b1.y;
  o1.z = (x1.z - mu) * rs * g1.z + b1.z;
  o1.w = (x1.w - mu) * rs * g1.w + b1.w;
  *(float4*)(dst + lane * 4) = o0;
  *(float4*)(dst + 256 + lane * 4) = o1;
}

__global__ void k_zero_pad(float* __restrict__ xp) {
  int r = blockIdx.x;
  int b = r / PADF, j = r - b * PADF;
  float* p = xp + ((size_t)b * NPAD + j) * DD;
  p[threadIdx.x * 2] = 0.f;
  p[threadIdx.x * 2 + 1] = 0.f;
}

// ---------------------------------------------------------------- landmarks
__global__ __launch_bounds__(256) void k_landmarks(
    float* __restrict__ ql, float* __restrict__ kl, const float* __restrict__ qkv) {
  int t = threadIdx.x;
  int mi = t >> 6, d = t & 63;
  int blk = blockIdx.x;
  int bh = blk >> 6, mg = blk & 63;
  int b = bh >> 3, h = bh & 7;
  int m = mg * 4 + mi;
  const float* base = qkv + (size_t)b * NPAD * 1536 + h * 64 + d;
  float sq = 0.f, sk = 0.f;
  int t0 = m * 65;
  for (int j = 0; j < 65; ++j) {
    const float* p = base + (size_t)(t0 + j) * 1536;
    sq += p[0];
    sk += p[512];
  }
  ql[((size_t)bh * 256 + m) * 64 + d] = sq * (0.125f / 65.f);
  kl[((size_t)bh * 256 + m) * 64 + d] = sk * (1.f / 65.f);
}

// ---------------------------------------------------------------- sim2 = ql @ kl^T
__global__ __launch_bounds__(256) void k_sim2(
    float* __restrict__ sim, const float* __restrict__ ql, const float* __restrict__ kl) {
  __shared__ __align__(16) float Aq[64][68];
  __shared__ __align__(16) float Bk[64][68];
  int t = threadIdx.x;
  int tj = blockIdx.x, ti = blockIdx.y, bh = blockIdx.z;
  int r = t >> 2, cc = (t & 3) * 16;
  const float* ap = ql + ((size_t)bh * 256 + ti * 64 + r) * 64 + cc;
  const float* bp = kl + ((size_t)bh * 256 + tj * 64 + r) * 64 + cc;
#pragma unroll
  for (int i = 0; i < 16; i += 4) {
    *(float4*)&Aq[r][cc + i] = *(const float4*)(ap + i);
    *(float4*)&Bk[r][cc + i] = *(const float4*)(bp + i);
  }
  __syncthreads();
  int tx = t & 15, ty = t >> 4;
  float acc[4][4];
#pragma unroll
  for (int i = 0; i < 4; ++i)
#pragma unroll
    for (int j = 0; j < 4; ++j) acc[i][j] = 0.f;
  for (int d = 0; d < 64; d += 4) {
    float4 a4[4], b4[4];
#pragma unroll
    for (int ii = 0; ii < 4; ++ii) a4[ii] = *(float4*)&Aq[ty * 4 + ii][d];
#pragma unroll
    for (int jj = 0; jj < 4; ++jj) b4[jj] = *(float4*)&Bk[tx * 4 + jj][d];
#pragma unroll
    for (int ii = 0; ii < 4; ++ii)
#pragma unroll
      for (int jj = 0; jj < 4; ++jj) acc[ii][jj] += dot4f(a4[ii], b4[jj]);
  }
#pragma unroll
  for (int ii = 0; ii < 4; ++ii)
#pragma unroll
    for (int jj = 0; jj < 4; ++jj)
      sim[((size_t)bh * 256 + ti * 64 + ty * 4 + ii) * 256 + tj * 64 + tx * 4 + jj] =
          acc[ii][jj];
}

// ---------------------------------------------------------------- row softmax (len 256)
__global__ __launch_bounds__(256) void k_softmax256(float* __restrict__ a) {
  int w = threadIdx.x >> 6, lane = threadIdx.x & 63;
  size_t row = (size_t)blockIdx.x * 4 + w;
  float* p = a + row * 256 + lane * 4;
  float4 v = *(float4*)p;
  float m = fmaxf(fmaxf(v.x, v.y), fmaxf(v.z, v.w));
  for (int o = 32; o; o >>= 1) m = fmaxf(m, __shfl_xor(m, o));
  v.x = expf(v.x - m); v.y = expf(v.y - m);
  v.z = expf(v.z - m); v.w = expf(v.w - m);
  float s = v.x + v.y + v.z + v.w;
  for (int o = 32; o; o >>= 1) s += __shfl_xor(s, o);
  float inv = 1.f / s;
  v.x *= inv; v.y *= inv; v.z *= inv; v.w *= inv;
  *(float4*)p = v;
}

// ---------------------------------------------------------------- pinv helpers
__global__ void k_pinv_sums(float* __restrict__ red, const float* __restrict__ a2) {
  int bh = blockIdx.x, t = threadIdx.x;
  const float* Ab = a2 + (size_t)bh * 65536;
  float s = 0.f;
  for (int i = 0; i < 256; ++i) s += fabsf(Ab[(size_t)i * 256 + t]);
  red[bh * 256 + t] = s;
  float c = 0.f;
  const float* rp = Ab + (size_t)t * 256;
  for (int j = 0; j < 256; j += 4) {
    float4 v = *(const float4*)(rp + j);
    c += fabsf(v.x) + fabsf(v.y) + fabsf(v.z) + fabsf(v.w);
  }
  red[4096 + bh * 256 + t] = c;
}

__global__ void k_pinv_scale(float* __restrict__ red) {
  __shared__ float sm[8];
  int t = threadIdx.x;
  float m1 = 0.f, m2 = 0.f;
  for (int k = t; k < 4096; k += 256) {
    m1 = fmaxf(m1, red[k]);
    m2 = fmaxf(m2, red[4096 + k]);
  }
  for (int o = 32; o; o >>= 1) {
    m1 = fmaxf(m1, __shfl_xor(m1, o));
    m2 = fmaxf(m2, __shfl_xor(m2, o));
  }
  int w = t >> 6;
  if ((t & 63) == 0) { sm[w] = m1; sm[4 + w] = m2; }
  __syncthreads();
  if (t == 0) {
    float a = fmaxf(fmaxf(sm[0], sm[1]), fmaxf(sm[2], sm[3]));
    float b = fmaxf(fmaxf(sm[4], sm[5]), fmaxf(sm[6], sm[7]));
    red[8192] = 1.0f / (a * b);
  }
}

__global__ void k_zinit(float* __restrict__ z, const float* __restrict__ a2,
                        const float* __restrict__ red) {
  float s = red[8192];
  int i = blockIdx.x, bh = blockIdx.y, j = threadIdx.x;
  z[((size_t)bh * 256 + i) * 256 + j] = a2[((size_t)bh * 256 + j) * 256 + i] * s;
}

// batched (16) 256x256 @ 256xN; C1 = a1*(A@B) + d1*I ; optional C2
__global__ __launch_bounds__(256) void k_bmm(
    const float* __restrict__ A, const float* __restrict__ Bm,
    float* __restrict__ C1, float a1, float d1,
    float* __restrict__ C2, float a2c, float d2, int N) {
  __shared__ __align__(16) float As[16][64];
  __shared__ __align__(16) float Bs[16][64];
  int t = threadIdx.x;
  int bh = blockIdx.z;
  int i0 = blockIdx.y * 64, j0 = blockIdx.x * 64;
  const float* Ab = A + (size_t)bh * 65536;
  const float* Bb = Bm + (size_t)bh * 256 * N;
  float acc[4][4];
#pragma unroll
  for (int i = 0; i < 4; ++i)
#pragma unroll
    for (int j = 0; j < 4; ++j) acc[i][j] = 0.f;
  int tx = t & 15, ty = t >> 4;
  for (int k0 = 0; k0 < 256; k0 += 16) {
    __syncthreads();
    {
      int r = t >> 2, kl2 = (t & 3) * 4;
      float4 v = *(const float4*)(Ab + (size_t)(i0 + r) * 256 + k0 + kl2);
      As[kl2 + 0][r] = v.x; As[kl2 + 1][r] = v.y;
      As[kl2 + 2][r] = v.z; As[kl2 + 3][r] = v.w;
    }
    {
      int kr = t >> 4, nl = (t & 15) * 4;
      *(float4*)&Bs[kr][nl] = *(const float4*)(Bb + (size_t)(k0 + kr) * N + j0 + nl);
    }
    __syncthreads();
#pragma unroll
    for (int kk = 0; kk < 16; ++kk) {
      float4 a4 = *(float4*)&As[kk][ty * 4];
      float4 b4 = *(float4*)&Bs[kk][tx * 4];
      float av[4] = {a4.x, a4.y, a4.z, a4.w};
      float bv2[4] = {b4.x, b4.y, b4.z, b4.w};
#pragma unroll
      for (int i = 0; i < 4; ++i)
#pragma unroll
        for (int j = 0; j < 4; ++j) acc[i][j] += av[i] * bv2[j];
    }
  }
#pragma unroll
  for (int ii = 0; ii < 4; ++ii)
#pragma unroll
    for (int jj = 0; jj < 4; ++jj) {
      int i = i0 + ty * 4 + ii, j = j0 + tx * 4 + jj;
      float v = acc[ii][jj];
      size_t off = (size_t)bh * 256 * N + (size_t)i * N + j;
      C1[off] = a1 * v + ((i == j) ? d1 : 0.f);
      if (C2) C2[off] = a2c * v + ((i == j) ? d2 : 0.f);
    }
}

// -------------------------- a3 @ v : MFMA flash (no-max, split-K chunks)
// grid (16 bh, A3KC kc), 256 thr / 4 waves; wave w owns landmarks w*64..w*64+63.
// S^T = mfma(K-rows, Q-rows) -> exp in-register -> P in LDS -> out^T = mfma(V^T, P)
__global__ __launch_bounds__(256, 2) void k_a3v_mfma(
    float* __restrict__ pacc, float* __restrict__ pL,
    const float* __restrict__ ql, const float* __restrict__ qkv) {
  __shared__ short Ks[64][72];     // [key][dim]
  __shared__ short Vt[64][72];     // [dim][key]
  __shared__ short Ps[4][64][72];  // per wave [lm][key]
  const int t = threadIdx.x;
  const int bh = blockIdx.x;
  const int kc = blockIdx.y;
  const int b = bh >> 3, h = bh & 7;
  const int lane = t & 63, w = t >> 6;
  const int fr = lane & 15, kg = lane >> 4;

  // Q fragments in registers: lm = w*64 + nf*16 + fr, dims kw*32 + kg*8 + 0..7
  bf16x8 qf[4][2];
#pragma unroll
  for (int nf = 0; nf < 4; ++nf) {
    const float* qp = ql + ((size_t)bh * 256 + w * 64 + nf * 16 + fr) * 64 + kg * 8;
#pragma unroll
    for (int kw = 0; kw < 2; ++kw) {
      float4 a = *(const float4*)(qp + kw * 32);
      float4 c = *(const float4*)(qp + kw * 32 + 4);
      uint4 uu = make_uint4(pk_bf16(a.x, a.y), pk_bf16(a.z, a.w), pk_bf16(c.x, c.y),
                            pk_bf16(c.z, c.w));
      qf[nf][kw] = *(bf16x8*)&uu;
    }
  }
  f32x4 oacc[4][4];
  f32x4 zero4 = {0.f, 0.f, 0.f, 0.f};
#pragma unroll
  for (int i = 0; i < 4; ++i)
#pragma unroll
    for (int j = 0; j < 4; ++j) oacc[i][j] = zero4;
  float Lp[4] = {0.f, 0.f, 0.f, 0.f};

  const int skey = t >> 2, sd = (t & 3) * 16;
  const float* kbase = qkv + (size_t)b * NPAD * 1536 + 512 + h * 64 + sd;

  for (int it = 0; it < A3CH / 64; ++it) {
    int nt = kc * A3CH + it * 64;
    __syncthreads();
    {  // stage K [key][dim] and V transposed [dim][key]
      const float* kp = kbase + (size_t)(nt + skey) * 1536;
      float4 k0 = *(const float4*)kp;
      float4 k1 = *(const float4*)(kp + 4);
      float4 k2 = *(const float4*)(kp + 8);
      float4 k3 = *(const float4*)(kp + 12);
      const float* vp = kp + 512;
      float4 v0 = *(const float4*)vp;
      float4 v1 = *(const float4*)(vp + 4);
      float4 v2 = *(const float4*)(vp + 8);
      float4 v3 = *(const float4*)(vp + 12);
      *(uint4*)&Ks[skey][sd] = make_uint4(pk_bf16(k0.x, k0.y), pk_bf16(k0.z, k0.w),
                                          pk_bf16(k1.x, k1.y), pk_bf16(k1.z, k1.w));
      *(uint4*)&Ks[skey][sd + 8] = make_uint4(pk_bf16(k2.x, k2.y), pk_bf16(k2.z, k2.w),
                                              pk_bf16(k3.x, k3.y), pk_bf16(k3.z, k3.w));
      Vt[sd + 0][skey] = (short)bf16_1(v0.x);
      Vt[sd + 1][skey] = (short)bf16_1(v0.y);
      Vt[sd + 2][skey] = (short)bf16_1(v0.z);
      Vt[sd + 3][skey] = (short)bf16_1(v0.w);
      Vt[sd + 4][skey] = (short)bf16_1(v1.x);
      Vt[sd + 5][skey] = (short)bf16_1(v1.y);
      Vt[sd + 6][skey] = (short)bf16_1(v1.z);
      Vt[sd + 7][skey] = (short)bf16_1(v1.w);
      Vt[sd + 8][skey] = (short)bf16_1(v2.x);
      Vt[sd + 9][skey] = (short)bf16_1(v2.y);
      Vt[sd + 10][skey] = (short)bf16_1(v2.z);
      Vt[sd + 11][skey] = (short)bf16_1(v2.w);
      Vt[sd + 12][skey] = (short)bf16_1(v3.x);
      Vt[sd + 13][skey] = (short)bf16_1(v3.y);
      Vt[sd + 14][skey] = (short)bf16_1(v3.z);
      Vt[sd + 15][skey] = (short)bf16_1(v3.w);
    }
    __syncthreads();
    // S^T[key][lm] = K-rows x Q-rows
    f32x4 sacc[4][4];
#pragma unroll
    for (int i = 0; i < 4; ++i)
#pragma unroll
      for (int j = 0; j < 4; ++j) sacc[i][j] = zero4;
#pragma unroll
    for (int kw = 0; kw < 2; ++kw) {
      bf16x8 kf[4];
#pragma unroll
      for (int mf = 0; mf < 4; ++mf)
        kf[mf] = *(const bf16x8*)&Ks[mf * 16 + fr][kw * 32 + kg * 8];
#pragma unroll
      for (int mf = 0; mf < 4; ++mf)
#pragma unroll
        for (int nf = 0; nf < 4; ++nf)
          sacc[mf][nf] = __builtin_amdgcn_mfma_f32_16x16x32_bf16(kf[mf], qf[nf][kw],
                                                                 sacc[mf][nf], 0, 0, 0);
    }
    // exp (no max: |s| << 1), accumulate L, pack P to LDS [lm][key]
#pragma unroll
    for (int mf = 0; mf < 4; ++mf)
#pragma unroll
      for (int nf = 0; nf < 4; ++nf) {
        f32x4 s = sacc[mf][nf];
        float p0 = __expf(s[0]);
        float p1 = __expf(s[1]);
        float p2 = __expf(s[2]);
        float p3 = __expf(s[3]);
        Lp[nf] += (p0 + p1) + (p2 + p3);
        uint2 pw = make_uint2(pk_bf16(p0, p1), pk_bf16(p2, p3));
        *(uint2*)&Ps[w][nf * 16 + fr][mf * 16 + kg * 4] = pw;
      }
    __syncthreads();
    // out^T[dim][lm] += V^T-rows x P-rows
#pragma unroll
    for (int kw = 0; kw < 2; ++kw) {
      bf16x8 vf[4], pf[4];
#pragma unroll
      for (int mf = 0; mf < 4; ++mf)
        vf[mf] = *(const bf16x8*)&Vt[mf * 16 + fr][kw * 32 + kg * 8];
#pragma unroll
      for (int nf = 0; nf < 4; ++nf)
        pf[nf] = *(const bf16x8*)&Ps[w][nf * 16 + fr][kw * 32 + kg * 8];
#pragma unroll
      for (int mf = 0; mf < 4; ++mf)
#pragma unroll
        for (int nf = 0; nf < 4; ++nf)
          oacc[mf][nf] = __builtin_amdgcn_mfma_f32_16x16x32_bf16(vf[mf], pf[nf],
                                                                 oacc[mf][nf], 0, 0, 0);
    }
  }
  // epilogue: lane holds out^T col lm = nf*16+fr, rows dim = mf*16+kg*4+r
  size_t obase = ((size_t)kc * 16 + bh) * 256;
#pragma unroll
  for (int mf = 0; mf < 4; ++mf)
#pragma unroll
    for (int nf = 0; nf < 4; ++nf) {
      int lm = w * 64 + nf * 16 + fr;
      *(f32x4*)(pacc + (obase + lm) * 64 + mf * 16 + kg * 4) = oacc[mf][nf];
    }
#pragma unroll
  for (int nf = 0; nf < 4; ++nf) {
    Lp[nf] += __shfl_xor(Lp[nf], 16);
    Lp[nf] += __shfl_xor(Lp[nf], 32);
  }
  if (lane < 16) {
#pragma unroll
    for (int nf = 0; nf < 4; ++nf)
      pL[obase + w * 64 + nf * 16 + lane] = Lp[nf];
  }
}

// combine A3KC plain partials -> bv[bh*256+m][64]; grid 4096, block 64
__global__ __launch_bounds__(64) void k_a3v_red(
    float* __restrict__ bv, const float* __restrict__ pacc,
    const float* __restrict__ pL) {
  int row = blockIdx.x;
  int d = threadIdx.x;
  float A = 0.f, L = 0.f;
#pragma unroll
  for (int c = 0; c < A3KC; ++c) {
    size_t pr = (size_t)c * 4096 + row;
    A += pacc[pr * 64 + d];
    L += pL[pr];
  }
  bv[(size_t)row * 64 + d] = A / L;
}

// ---------------------------------------------------------------- scores S
__global__ __launch_bounds__(256) void k_score(
    float* __restrict__ S, const float* __restrict__ qkv,
    const float* __restrict__ kl, int bh0) {
  __shared__ __align__(16) float Aq[64][68];
  __shared__ __align__(16) float Bk[64][68];
  int t = threadIdx.x;
  int ti = blockIdx.x, tj = blockIdx.y;
  int bhl = blockIdx.z;
  int bh = bh0 + bhl;
  int b = bh >> 3, h = bh & 7;
  int r = t >> 2, cc = (t & 3) * 16;
  {
    const float* ap = qkv + ((size_t)b * NPAD + ti * 64 + r) * 1536 + h * 64 + cc;
    const float* bp = kl + ((size_t)bh * 256 + tj * 64 + r) * 64 + cc;
#pragma unroll
    for (int i = 0; i < 16; i += 4) {
      float4 qa = *(const float4*)(ap + i);
      qa.x *= 0.125f; qa.y *= 0.125f; qa.z *= 0.125f; qa.w *= 0.125f;
      *(float4*)&Aq[r][cc + i] = qa;
      *(float4*)&Bk[r][cc + i] = *(const float4*)(bp + i);
    }
  }
  __syncthreads();
  int tx = t & 15, ty = t >> 4;
  float acc[4][4];
#pragma unroll
  for (int i = 0; i < 4; ++i)
#pragma unroll
    for (int j = 0; j < 4; ++j) acc[i][j] = 0.f;
  for (int d = 0; d < 64; d += 4) {
    float4 a4[4], b4[4];
#pragma unroll
    for (int ii = 0; ii < 4; ++ii) a4[ii] = *(float4*)&Aq[ty * 4 + ii][d];
#pragma unroll
    for (int jj = 0; jj < 4; ++jj) b4[jj] = *(float4*)&Bk[tx * 4 + jj][d];
#pragma unroll
    for (int ii = 0; ii < 4; ++ii)
#pragma unroll
      for (int jj = 0; jj < 4; ++jj) acc[ii][jj] += dot4f(a4[ii], b4[jj]);
  }
#pragma unroll
  for (int ii = 0; ii < 4; ++ii) {
    float4 v;
    v.x = acc[ii][0]; v.y = acc[ii][1]; v.z = acc[ii][2]; v.w = acc[ii][3];
    *(float4*)(S + ((size_t)bhl * NPAD + ti * 64 + ty * 4 + ii) * 256 + tj * 64 +
               tx * 4) = v;
  }
}

// --------------------------- out = softmax(S) @ w2 + conv(v), 32 tokens/block
__global__ __launch_bounds__(256) void k_pv(
    float* __restrict__ attout, const float* __restrict__ S,
    const float* __restrict__ qkv, const float* __restrict__ w2,
    const float* __restrict__ resw, int bh0) {
  __shared__ __align__(16) float pT[256][36];
  __shared__ __align__(16) float cS[64][68];
  __shared__ float w33[33];
  int t = threadIdx.x;
  int tb = blockIdx.x;
  int bhl = blockIdx.y;
  int bh = bh0 + bhl;
  int b = bh >> 3, h = bh & 7;
  int n0 = tb * 32;
  if (t < 33) w33[t] = resw[h * 33 + t];
  {
    int r = t >> 3;
    int seg = (t & 7) * 32;
    const float* sp = S + ((size_t)bhl * NPAD + n0 + r) * 256 + seg;
#pragma unroll
    for (int k = 0; k < 32; k += 4) {
      float4 v = *(const float4*)(sp + k);
      pT[seg + k + 0][r] = v.x;
      pT[seg + k + 1][r] = v.y;
      pT[seg + k + 2][r] = v.z;
      pT[seg + k + 3][r] = v.w;
    }
  }
  __syncthreads();
  {
    int tt = t >> 3, g = t & 7;
    float v[32];
    float m = -INFINITY;
#pragma unroll
    for (int k = 0; k < 32; ++k) {
      v[k] = pT[g + 8 * k][tt];
      m = fmaxf(m, v[k]);
    }
    for (int o = 4; o; o >>= 1) m = fmaxf(m, __shfl_xor(m, o));
    float s = 0.f;
#pragma unroll
    for (int k = 0; k < 32; ++k) {
      v[k] = expf(v[k] - m);
      s += v[k];
    }
    for (int o = 4; o; o >>= 1) s += __shfl_xor(s, o);
    float inv = 1.f / s;
#pragma unroll
    for (int k = 0; k < 32; ++k) pT[g + 8 * k][tt] = v[k] * inv;
  }
  int ty = t >> 5, tx = t & 31;
  float acc[4][2] = {{0.f, 0.f}, {0.f, 0.f}, {0.f, 0.f}, {0.f, 0.f}};
  for (int cb = 0; cb < 4; ++cb) {
    __syncthreads();
    {
      int r = t >> 2, cc = (t & 3) * 16;
      const float* p = w2 + ((size_t)bh * 256 + cb * 64 + r) * 64 + cc;
#pragma unroll
      for (int i = 0; i < 16; i += 4)
        *(float4*)&cS[r][cc + i] = *(const float4*)(p + i);
    }
    __syncthreads();
#pragma unroll 4
    for (int l = 0; l < 64; ++l) {
      float4 p4 = *(float4*)&pT[cb * 64 + l][ty * 4];
      float2 wv = *(float2*)&cS[l][tx * 2];
      acc[0][0] += p4.x * wv.x; acc[0][1] += p4.x * wv.y;
      acc[1][0] += p4.y * wv.x; acc[1][1] += p4.y * wv.y;
      acc[2][0] += p4.z * wv.x; acc[2][1] += p4.z * wv.y;
      acc[3][0] += p4.w * wv.x; acc[3][1] += p4.w * wv.y;
    }
  }
  __syncthreads();
  {
    int r = t >> 2, cc = (t & 3) * 16;
    int seq = n0 - 16 + r;
    if (seq >= 0 && seq < NPAD) {
      const float* p = qkv + ((size_t)b * NPAD + seq) * 1536 + 1024 + h * 64 + cc;
#pragma unroll
      for (int i = 0; i < 16; i += 4)
        *(float4*)&cS[r][cc + i] = *(const float4*)(p + i);
    } else {
      float4 z = {0, 0, 0, 0};
#pragma unroll
      for (int i = 0; i < 16; i += 4) *(float4*)&cS[r][cc + i] = z;
    }
  }
  __syncthreads();
  float cacc[4][2] = {{0.f, 0.f}, {0.f, 0.f}, {0.f, 0.f}, {0.f, 0.f}};
  for (int k = 0; k < 33; ++k) {
    float wv = w33[k];
#pragma unroll
    for (int i = 0; i < 4; ++i) {
      float2 v2 = *(float2*)&cS[4 * ty + i + k][tx * 2];
      cacc[i][0] += wv * v2.x;
      cacc[i][1] += wv * v2.y;
    }
  }
#pragma unroll
  for (int i = 0; i < 4; ++i) {
    float2 o;
    o.x = acc[i][0] + cacc[i][0];
    o.y = acc[i][1] + cacc[i][1];
    *(float2*)(attout + ((size_t)b * NPAD + n0 + 4 * ty + i) * DD + h * 64 + tx * 2) = o;
  }
}

// ---------------------------------------------------------------- PPEG (combined 7x7)
__global__ __launch_bounds__(128) void k_ppeg(
    float* __restrict__ hB, const float* __restrict__ hA,
    const float* __restrict__ w7, const float* __restrict__ b7,
    const float* __restrict__ w5, const float* __restrict__ b5,
    const float* __restrict__ w3, const float* __restrict__ b3) {
  __shared__ float cw[49][128];
  int t = threadIdx.x;
  int i = blockIdx.x >> 2;
  int j0 = (blockIdx.x & 3) * 32;
  int cg = blockIdx.y, b = blockIdx.z;
  int c = cg * 128 + t;
#pragma unroll
  for (int k = 0; k < 49; ++k) cw[k][t] = w7[c * 49 + k];
#pragma unroll
  for (int di = 0; di < 5; ++di)
#pragma unroll
    for (int dj = 0; dj < 5; ++dj)
      cw[(di + 1) * 7 + dj + 1][t] += w5[c * 25 + di * 5 + dj];
#pragma unroll
  for (int di = 0; di < 3; ++di)
#pragma unroll
    for (int dj = 0; dj < 3; ++dj)
      cw[(di + 2) * 7 + dj + 2][t] += w3[c * 9 + di * 3 + dj];
  cw[24][t] += 1.0f;
  float bias = b7[c] + b5[c] + b3[c];
  const float* base = hA + (size_t)b * TT * DD + DD + c;
  float* obase = hB + (size_t)b * TT * DD + DD + c;
  float acc[32];
#pragma unroll
  for (int j = 0; j < 32; ++j) acc[j] = bias;
  for (int di = 0; di < 7; ++di) {
    int ii = i + di - 3;
    if ((unsigned)ii >= 128u) continue;
    float win[38];
#pragma unroll
    for (int w = 0; w < 38; ++w) {
      int col = j0 - 3 + w;
      win[w] = ((unsigned)col < 128u) ? base[(size_t)(ii * 128 + col) * DD] : 0.f;
    }
#pragma unroll
    for (int dj = 0; dj < 7; ++dj) {
      float wv = cw[di * 7 + dj][t];
#pragma unroll
      for (int j = 0; j < 32; ++j) acc[j] += win[j + dj] * wv;
    }
  }
#pragma unroll
  for (int j = 0; j < 32; ++j) obase[(size_t)(i * 128 + j0 + j) * DD] = acc[j];
}

// ---------------------------------------------------------------- final head
__global__ __launch_bounds__(512) void k_final(
    float* __restrict__ out, const float* __restrict__ h,
    const float* __restrict__ g, const float* __restrict__ be,
    const float* __restrict__ cw, const float* __restrict__ cbias) {
  __shared__ float sm[16];
  int t = threadIdx.x;
  for (int b = 0; b < 2; ++b) {
    const float* row = h + (size_t)b * TT * DD;
    float x = row[t];
    float s = x;
    for (int o = 32; o; o >>= 1) s += __shfl_xor(s, o);
    if ((t & 63) == 0) sm[t >> 6] = s;
    __syncthreads();
    float mu = 0.f;
    for (int i = 0; i < 8; ++i) mu += sm[i];
    mu *= (1.f / 512.f);
    __syncthreads();
    float d = x - mu;
    s = d * d;
    for (int o = 32; o; o >>= 1) s += __shfl_xor(s, o);
    if ((t & 63) == 0) sm[t >> 6] = s;
    __syncthreads();
    float var = 0.f;
    for (int i = 0; i < 8; ++i) var += sm[i];
    var *= (1.f / 512.f);
    float rs = rsqrtf(var + 1e-5f);
    __syncthreads();
    float f = d * rs * g[t] + be[t];
    float p0 = f * cw[2 * t], p1 = f * cw[2 * t + 1];
    for (int o = 32; o; o >>= 1) {
      p0 += __shfl_xor(p0, o);
      p1 += __shfl_xor(p1, o);
    }
    if ((t & 63) == 0) {
      sm[t >> 6] = p0;
      sm[8 + (t >> 6)] = p1;
    }
    __syncthreads();
    if (t == 0) {
      float q0 = 0.f, q1 = 0.f;
      for (int i = 0; i < 8; ++i) {
        q0 += sm[i];
        q1 += sm[8 + i];
      }
      out[b * 2 + 0] = q0 + cbias[0];
      out[b * 2 + 1] = q1 + cbias[1];
    }
    __syncthreads();
  }
}

// ---------------------------------------------------------------- host side
static void run_attn(float* h, const float* lng, const float* lnb,
                     const float* wqkv, const float* wout, const float* bout,
                     const float* resw, float* xp, float* qkv, float* ql, float* kl,
                     float* a2, float* z0, float* z1, float* xz, float* yA, float* yB,
                     float* yC, float* bv, float* w2, float* red, float* Sbuf,
                     unsigned short* wth, unsigned short* wtl, hipStream_t stream) {
  k_zero_pad<<<BB * PADF, 256, 0, stream>>>(xp);
  k_ln_pad<<<(BB * TT + 3) / 4, 256, 0, stream>>>(xp, h, lng, lnb);
  k_cvt_wt<<<dim3(DD / 32, 1536 / 32), 256, 0, stream>>>(wqkv, wth, wtl, DD, 1536);
  k_gemm_mfma<1><<<dim3(BB * NPAD / 128, 1536 / 128), 256, 0, stream>>>(
      xp, wth, wtl, nullptr, qkv, BB * NPAD, DD, 1536, DD);
  k_landmarks<<<1024, 256, 0, stream>>>(ql, kl, qkv);
  float* pacc = Sbuf;
  float* pL = Sbuf + (size_t)A3KC * 4096 * 64;
  k_a3v_mfma<<<dim3(16, A3KC), 256, 0, stream>>>(pacc, pL, ql, qkv);
  k_a3v_red<<<4096, 64, 0, stream>>>(bv, pacc, pL);
  k_sim2<<<dim3(4, 4, 16), 256, 0, stream>>>(a2, ql, kl);
  k_softmax256<<<1024, 256, 0, stream>>>(a2);
  k_pinv_sums<<<16, 256, 0, stream>>>(red, a2);
  k_pinv_scale<<<1, 256, 0, stream>>>(red);
  k_zinit<<<dim3(256, 16), 256, 0, stream>>>(z0, a2, red);
  float* zc = z0;
  float* zn = z1;
  for (int it = 0; it < 6; ++it) {
    k_bmm<<<dim3(4, 4, 16), 256, 0, stream>>>(a2, zc, xz, 1.f, 0.f, yA, -1.f, 7.f, 256);
    k_bmm<<<dim3(4, 4, 16), 256, 0, stream>>>(xz, yA, yB, -1.f, 15.f, nullptr, 0.f, 0.f, 256);
    k_bmm<<<dim3(4, 4, 16), 256, 0, stream>>>(xz, yB, yC, -1.f, 13.f, nullptr, 0.f, 0.f, 256);
    k_bmm<<<dim3(4, 4, 16), 256, 0, stream>>>(zc, yC, zn, 0.25f, 0.f, nullptr, 0.f, 0.f, 256);
    float* tmp = zc; zc = zn; zn = tmp;
  }
  k_bmm<<<dim3(1, 4, 16), 256, 0, stream>>>(zc, bv, w2, 1.f, 0.f, nullptr, 0.f, 0.f, 64);
  for (int bh0 = 0; bh0 < 16; bh0 += NBH) {
    k_score<<<dim3(NPAD / 64, 4, NBH), 256, 0, stream>>>(Sbuf, qkv, kl, bh0);
    k_pv<<<dim3(NPAD / 32, NBH), 256, 0, stream>>>(xp, Sbuf, qkv, w2, resw, bh0);
  }
  k_cvt_wt<<<dim3(DD / 32, DD / 32), 256, 0, stream>>>(wout, wth, wtl, DD, DD);
  k_gemm_mfma<2><<<dim3(129, 4, BB), 256, 0, stream>>>(xp, wth, wtl, bout, h, TT, DD,
                                                       DD, DD);
}

extern "C" void kernel_launch(void* const* d_in, const int* in_sizes, int n_in,
                              void* d_out, int out_size, void* d_ws, size_t ws_size,
                              hipStream_t stream) {
  const float* x        = (const float*)d_in[0];
  const float* w_feat   = (const float*)d_in[1];
  const float* b_feat   = (const float*)d_in[2];
  const float* cls_tok  = (const float*)d_in[3];
  const float* ln1_g    = (const float*)d_in[4];
  const float* ln1_b    = (const float*)d_in[5];
  const float* qkv1     = (const float*)d_in[6];
  const float* out1_w   = (const float*)d_in[7];
  const float* out1_b   = (const float*)d_in[8];
  const float* res1_w   = (const float*)d_in[9];
  const float* ppeg_w7  = (const float*)d_in[10];
  const float* ppeg_b7  = (const float*)d_in[11];
  const float* ppeg_w5  = (const float*)d_in[12];
  const float* ppeg_b5  = (const float*)d_in[13];
  const float* ppeg_w3  = (const float*)d_in[14];
  const float* ppeg_b3  = (const float*)d_in[15];
  const float* ln2_g    = (const float*)d_in[16];
  const float* ln2_b    = (const float*)d_in[17];
  const float* qkv2     = (const float*)d_in[18];
  const float* out2_w   = (const float*)d_in[19];
  const float* out2_b   = (const float*)d_in[20];
  const float* res2_w   = (const float*)d_in[21];
  const float* lnf_g    = (const float*)d_in[22];
  const float* lnf_b    = (const float*)d_in[23];
  const float* cls_w    = (const float*)d_in[24];
  const float* cls_b    = (const float*)d_in[25];

  float* ws = (float*)d_ws;
  size_t off = 0;
  float* hA  = ws + off; off += (size_t)BB * TT * DD;
  float* hB  = ws + off; off += (size_t)BB * TT * DD;
  float* xp  = ws + off; off += (size_t)BB * NPAD * DD;
  float* qkv = ws + off; off += (size_t)BB * NPAD * 3 * DD;
  float* ql  = ws + off; off += (size_t)BB * HH * 256 * 64;
  float* kl  = ws + off; off += (size_t)BB * HH * 256 * 64;
  float* a2  = ws + off; off += (size_t)16 * 65536;
  float* z0  = ws + off; off += (size_t)16 * 65536;
  float* z1  = ws + off; off += (size_t)16 * 65536;
  float* xz  = ws + off; off += (size_t)16 * 65536;
  float* yA  = ws + off; off += (size_t)16 * 65536;
  float* yB  = ws + off; off += (size_t)16 * 65536;
  float* yC  = ws + off; off += (size_t)16 * 65536;
  float* bv  = ws + off; off += (size_t)BB * HH * 256 * 64;
  float* w2  = ws + off; off += (size_t)BB * HH * 256 * 64;
  float* red = ws + off; off += 8448;
  unsigned short* wth = (unsigned short*)(ws + off); off += 393216;  // 786432 shorts
  unsigned short* wtl = (unsigned short*)(ws + off); off += 393216;

  // Stage 1: h = gelu(x @ w_feat + b_feat), prepend cls token
  k_set_cls<<<2, 512, 0, stream>>>(hA, cls_tok);
  k_cvt_wt<<<dim3(1024 / 32, DD / 32), 256, 0, stream>>>(w_feat, wth, wtl, 1024, DD);
  k_gemm_mfma<0><<<dim3(32768 / 128, DD / 128), 256, 0, stream>>>(
      x, wth, wtl, b_feat, hA, 32768, 1024, DD, 1024);
  // Attention 1 (residual in-place on hA; hB is dead -> scratch)
  run_attn(hA, ln1_g, ln1_b, qkv1, out1_w, out1_b, res1_w, xp, qkv, ql, kl, a2, z0, z1,
           xz, yA, yB, yC, bv, w2, red, hB, wth, wtl, stream);
  // PPEG: hB = ppeg(hA)
  k_copy_cls<<<2, 512, 0, stream>>>(hB, hA);
  k_ppeg<<<dim3(512, 4, 2), 128, 0, stream>>>(hB, hA, ppeg_w7, ppeg_b7, ppeg_w5, ppeg_b5,
                                              ppeg_w3, ppeg_b3);
  // Attention 2 (residual in-place on hB; hA is dead -> scratch)
  run_attn(hB, ln2_g, ln2_b, qkv2, out2_w, out2_b, res2_w, xp, qkv, ql, kl, a2, z0, z1,
           xz, yA, yB, yC, bv, w2, red, hA, wth, wtl, stream);
  // Final: LN(cls) @ cls_w + cls_b
  k_final<<<1, 512, 0, stream>>>((float*)d_out, hB, lnf_g, lnf_b, cls_w, cls_b);
}

// Round 7
// 2152.295 us; speedup vs baseline: 5.0001x; 1.4691x over previous
//
#include <hip/hip_runtime.h>
#include <cstdint>
#include <cstddef>

#define BB 2
#define TT 16385
#define NPAD 16640
#define DD 512
#define HH 8
#define DHH 64
#define MLAND 256
#define PADF 255
#define A3KC 26
#define A3CH 640

typedef __attribute__((ext_vector_type(8))) short bf16x8;
typedef __attribute__((ext_vector_type(4))) float f32x4;

__device__ __forceinline__ float gelu_f(float v) {
  float c = 0.7978845608028654f * (v + 0.044715f * v * v * v);
  return 0.5f * v * (1.0f + tanhf(c));
}

// split a,b into bf16 hi (packed) and bf16 lo (packed), RNE
__device__ __forceinline__ void split2(float a, float b, unsigned& hi, unsigned& lo) {
  unsigned ua = __float_as_uint(a);
  unsigned ha = (ua + 0x7FFFu + ((ua >> 16) & 1u)) & 0xFFFF0000u;
  unsigned ub = __float_as_uint(b);
  unsigned hb = (ub + 0x7FFFu + ((ub >> 16) & 1u)) & 0xFFFF0000u;
  float la = a - __uint_as_float(ha);
  float lb = b - __uint_as_float(hb);
  hi = (ha >> 16) | hb;
  unsigned ula = __float_as_uint(la);
  unsigned pa = (ula + 0x7FFFu + ((ula >> 16) & 1u)) >> 16;
  unsigned ulb = __float_as_uint(lb);
  unsigned pb = (ulb + 0x7FFFu + ((ulb >> 16) & 1u)) & 0xFFFF0000u;
  lo = pa | pb;
}

__device__ __forceinline__ unsigned pk_bf16(float a, float b) {
  unsigned ua = __float_as_uint(a);
  ua = (ua + 0x7FFFu + ((ua >> 16) & 1u)) >> 16;
  unsigned ub = __float_as_uint(b);
  ub = (ub + 0x7FFFu + ((ub >> 16) & 1u)) & 0xFFFF0000u;
  return ua | ub;
}
__device__ __forceinline__ unsigned short bf16_1(float a) {
  unsigned ua = __float_as_uint(a);
  return (unsigned short)((ua + 0x7FFFu + ((ua >> 16) & 1u)) >> 16);
}

// ---------------------------------------------------------------- cls rows
__global__ void k_set_cls(float* __restrict__ h, const float* __restrict__ cls) {
  h[(size_t)blockIdx.x * TT * DD + threadIdx.x] = cls[threadIdx.x];
}
__global__ void k_copy_cls(float* __restrict__ dst, const float* __restrict__ src) {
  size_t o = (size_t)blockIdx.x * TT * DD + threadIdx.x;
  dst[o] = src[o];
}

// ------------------------------------------------ W[K][N] -> Wt hi/lo [N][K]
__global__ __launch_bounds__(256) void k_cvt_wt(
    const float* __restrict__ W, unsigned short* __restrict__ Wth,
    unsigned short* __restrict__ Wtl, int K, int N) {
  __shared__ float tile[32][33];
  int kb = blockIdx.x * 32, nb = blockIdx.y * 32;
  int t = threadIdx.x;
  int tr = t >> 3, tc4 = (t & 7) * 4;
  float4 v = *(const float4*)(W + (size_t)(kb + tr) * N + nb + tc4);
  tile[tr][tc4 + 0] = v.x;
  tile[tr][tc4 + 1] = v.y;
  tile[tr][tc4 + 2] = v.z;
  tile[tr][tc4 + 3] = v.w;
  __syncthreads();
  int n = nb + tr;
  unsigned short hv[4], lv[4];
#pragma unroll
  for (int j = 0; j < 4; ++j) {
    float a = tile[tc4 + j][tr];
    unsigned ua = __float_as_uint(a);
    unsigned ha = (ua + 0x7FFFu + ((ua >> 16) & 1u)) & 0xFFFF0000u;
    float lo = a - __uint_as_float(ha);
    unsigned ul = __float_as_uint(lo);
    unsigned hl = (ul + 0x7FFFu + ((ul >> 16) & 1u)) >> 16;
    hv[j] = (unsigned short)(ha >> 16);
    lv[j] = (unsigned short)hl;
  }
  ushort4 hs = make_ushort4(hv[0], hv[1], hv[2], hv[3]);
  ushort4 ls = make_ushort4(lv[0], lv[1], lv[2], lv[3]);
  *(ushort4*)(Wth + (size_t)n * K + kb + tc4) = hs;
  *(ushort4*)(Wtl + (size_t)n * K + kb + tc4) = ls;
}

// ------------------------------------------ split-bf16 MFMA GEMM, 128x128 tile
// MODE 0: feat; MODE 1: plain (qkv); MODE 2: proj (+residual, grid.z=batch)
// LDS planes padded [128][40] (80B = 20 banks) to kill the 8-way frag-read conflict
template <int MODE>
__global__ __launch_bounds__(256) void k_gemm_mfma(
    const float* __restrict__ A, const unsigned short* __restrict__ Wth,
    const unsigned short* __restrict__ Wtl, const float* __restrict__ bias,
    float* __restrict__ C, int M, int K, int N, int lda) {
  __shared__ short Ash[128][40];
  __shared__ short Asl[128][40];
  __shared__ short Bsh[128][40];
  __shared__ short Bsl[128][40];
  const int t = threadIdx.x;
  const int rb = blockIdx.x * 128, cb = blockIdx.y * 128;
  const float* Ab = A;
  float* Cb = C;
  if (MODE == 2) {
    int b = blockIdx.z;
    Ab = A + (size_t)b * NPAD * DD + (size_t)PADF * DD;
    Cb = C + (size_t)b * TT * DD;
  }
  const int lane = t & 63, wv = t >> 6;
  const int wr = wv >> 1, wc = wv & 1;
  const int fr = lane & 15, kg = lane >> 4;
  const int srow = t >> 1, skh = (t & 1) * 16;

  f32x4 acc[4][4];
  f32x4 zero4 = {0.f, 0.f, 0.f, 0.f};
#pragma unroll
  for (int i = 0; i < 4; ++i)
#pragma unroll
    for (int j = 0; j < 4; ++j) acc[i][j] = zero4;

  for (int k0 = 0; k0 < K; k0 += 32) {
    __syncthreads();
    {  // stage A with hi/lo split
      int grow = rb + srow;
      float4 f0 = {0, 0, 0, 0}, f1 = {0, 0, 0, 0}, f2 = {0, 0, 0, 0}, f3 = {0, 0, 0, 0};
      if (grow < M) {
        const float* p = Ab + (size_t)grow * lda + k0 + skh;
        f0 = *(const float4*)p;
        f1 = *(const float4*)(p + 4);
        f2 = *(const float4*)(p + 8);
        f3 = *(const float4*)(p + 12);
      }
      unsigned h0, h1, h2, h3, h4, h5, h6, h7;
      unsigned l0, l1, l2, l3, l4, l5, l6, l7;
      split2(f0.x, f0.y, h0, l0);
      split2(f0.z, f0.w, h1, l1);
      split2(f1.x, f1.y, h2, l2);
      split2(f1.z, f1.w, h3, l3);
      split2(f2.x, f2.y, h4, l4);
      split2(f2.z, f2.w, h5, l5);
      split2(f3.x, f3.y, h6, l6);
      split2(f3.z, f3.w, h7, l7);
      *(uint4*)&Ash[srow][skh] = make_uint4(h0, h1, h2, h3);
      *(uint4*)&Ash[srow][skh + 8] = make_uint4(h4, h5, h6, h7);
      *(uint4*)&Asl[srow][skh] = make_uint4(l0, l1, l2, l3);
      *(uint4*)&Asl[srow][skh + 8] = make_uint4(l4, l5, l6, l7);
    }
    {  // stage B (pre-split planes, row-major [N][K])
      int lc = t >> 1;
      const unsigned short* ph = Wth + (size_t)(cb + lc) * K + k0 + skh;
      const unsigned short* pl = Wtl + (size_t)(cb + lc) * K + k0 + skh;
      *(uint4*)&Bsh[lc][skh] = *(const uint4*)ph;
      *(uint4*)&Bsh[lc][skh + 8] = *(const uint4*)(ph + 8);
      *(uint4*)&Bsl[lc][skh] = *(const uint4*)pl;
      *(uint4*)&Bsl[lc][skh + 8] = *(const uint4*)(pl + 8);
    }
    __syncthreads();
    bf16x8 ah[4], al[4], bh[4], bl[4];
#pragma unroll
    for (int mf = 0; mf < 4; ++mf) {
      ah[mf] = *(const bf16x8*)&Ash[wr * 64 + mf * 16 + fr][kg * 8];
      al[mf] = *(const bf16x8*)&Asl[wr * 64 + mf * 16 + fr][kg * 8];
    }
#pragma unroll
    for (int nf = 0; nf < 4; ++nf) {
      bh[nf] = *(const bf16x8*)&Bsh[wc * 64 + nf * 16 + fr][kg * 8];
      bl[nf] = *(const bf16x8*)&Bsl[wc * 64 + nf * 16 + fr][kg * 8];
    }
#pragma unroll
    for (int mf = 0; mf < 4; ++mf)
#pragma unroll
      for (int nf = 0; nf < 4; ++nf) {
        acc[mf][nf] =
            __builtin_amdgcn_mfma_f32_16x16x32_bf16(ah[mf], bh[nf], acc[mf][nf], 0, 0, 0);
        acc[mf][nf] =
            __builtin_amdgcn_mfma_f32_16x16x32_bf16(al[mf], bh[nf], acc[mf][nf], 0, 0, 0);
        acc[mf][nf] =
            __builtin_amdgcn_mfma_f32_16x16x32_bf16(ah[mf], bl[nf], acc[mf][nf], 0, 0, 0);
      }
  }
#pragma unroll
  for (int mf = 0; mf < 4; ++mf) {
#pragma unroll
    for (int r = 0; r < 4; ++r) {
      int row = rb + wr * 64 + mf * 16 + kg * 4 + r;
      if (MODE == 2 && row >= M) continue;
      size_t orow = (MODE == 0) ? (size_t)(row + (row >> 14) + 1) : (size_t)row;
#pragma unroll
      for (int nf = 0; nf < 4; ++nf) {
        int col = cb + wc * 64 + nf * 16 + fr;
        float v = acc[mf][nf][r];
        if (MODE == 0) {
          Cb[orow * DD + col] = gelu_f(v + bias[col]);
        } else if (MODE == 1) {
          Cb[orow * (size_t)N + col] = v;
        } else {
          float old = Cb[orow * DD + col];
          Cb[orow * DD + col] = old + v + bias[col];
        }
      }
    }
  }
}

// ---------------------------------------------------------------- LN + pad
__global__ __launch_bounds__(256) void k_ln_pad(
    float* __restrict__ xp, const float* __restrict__ h,
    const float* __restrict__ gam, const float* __restrict__ bet) {
  int w = threadIdx.x >> 6, lane = threadIdx.x & 63;
  int row = blockIdx.x * 4 + w;
  if (row >= BB * TT) return;
  int b = row / TT, i = row - b * TT;
  const float* src = h + (size_t)row * DD;
  float4 x0 = *(const float4*)(src + lane * 4);
  float4 x1 = *(const float4*)(src + 256 + lane * 4);
  float s = x0.x + x0.y + x0.z + x0.w + x1.x + x1.y + x1.z + x1.w;
  for (int o = 32; o; o >>= 1) s += __shfl_xor(s, o);
  float mu = s * (1.f / 512.f);
  float q = (x0.x - mu) * (x0.x - mu) + (x0.y - mu) * (x0.y - mu) +
            (x0.z - mu) * (x0.z - mu) + (x0.w - mu) * (x0.w - mu) +
            (x1.x - mu) * (x1.x - mu) + (x1.y - mu) * (x1.y - mu) +
            (x1.z - mu) * (x1.z - mu) + (x1.w - mu) * (x1.w - mu);
  for (int o = 32; o; o >>= 1) q += __shfl_xor(q, o);
  float rs = rsqrtf(q * (1.f / 512.f) + 1e-5f);
  float4 g0 = *(const float4*)(gam + lane * 4);
  float4 g1 = *(const float4*)(gam + 256 + lane * 4);
  float4 b0 = *(const float4*)(bet + lane * 4);
  float4 b1 = *(const float4*)(bet + 256 + lane * 4);
  float* dst = xp + ((size_t)b * NPAD + PADF + i) * DD;
  float4 o0, o1;
  o0.x = (x0.x - mu) * rs * g0.x + b0.x;
  o0.y = (x0.y - mu) * rs * g0.y + b0.y;
  o0.z = (x0.z - mu) * rs * g0.z + b0.z;
  o0.w = (x0.w - mu) * rs * g0.w + b0.w;
  o1.x = (x1.x - mu) * rs * g1.x + b1.x;
  o1.y = (x1.y - mu) * rs * g1.y + b1.y;
  o1.z = (x1.z - mu) * rs * g1.z + b1.z;
  o1.w = (x1.w - mu) * rs * g1.w + b1.w;
  *(float4*)(dst + lane * 4) = o0;
  *(float4*)(dst + 256 + lane * 4) = o1;
}

__global__ void k_zero_pad(float* __restrict__ xp) {
  int r = blockIdx.x;
  int b = r / PADF, j = r - b * PADF;
  float* p = xp + ((size_t)b * NPAD + j) * DD;
  p[threadIdx.x * 2] = 0.f;
  p[threadIdx.x * 2 + 1] = 0.f;
}

// ---------------------------------------------------------------- landmarks
__global__ __launch_bounds__(256) void k_landmarks(
    float* __restrict__ ql, float* __restrict__ kl, const float* __restrict__ qkv) {
  int t = threadIdx.x;
  int mi = t >> 6, d = t & 63;
  int blk = blockIdx.x;
  int bh = blk >> 6, mg = blk & 63;
  int b = bh >> 3, h = bh & 7;
  int m = mg * 4 + mi;
  const float* base = qkv + (size_t)b * NPAD * 1536 + h * 64 + d;
  float sq = 0.f, sk = 0.f;
  int t0 = m * 65;
  for (int j = 0; j < 65; ++j) {
    const float* p = base + (size_t)(t0 + j) * 1536;
    sq += p[0];
    sk += p[512];
  }
  ql[((size_t)bh * 256 + m) * 64 + d] = sq * (0.125f / 65.f);
  kl[((size_t)bh * 256 + m) * 64 + d] = sk * (1.f / 65.f);
}

// ---------------------------------------------------------------- sim2 = ql @ kl^T
__global__ __launch_bounds__(256) void k_sim2(
    float* __restrict__ sim, const float* __restrict__ ql, const float* __restrict__ kl) {
  __shared__ __align__(16) float Aq[64][68];
  __shared__ __align__(16) float Bk[64][68];
  int t = threadIdx.x;
  int tj = blockIdx.x, ti = blockIdx.y, bh = blockIdx.z;
  int r = t >> 2, cc = (t & 3) * 16;
  const float* ap = ql + ((size_t)bh * 256 + ti * 64 + r) * 64 + cc;
  const float* bp = kl + ((size_t)bh * 256 + tj * 64 + r) * 64 + cc;
#pragma unroll
  for (int i = 0; i < 16; i += 4) {
    *(float4*)&Aq[r][cc + i] = *(const float4*)(ap + i);
    *(float4*)&Bk[r][cc + i] = *(const float4*)(bp + i);
  }
  __syncthreads();
  int tx = t & 15, ty = t >> 4;
  float acc[4][4];
#pragma unroll
  for (int i = 0; i < 4; ++i)
#pragma unroll
    for (int j = 0; j < 4; ++j) acc[i][j] = 0.f;
  for (int d = 0; d < 64; d += 4) {
    float4 a4[4], b4[4];
#pragma unroll
    for (int ii = 0; ii < 4; ++ii) a4[ii] = *(float4*)&Aq[ty * 4 + ii][d];
#pragma unroll
    for (int jj = 0; jj < 4; ++jj) b4[jj] = *(float4*)&Bk[tx * 4 + jj][d];
#pragma unroll
    for (int ii = 0; ii < 4; ++ii)
#pragma unroll
      for (int jj = 0; jj < 4; ++jj)
        acc[ii][jj] += a4[ii].x * b4[jj].x + a4[ii].y * b4[jj].y + a4[ii].z * b4[jj].z +
                       a4[ii].w * b4[jj].w;
  }
#pragma unroll
  for (int ii = 0; ii < 4; ++ii)
#pragma unroll
    for (int jj = 0; jj < 4; ++jj)
      sim[((size_t)bh * 256 + ti * 64 + ty * 4 + ii) * 256 + tj * 64 + tx * 4 + jj] =
          acc[ii][jj];
}

// ---------------------------------------------------------------- row softmax (len 256)
__global__ __launch_bounds__(256) void k_softmax256(float* __restrict__ a) {
  int w = threadIdx.x >> 6, lane = threadIdx.x & 63;
  size_t row = (size_t)blockIdx.x * 4 + w;
  float* p = a + row * 256 + lane * 4;
  float4 v = *(float4*)p;
  float m = fmaxf(fmaxf(v.x, v.y), fmaxf(v.z, v.w));
  for (int o = 32; o; o >>= 1) m = fmaxf(m, __shfl_xor(m, o));
  v.x = expf(v.x - m); v.y = expf(v.y - m);
  v.z = expf(v.z - m); v.w = expf(v.w - m);
  float s = v.x + v.y + v.z + v.w;
  for (int o = 32; o; o >>= 1) s += __shfl_xor(s, o);
  float inv = 1.f / s;
  v.x *= inv; v.y *= inv; v.z *= inv; v.w *= inv;
  *(float4*)p = v;
}

// ---------------------------------------------------------------- pinv helpers
__global__ void k_pinv_sums(float* __restrict__ red, const float* __restrict__ a2) {
  int bh = blockIdx.x, t = threadIdx.x;
  const float* Ab = a2 + (size_t)bh * 65536;
  float s = 0.f;
  for (int i = 0; i < 256; ++i) s += fabsf(Ab[(size_t)i * 256 + t]);
  red[bh * 256 + t] = s;
  float c = 0.f;
  const float* rp = Ab + (size_t)t * 256;
  for (int j = 0; j < 256; j += 4) {
    float4 v = *(const float4*)(rp + j);
    c += fabsf(v.x) + fabsf(v.y) + fabsf(v.z) + fabsf(v.w);
  }
  red[4096 + bh * 256 + t] = c;
}

__global__ void k_pinv_scale(float* __restrict__ red) {
  __shared__ float sm[8];
  int t = threadIdx.x;
  float m1 = 0.f, m2 = 0.f;
  for (int k = t; k < 4096; k += 256) {
    m1 = fmaxf(m1, red[k]);
    m2 = fmaxf(m2, red[4096 + k]);
  }
  for (int o = 32; o; o >>= 1) {
    m1 = fmaxf(m1, __shfl_xor(m1, o));
    m2 = fmaxf(m2, __shfl_xor(m2, o));
  }
  int w = t >> 6;
  if ((t & 63) == 0) { sm[w] = m1; sm[4 + w] = m2; }
  __syncthreads();
  if (t == 0) {
    float a = fmaxf(fmaxf(sm[0], sm[1]), fmaxf(sm[2], sm[3]));
    float b = fmaxf(fmaxf(sm[4], sm[5]), fmaxf(sm[6], sm[7]));
    red[8192] = 1.0f / (a * b);
  }
}

__global__ void k_zinit(float* __restrict__ z, const float* __restrict__ a2,
                        const float* __restrict__ red) {
  float s = red[8192];
  int i = blockIdx.x, bh = blockIdx.y, j = threadIdx.x;
  z[((size_t)bh * 256 + i) * 256 + j] = a2[((size_t)bh * 256 + j) * 256 + i] * s;
}

// ------------------- batched 256x256 @ 256xN MFMA; C1 = a1*(A@B)+d1*I; opt C2
// 64x64 tile per block, 4 waves each owning 16 output cols
__global__ __launch_bounds__(256) void k_bmm_mfma(
    const float* __restrict__ A, const float* __restrict__ Bm,
    float* __restrict__ C1, float a1, float d1,
    float* __restrict__ C2, float a2c, float d2, int N) {
  __shared__ short Ash[64][40];
  __shared__ short Asl[64][40];
  __shared__ short Bsh[64][40];
  __shared__ short Bsl[64][40];
  const int t = threadIdx.x;
  const int bh = blockIdx.z;
  const int i0 = blockIdx.y * 64, j0 = blockIdx.x * 64;
  const float* Ab = A + (size_t)bh * 65536;
  const float* Bb = Bm + (size_t)bh * 256 * N;
  const int lane = t & 63, w = t >> 6;
  const int fr = lane & 15, kg = lane >> 4;
  f32x4 acc[4];
  f32x4 zero4 = {0.f, 0.f, 0.f, 0.f};
#pragma unroll
  for (int i = 0; i < 4; ++i) acc[i] = zero4;

  const int ar = t >> 2, akseg = (t & 3) * 8;
  for (int k0 = 0; k0 < 256; k0 += 32) {
    __syncthreads();
    {  // stage A rows (split)
      const float* p = Ab + (size_t)(i0 + ar) * 256 + k0 + akseg;
      float4 f0 = *(const float4*)p;
      float4 f1 = *(const float4*)(p + 4);
      unsigned h0, h1, h2, h3, l0, l1, l2, l3;
      split2(f0.x, f0.y, h0, l0);
      split2(f0.z, f0.w, h1, l1);
      split2(f1.x, f1.y, h2, l2);
      split2(f1.z, f1.w, h3, l3);
      *(uint2*)&Ash[ar][akseg] = make_uint2(h0, h1);
      *(uint2*)&Ash[ar][akseg + 4] = make_uint2(h2, h3);
      *(uint2*)&Asl[ar][akseg] = make_uint2(l0, l1);
      *(uint2*)&Asl[ar][akseg + 4] = make_uint2(l2, l3);
    }
    {  // stage B transposed (split): Bsh[j_local][k_local]
#pragma unroll
      for (int pass = 0; pass < 2; ++pass) {
        int kr = pass * 16 + (t >> 4);
        int jseg = (t & 15) * 4;
        const float* p = Bb + (size_t)(k0 + kr) * N + j0 + jseg;
        float4 f = *(const float4*)p;
        float fv[4] = {f.x, f.y, f.z, f.w};
#pragma unroll
        for (int c = 0; c < 4; ++c) {
          unsigned ua = __float_as_uint(fv[c]);
          unsigned ha = (ua + 0x7FFFu + ((ua >> 16) & 1u)) & 0xFFFF0000u;
          float lo = fv[c] - __uint_as_float(ha);
          Bsh[jseg + c][kr] = (short)(ha >> 16);
          Bsl[jseg + c][kr] = (short)bf16_1(lo);
        }
      }
    }
    __syncthreads();
    bf16x8 bhf = *(const bf16x8*)&Bsh[w * 16 + fr][kg * 8];
    bf16x8 blf = *(const bf16x8*)&Bsl[w * 16 + fr][kg * 8];
#pragma unroll
    for (int mf = 0; mf < 4; ++mf) {
      bf16x8 ah = *(const bf16x8*)&Ash[mf * 16 + fr][kg * 8];
      bf16x8 al = *(const bf16x8*)&Asl[mf * 16 + fr][kg * 8];
      acc[mf] = __builtin_amdgcn_mfma_f32_16x16x32_bf16(ah, bhf, acc[mf], 0, 0, 0);
      acc[mf] = __builtin_amdgcn_mfma_f32_16x16x32_bf16(al, bhf, acc[mf], 0, 0, 0);
      acc[mf] = __builtin_amdgcn_mfma_f32_16x16x32_bf16(ah, blf, acc[mf], 0, 0, 0);
    }
  }
  int j = j0 + w * 16 + fr;
#pragma unroll
  for (int mf = 0; mf < 4; ++mf) {
#pragma unroll
    for (int rr = 0; rr < 4; ++rr) {
      int i = i0 + mf * 16 + kg * 4 + rr;
      float v = acc[mf][rr];
      size_t off = (size_t)bh * 256 * N + (size_t)i * N + j;
      C1[off] = a1 * v + ((i == j) ? d1 : 0.f);
      if (C2) C2[off] = a2c * v + ((i == j) ? d2 : 0.f);
    }
  }
}

// -------------------------- a3 @ v : MFMA flash (no-max, split-K chunks)
__global__ __launch_bounds__(256, 2) void k_a3v_mfma(
    float* __restrict__ pacc, float* __restrict__ pL,
    const float* __restrict__ ql, const float* __restrict__ qkv) {
  __shared__ short Ks[64][72];
  __shared__ short Vt[64][72];
  __shared__ short Ps[4][64][72];
  const int t = threadIdx.x;
  const int bh = blockIdx.x;
  const int kc = blockIdx.y;
  const int b = bh >> 3, h = bh & 7;
  const int lane = t & 63, w = t >> 6;
  const int fr = lane & 15, kg = lane >> 4;

  bf16x8 qf[4][2];
#pragma unroll
  for (int nf = 0; nf < 4; ++nf) {
    const float* qp = ql + ((size_t)bh * 256 + w * 64 + nf * 16 + fr) * 64 + kg * 8;
#pragma unroll
    for (int kw = 0; kw < 2; ++kw) {
      float4 a = *(const float4*)(qp + kw * 32);
      float4 c = *(const float4*)(qp + kw * 32 + 4);
      uint4 uu = make_uint4(pk_bf16(a.x, a.y), pk_bf16(a.z, a.w), pk_bf16(c.x, c.y),
                            pk_bf16(c.z, c.w));
      qf[nf][kw] = *(bf16x8*)&uu;
    }
  }
  f32x4 oacc[4][4];
  f32x4 zero4 = {0.f, 0.f, 0.f, 0.f};
#pragma unroll
  for (int i = 0; i < 4; ++i)
#pragma unroll
    for (int j = 0; j < 4; ++j) oacc[i][j] = zero4;
  float Lp[4] = {0.f, 0.f, 0.f, 0.f};

  const int skey = t >> 2, sd = (t & 3) * 16;
  const float* kbase = qkv + (size_t)b * NPAD * 1536 + 512 + h * 64 + sd;

  for (int it = 0; it < A3CH / 64; ++it) {
    int nt = kc * A3CH + it * 64;
    __syncthreads();
    {
      const float* kp = kbase + (size_t)(nt + skey) * 1536;
      float4 k0 = *(const float4*)kp;
      float4 k1 = *(const float4*)(kp + 4);
      float4 k2 = *(const float4*)(kp + 8);
      float4 k3 = *(const float4*)(kp + 12);
      const float* vp = kp + 512;
      float4 v0 = *(const float4*)vp;
      float4 v1 = *(const float4*)(vp + 4);
      float4 v2 = *(const float4*)(vp + 8);
      float4 v3 = *(const float4*)(vp + 12);
      *(uint4*)&Ks[skey][sd] = make_uint4(pk_bf16(k0.x, k0.y), pk_bf16(k0.z, k0.w),
                                          pk_bf16(k1.x, k1.y), pk_bf16(k1.z, k1.w));
      *(uint4*)&Ks[skey][sd + 8] = make_uint4(pk_bf16(k2.x, k2.y), pk_bf16(k2.z, k2.w),
                                              pk_bf16(k3.x, k3.y), pk_bf16(k3.z, k3.w));
      Vt[sd + 0][skey] = (short)bf16_1(v0.x);
      Vt[sd + 1][skey] = (short)bf16_1(v0.y);
      Vt[sd + 2][skey] = (short)bf16_1(v0.z);
      Vt[sd + 3][skey] = (short)bf16_1(v0.w);
      Vt[sd + 4][skey] = (short)bf16_1(v1.x);
      Vt[sd + 5][skey] = (short)bf16_1(v1.y);
      Vt[sd + 6][skey] = (short)bf16_1(v1.z);
      Vt[sd + 7][skey] = (short)bf16_1(v1.w);
      Vt[sd + 8][skey] = (short)bf16_1(v2.x);
      Vt[sd + 9][skey] = (short)bf16_1(v2.y);
      Vt[sd + 10][skey] = (short)bf16_1(v2.z);
      Vt[sd + 11][skey] = (short)bf16_1(v2.w);
      Vt[sd + 12][skey] = (short)bf16_1(v3.x);
      Vt[sd + 13][skey] = (short)bf16_1(v3.y);
      Vt[sd + 14][skey] = (short)bf16_1(v3.z);
      Vt[sd + 15][skey] = (short)bf16_1(v3.w);
    }
    __syncthreads();
    f32x4 sacc[4][4];
#pragma unroll
    for (int i = 0; i < 4; ++i)
#pragma unroll
      for (int j = 0; j < 4; ++j) sacc[i][j] = zero4;
#pragma unroll
    for (int kw = 0; kw < 2; ++kw) {
      bf16x8 kf[4];
#pragma unroll
      for (int mf = 0; mf < 4; ++mf)
        kf[mf] = *(const bf16x8*)&Ks[mf * 16 + fr][kw * 32 + kg * 8];
#pragma unroll
      for (int mf = 0; mf < 4; ++mf)
#pragma unroll
        for (int nf = 0; nf < 4; ++nf)
          sacc[mf][nf] = __builtin_amdgcn_mfma_f32_16x16x32_bf16(kf[mf], qf[nf][kw],
                                                                 sacc[mf][nf], 0, 0, 0);
    }
#pragma unroll
    for (int mf = 0; mf < 4; ++mf)
#pragma unroll
      for (int nf = 0; nf < 4; ++nf) {
        f32x4 s = sacc[mf][nf];
        float p0 = __expf(s[0]);
        float p1 = __expf(s[1]);
        float p2 = __expf(s[2]);
        float p3 = __expf(s[3]);
        Lp[nf] += (p0 + p1) + (p2 + p3);
        uint2 pw = make_uint2(pk_bf16(p0, p1), pk_bf16(p2, p3));
        *(uint2*)&Ps[w][nf * 16 + fr][mf * 16 + kg * 4] = pw;
      }
    __syncthreads();
#pragma unroll
    for (int kw = 0; kw < 2; ++kw) {
      bf16x8 vf[4], pf[4];
#pragma unroll
      for (int mf = 0; mf < 4; ++mf)
        vf[mf] = *(const bf16x8*)&Vt[mf * 16 + fr][kw * 32 + kg * 8];
#pragma unroll
      for (int nf = 0; nf < 4; ++nf)
        pf[nf] = *(const bf16x8*)&Ps[w][nf * 16 + fr][kw * 32 + kg * 8];
#pragma unroll
      for (int mf = 0; mf < 4; ++mf)
#pragma unroll
        for (int nf = 0; nf < 4; ++nf)
          oacc[mf][nf] = __builtin_amdgcn_mfma_f32_16x16x32_bf16(vf[mf], pf[nf],
                                                                 oacc[mf][nf], 0, 0, 0);
    }
  }
  size_t obase = ((size_t)kc * 16 + bh) * 256;
#pragma unroll
  for (int mf = 0; mf < 4; ++mf)
#pragma unroll
    for (int nf = 0; nf < 4; ++nf) {
      int lm = w * 64 + nf * 16 + fr;
      *(f32x4*)(pacc + (obase + lm) * 64 + mf * 16 + kg * 4) = oacc[mf][nf];
    }
#pragma unroll
  for (int nf = 0; nf < 4; ++nf) {
    Lp[nf] += __shfl_xor(Lp[nf], 16);
    Lp[nf] += __shfl_xor(Lp[nf], 32);
  }
  if (lane < 16) {
#pragma unroll
    for (int nf = 0; nf < 4; ++nf)
      pL[obase + w * 64 + nf * 16 + lane] = Lp[nf];
  }
}

__global__ __launch_bounds__(64) void k_a3v_red(
    float* __restrict__ bv, const float* __restrict__ pacc,
    const float* __restrict__ pL) {
  int row = blockIdx.x;
  int d = threadIdx.x;
  float A = 0.f, L = 0.f;
#pragma unroll
  for (int c = 0; c < A3KC; ++c) {
    size_t pr = (size_t)c * 4096 + row;
    A += pacc[pr * 64 + d];
    L += pL[pr];
  }
  bv[(size_t)row * 64 + d] = A / L;
}

// ------------- fused sim1: attout = softmax(0.125*q @ kl^T) @ w2 (MFMA, no-max)
// grid (65 token-tiles, 16 bh); 4 waves, wave w owns tokens tile*256 + w*64..+63
__global__ __launch_bounds__(256, 2) void k_att1(
    float* __restrict__ attout, const float* __restrict__ qkv,
    const float* __restrict__ kl, const float* __restrict__ w2) {
  __shared__ short KLs[64][72];     // [lm_local][dim]
  __shared__ short W2t[64][72];     // [dim][lm_local]
  __shared__ short Ps[4][64][72];   // per wave [token][lm_local]
  const int t = threadIdx.x;
  const int tile = blockIdx.x, bh = blockIdx.y;
  const int b = bh >> 3, h = bh & 7;
  const int lane = t & 63, w = t >> 6;
  const int fr = lane & 15, kg = lane >> 4;
  const int n0 = tile * 256;

  // Q fragments (scaled 0.125): token = n0 + w*64 + nf*16 + fr
  bf16x8 qf[4][2];
#pragma unroll
  for (int nf = 0; nf < 4; ++nf) {
    const float* qp =
        qkv + ((size_t)b * NPAD + n0 + w * 64 + nf * 16 + fr) * 1536 + h * 64 + kg * 8;
#pragma unroll
    for (int kw = 0; kw < 2; ++kw) {
      float4 a = *(const float4*)(qp + kw * 32);
      float4 c = *(const float4*)(qp + kw * 32 + 4);
      uint4 uu = make_uint4(pk_bf16(a.x * 0.125f, a.y * 0.125f),
                            pk_bf16(a.z * 0.125f, a.w * 0.125f),
                            pk_bf16(c.x * 0.125f, c.y * 0.125f),
                            pk_bf16(c.z * 0.125f, c.w * 0.125f));
      qf[nf][kw] = *(bf16x8*)&uu;
    }
  }
  f32x4 oacc[4][4];
  f32x4 zero4 = {0.f, 0.f, 0.f, 0.f};
#pragma unroll
  for (int i = 0; i < 4; ++i)
#pragma unroll
    for (int j = 0; j < 4; ++j) oacc[i][j] = zero4;
  float Lp[4] = {0.f, 0.f, 0.f, 0.f};

  const int sr = t >> 2, sc = (t & 3) * 16;
  for (int cb = 0; cb < 4; ++cb) {
    __syncthreads();
    {  // stage KL chunk [lm][dim] and W2^T chunk [dim][lm]
      const float* kp = kl + ((size_t)bh * 256 + cb * 64 + sr) * 64 + sc;
      float4 k0 = *(const float4*)kp;
      float4 k1 = *(const float4*)(kp + 4);
      float4 k2 = *(const float4*)(kp + 8);
      float4 k3 = *(const float4*)(kp + 12);
      *(uint4*)&KLs[sr][sc] = make_uint4(pk_bf16(k0.x, k0.y), pk_bf16(k0.z, k0.w),
                                         pk_bf16(k1.x, k1.y), pk_bf16(k1.z, k1.w));
      *(uint4*)&KLs[sr][sc + 8] = make_uint4(pk_bf16(k2.x, k2.y), pk_bf16(k2.z, k2.w),
                                             pk_bf16(k3.x, k3.y), pk_bf16(k3.z, k3.w));
      const float* wp = w2 + ((size_t)bh * 256 + cb * 64 + sr) * 64 + sc;
      float4 v0 = *(const float4*)wp;
      float4 v1 = *(const float4*)(wp + 4);
      float4 v2 = *(const float4*)(wp + 8);
      float4 v3 = *(const float4*)(wp + 12);
      W2t[sc + 0][sr] = (short)bf16_1(v0.x);
      W2t[sc + 1][sr] = (short)bf16_1(v0.y);
      W2t[sc + 2][sr] = (short)bf16_1(v0.z);
      W2t[sc + 3][sr] = (short)bf16_1(v0.w);
      W2t[sc + 4][sr] = (short)bf16_1(v1.x);
      W2t[sc + 5][sr] = (short)bf16_1(v1.y);
      W2t[sc + 6][sr] = (short)bf16_1(v1.z);
      W2t[sc + 7][sr] = (short)bf16_1(v1.w);
      W2t[sc + 8][sr] = (short)bf16_1(v2.x);
      W2t[sc + 9][sr] = (short)bf16_1(v2.y);
      W2t[sc + 10][sr] = (short)bf16_1(v2.z);
      W2t[sc + 11][sr] = (short)bf16_1(v2.w);
      W2t[sc + 12][sr] = (short)bf16_1(v3.x);
      W2t[sc + 13][sr] = (short)bf16_1(v3.y);
      W2t[sc + 14][sr] = (short)bf16_1(v3.z);
      W2t[sc + 15][sr] = (short)bf16_1(v3.w);
    }
    __syncthreads();
    // S^T chunk: rows = lm_local, cols = token
    f32x4 sacc[4][4];
#pragma unroll
    for (int i = 0; i < 4; ++i)
#pragma unroll
      for (int j = 0; j < 4; ++j) sacc[i][j] = zero4;
#pragma unroll
    for (int kw = 0; kw < 2; ++kw) {
      bf16x8 kf[4];
#pragma unroll
      for (int mf = 0; mf < 4; ++mf)
        kf[mf] = *(const bf16x8*)&KLs[mf * 16 + fr][kw * 32 + kg * 8];
#pragma unroll
      for (int mf = 0; mf < 4; ++mf)
#pragma unroll
        for (int nf = 0; nf < 4; ++nf)
          sacc[mf][nf] = __builtin_amdgcn_mfma_f32_16x16x32_bf16(kf[mf], qf[nf][kw],
                                                                 sacc[mf][nf], 0, 0, 0);
    }
    // exp (no max: |s| << 1), per-token L accumulate, pack P
#pragma unroll
    for (int mf = 0; mf < 4; ++mf)
#pragma unroll
      for (int nf = 0; nf < 4; ++nf) {
        f32x4 s = sacc[mf][nf];
        float p0 = __expf(s[0]);
        float p1 = __expf(s[1]);
        float p2 = __expf(s[2]);
        float p3 = __expf(s[3]);
        Lp[nf] += (p0 + p1) + (p2 + p3);
        uint2 pw = make_uint2(pk_bf16(p0, p1), pk_bf16(p2, p3));
        *(uint2*)&Ps[w][nf * 16 + fr][mf * 16 + kg * 4] = pw;
      }
    __syncthreads();
    // PV partial: out^T[dim][token] += W2^T chunk x P chunk
#pragma unroll
    for (int kw = 0; kw < 2; ++kw) {
      bf16x8 vf[4], pf[4];
#pragma unroll
      for (int mf = 0; mf < 4; ++mf)
        vf[mf] = *(const bf16x8*)&W2t[mf * 16 + fr][kw * 32 + kg * 8];
#pragma unroll
      for (int nf = 0; nf < 4; ++nf)
        pf[nf] = *(const bf16x8*)&Ps[w][nf * 16 + fr][kw * 32 + kg * 8];
#pragma unroll
      for (int mf = 0; mf < 4; ++mf)
#pragma unroll
        for (int nf = 0; nf < 4; ++nf)
          oacc[mf][nf] = __builtin_amdgcn_mfma_f32_16x16x32_bf16(vf[mf], pf[nf],
                                                                 oacc[mf][nf], 0, 0, 0);
    }
  }
#pragma unroll
  for (int nf = 0; nf < 4; ++nf) {
    Lp[nf] += __shfl_xor(Lp[nf], 16);
    Lp[nf] += __shfl_xor(Lp[nf], 32);
  }
#pragma unroll
  for (int nf = 0; nf < 4; ++nf) {
    float inv = 1.0f / Lp[nf];
    int tok = n0 + w * 64 + nf * 16 + fr;
#pragma unroll
    for (int mf = 0; mf < 4; ++mf) {
      f32x4 o = oacc[mf][nf];
      o[0] *= inv; o[1] *= inv; o[2] *= inv; o[3] *= inv;
      *(f32x4*)(attout + ((size_t)b * NPAD + tok) * DD + h * 64 + mf * 16 + kg * 4) = o;
    }
  }
}

// ---------------- attout += depthwise33(v); grid (NPAD/64, 16 bh)
__global__ __launch_bounds__(256) void k_convres(
    float* __restrict__ attout, const float* __restrict__ qkv,
    const float* __restrict__ resw) {
  __shared__ float vS[96][68];
  __shared__ float w33[33];
  int t = threadIdx.x;
  int tb = blockIdx.x, bh = blockIdx.y;
  int b = bh >> 3, h = bh & 7;
  int n0 = tb * 64;
  if (t < 33) w33[t] = resw[h * 33 + t];
  int sc = (t & 3) * 16;
#pragma unroll
  for (int pass = 0; pass < 2; ++pass) {
    int r = (t >> 2) + pass * 64;
    if (r < 96) {
      int seq = n0 - 16 + r;
      if (seq >= 0 && seq < NPAD) {
        const float* p = qkv + ((size_t)b * NPAD + seq) * 1536 + 1024 + h * 64 + sc;
#pragma unroll
        for (int i = 0; i < 16; i += 4) *(float4*)&vS[r][sc + i] = *(const float4*)(p + i);
      } else {
        float4 z = {0, 0, 0, 0};
#pragma unroll
        for (int i = 0; i < 16; i += 4) *(float4*)&vS[r][sc + i] = z;
      }
    }
  }
  __syncthreads();
  int tg = t >> 5;
  int d2 = (t & 31) * 2;
#pragma unroll
  for (int tk = 0; tk < 8; ++tk) {
    int tokL = tg * 8 + tk;
    float ax = 0.f, ay = 0.f;
    for (int k = 0; k < 33; ++k) {
      float2 v = *(float2*)&vS[tokL + k][d2];
      ax += w33[k] * v.x;
      ay += w33[k] * v.y;
    }
    float* dst = attout + ((size_t)b * NPAD + n0 + tokL) * DD + h * 64 + d2;
    float2 o = *(float2*)dst;
    o.x += ax;
    o.y += ay;
    *(float2*)dst = o;
  }
}

// ---------------------------------------------------------------- PPEG (combined 7x7)
__global__ __launch_bounds__(128) void k_ppeg(
    float* __restrict__ hB, const float* __restrict__ hA,
    const float* __restrict__ w7, const float* __restrict__ b7,
    const float* __restrict__ w5, const float* __restrict__ b5,
    const float* __restrict__ w3, const float* __restrict__ b3) {
  __shared__ float cw[49][128];
  int t = threadIdx.x;
  int i = blockIdx.x >> 2;
  int j0 = (blockIdx.x & 3) * 32;
  int cg = blockIdx.y, b = blockIdx.z;
  int c = cg * 128 + t;
#pragma unroll
  for (int k = 0; k < 49; ++k) cw[k][t] = w7[c * 49 + k];
#pragma unroll
  for (int di = 0; di < 5; ++di)
#pragma unroll
    for (int dj = 0; dj < 5; ++dj)
      cw[(di + 1) * 7 + dj + 1][t] += w5[c * 25 + di * 5 + dj];
#pragma unroll
  for (int di = 0; di < 3; ++di)
#pragma unroll
    for (int dj = 0; dj < 3; ++dj)
      cw[(di + 2) * 7 + dj + 2][t] += w3[c * 9 + di * 3 + dj];
  cw[24][t] += 1.0f;
  float bias = b7[c] + b5[c] + b3[c];
  const float* base = hA + (size_t)b * TT * DD + DD + c;
  float* obase = hB + (size_t)b * TT * DD + DD + c;
  float acc[32];
#pragma unroll
  for (int j = 0; j < 32; ++j) acc[j] = bias;
  for (int di = 0; di < 7; ++di) {
    int ii = i + di - 3;
    if ((unsigned)ii >= 128u) continue;
    float win[38];
#pragma unroll
    for (int w = 0; w < 38; ++w) {
      int col = j0 - 3 + w;
      win[w] = ((unsigned)col < 128u) ? base[(size_t)(ii * 128 + col) * DD] : 0.f;
    }
#pragma unroll
    for (int dj = 0; dj < 7; ++dj) {
      float wv = cw[di * 7 + dj][t];
#pragma unroll
      for (int j = 0; j < 32; ++j) acc[j] += win[j + dj] * wv;
    }
  }
#pragma unroll
  for (int j = 0; j < 32; ++j) obase[(size_t)(i * 128 + j0 + j) * DD] = acc[j];
}

// ---------------------------------------------------------------- final head
__global__ __launch_bounds__(512) void k_final(
    float* __restrict__ out, const float* __restrict__ h,
    const float* __restrict__ g, const float* __restrict__ be,
    const float* __restrict__ cw, const float* __restrict__ cbias) {
  __shared__ float sm[16];
  int t = threadIdx.x;
  for (int b = 0; b < 2; ++b) {
    const float* row = h + (size_t)b * TT * DD;
    float x = row[t];
    float s = x;
    for (int o = 32; o; o >>= 1) s += __shfl_xor(s, o);
    if ((t & 63) == 0) sm[t >> 6] = s;
    __syncthreads();
    float mu = 0.f;
    for (int i = 0; i < 8; ++i) mu += sm[i];
    mu *= (1.f / 512.f);
    __syncthreads();
    float d = x - mu;
    s = d * d;
    for (int o = 32; o; o >>= 1) s += __shfl_xor(s, o);
    if ((t & 63) == 0) sm[t >> 6] = s;
    __syncthreads();
    float var = 0.f;
    for (int i = 0; i < 8; ++i) var += sm[i];
    var *= (1.f / 512.f);
    float rs = rsqrtf(var + 1e-5f);
    __syncthreads();
    float f = d * rs * g[t] + be[t];
    float p0 = f * cw[2 * t], p1 = f * cw[2 * t + 1];
    for (int o = 32; o; o >>= 1) {
      p0 += __shfl_xor(p0, o);
      p1 += __shfl_xor(p1, o);
    }
    if ((t & 63) == 0) {
      sm[t >> 6] = p0;
      sm[8 + (t >> 6)] = p1;
    }
    __syncthreads();
    if (t == 0) {
      float q0 = 0.f, q1 = 0.f;
      for (int i = 0; i < 8; ++i) {
        q0 += sm[i];
        q1 += sm[8 + i];
      }
      out[b * 2 + 0] = q0 + cbias[0];
      out[b * 2 + 1] = q1 + cbias[1];
    }
    __syncthreads();
  }
}

// ---------------------------------------------------------------- host side
static void run_attn(float* h, const float* lng, const float* lnb,
                     const float* wqkv, const float* wout, const float* bout,
                     const float* resw, float* xp, float* qkv, float* ql, float* kl,
                     float* a2, float* z0, float* z1, float* xz, float* yA, float* yB,
                     float* yC, float* bv, float* w2, float* red, float* Sbuf,
                     unsigned short* wth, unsigned short* wtl, hipStream_t stream) {
  k_zero_pad<<<BB * PADF, 256, 0, stream>>>(xp);
  k_ln_pad<<<(BB * TT + 3) / 4, 256, 0, stream>>>(xp, h, lng, lnb);
  k_cvt_wt<<<dim3(DD / 32, 1536 / 32), 256, 0, stream>>>(wqkv, wth, wtl, DD, 1536);
  k_gemm_mfma<1><<<dim3(BB * NPAD / 128, 1536 / 128), 256, 0, stream>>>(
      xp, wth, wtl, nullptr, qkv, BB * NPAD, DD, 1536, DD);
  k_landmarks<<<1024, 256, 0, stream>>>(ql, kl, qkv);
  float* pacc = Sbuf;
  float* pL = Sbuf + (size_t)A3KC * 4096 * 64;
  k_a3v_mfma<<<dim3(16, A3KC), 256, 0, stream>>>(pacc, pL, ql, qkv);
  k_a3v_red<<<4096, 64, 0, stream>>>(bv, pacc, pL);
  k_sim2<<<dim3(4, 4, 16), 256, 0, stream>>>(a2, ql, kl);
  k_softmax256<<<1024, 256, 0, stream>>>(a2);
  k_pinv_sums<<<16, 256, 0, stream>>>(red, a2);
  k_pinv_scale<<<1, 256, 0, stream>>>(red);
  k_zinit<<<dim3(256, 16), 256, 0, stream>>>(z0, a2, red);
  float* zc = z0;
  float* zn = z1;
  for (int it = 0; it < 6; ++it) {
    k_bmm_mfma<<<dim3(4, 4, 16), 256, 0, stream>>>(a2, zc, xz, 1.f, 0.f, yA, -1.f, 7.f, 256);
    k_bmm_mfma<<<dim3(4, 4, 16), 256, 0, stream>>>(xz, yA, yB, -1.f, 15.f, nullptr, 0.f, 0.f, 256);
    k_bmm_mfma<<<dim3(4, 4, 16), 256, 0, stream>>>(xz, yB, yC, -1.f, 13.f, nullptr, 0.f, 0.f, 256);
    k_bmm_mfma<<<dim3(4, 4, 16), 256, 0, stream>>>(zc, yC, zn, 0.25f, 0.f, nullptr, 0.f, 0.f, 256);
    float* tmp = zc; zc = zn; zn = tmp;
  }
  k_bmm_mfma<<<dim3(1, 4, 16), 256, 0, stream>>>(zc, bv, w2, 1.f, 0.f, nullptr, 0.f, 0.f, 64);
  k_att1<<<dim3(NPAD / 256, 16), 256, 0, stream>>>(xp, qkv, kl, w2);
  k_convres<<<dim3(NPAD / 64, 16), 256, 0, stream>>>(xp, qkv, resw);
  k_cvt_wt<<<dim3(DD / 32, DD / 32), 256, 0, stream>>>(wout, wth, wtl, DD, DD);
  k_gemm_mfma<2><<<dim3(129, 4, BB), 256, 0, stream>>>(xp, wth, wtl, bout, h, TT, DD,
                                                       DD, DD);
}

extern "C" void kernel_launch(void* const* d_in, const int* in_sizes, int n_in,
                              void* d_out, int out_size, void* d_ws, size_t ws_size,
                              hipStream_t stream) {
  const float* x        = (const float*)d_in[0];
  const float* w_feat   = (const float*)d_in[1];
  const float* b_feat   = (const float*)d_in[2];
  const float* cls_tok  = (const float*)d_in[3];
  const float* ln1_g    = (const float*)d_in[4];
  const float* ln1_b    = (const float*)d_in[5];
  const float* qkv1     = (const float*)d_in[6];
  const float* out1_w   = (const float*)d_in[7];
  const float* out1_b   = (const float*)d_in[8];
  const float* res1_w   = (const float*)d_in[9];
  const float* ppeg_w7  = (const float*)d_in[10];
  const float* ppeg_b7  = (const float*)d_in[11];
  const float* ppeg_w5  = (const float*)d_in[12];
  const float* ppeg_b5  = (const float*)d_in[13];
  const float* ppeg_w3  = (const float*)d_in[14];
  const float* ppeg_b3  = (const float*)d_in[15];
  const float* ln2_g    = (const float*)d_in[16];
  const float* ln2_b    = (const float*)d_in[17];
  const float* qkv2     = (const float*)d_in[18];
  const float* out2_w   = (const float*)d_in[19];
  const float* out2_b   = (const float*)d_in[20];
  const float* res2_w   = (const float*)d_in[21];
  const float* lnf_g    = (const float*)d_in[22];
  const float* lnf_b    = (const float*)d_in[23];
  const float* cls_w    = (const float*)d_in[24];
  const float* cls_b    = (const float*)d_in[25];

  float* ws = (float*)d_ws;
  size_t off = 0;
  float* hA  = ws + off; off += (size_t)BB * TT * DD;
  float* hB  = ws + off; off += (size_t)BB * TT * DD;
  float* xp  = ws + off; off += (size_t)BB * NPAD * DD;
  float* qkv = ws + off; off += (size_t)BB * NPAD * 3 * DD;
  float* ql  = ws + off; off += (size_t)BB * HH * 256 * 64;
  float* kl  = ws + off; off += (size_t)BB * HH * 256 * 64;
  float* a2  = ws + off; off += (size_t)16 * 65536;
  float* z0  = ws + off; off += (size_t)16 * 65536;
  float* z1  = ws + off; off += (size_t)16 * 65536;
  float* xz  = ws + off; off += (size_t)16 * 65536;
  float* yA  = ws + off; off += (size_t)16 * 65536;
  float* yB  = ws + off; off += (size_t)16 * 65536;
  float* yC  = ws + off; off += (size_t)16 * 65536;
  float* bv  = ws + off; off += (size_t)BB * HH * 256 * 64;
  float* w2  = ws + off; off += (size_t)BB * HH * 256 * 64;
  float* red = ws + off; off += 8448;
  unsigned short* wth = (unsigned short*)(ws + off); off += 393216;
  unsigned short* wtl = (unsigned short*)(ws + off); off += 393216;

  // Stage 1: h = gelu(x @ w_feat + b_feat), prepend cls token
  k_set_cls<<<2, 512, 0, stream>>>(hA, cls_tok);
  k_cvt_wt<<<dim3(1024 / 32, DD / 32), 256, 0, stream>>>(w_feat, wth, wtl, 1024, DD);
  k_gemm_mfma<0><<<dim3(32768 / 128, DD / 128), 256, 0, stream>>>(
      x, wth, wtl, b_feat, hA, 32768, 1024, DD, 1024);
  // Attention 1 (residual in-place on hA; hB is dead -> scratch)
  run_attn(hA, ln1_g, ln1_b, qkv1, out1_w, out1_b, res1_w, xp, qkv, ql, kl, a2, z0, z1,
           xz, yA, yB, yC, bv, w2, red, hB, wth, wtl, stream);
  // PPEG: hB = ppeg(hA)
  k_copy_cls<<<2, 512, 0, stream>>>(hB, hA);
  k_ppeg<<<dim3(512, 4, 2), 128, 0, stream>>>(hB, hA, ppeg_w7, ppeg_b7, ppeg_w5, ppeg_b5,
                                              ppeg_w3, ppeg_b3);
  // Attention 2 (residual in-place on hB; hA is dead -> scratch)
  run_attn(hB, ln2_g, ln2_b, qkv2, out2_w, out2_b, res2_w, xp, qkv, ql, kl, a2, z0, z1,
           xz, yA, yB, yC, bv, w2, red, hA, wth, wtl, stream);
  // Final: LN(cls) @ cls_w + cls_b
  k_final<<<1, 512, 0, stream>>>((float*)d_out, hB, lnf_g, lnf_b, cls_w, cls_b);
}

// Round 8
// 2074.050 us; speedup vs baseline: 5.1887x; 1.0377x over previous
//
#include <hip/hip_runtime.h>
#include <cstdint>
#include <cstddef>

#define BB 2
#define TT 16385
#define NPAD 16640
#define DD 512
#define HH 8
#define DHH 64
#define MLAND 256
#define PADF 255
#define A3KC 26
#define A3CH 640

typedef __attribute__((ext_vector_type(8))) _Float16 f16x8;
typedef __attribute__((ext_vector_type(4))) float f32x4;

__device__ __forceinline__ float gelu_f(float v) {
  float c = 0.7978845608028654f * (v + 0.044715f * v * v * v);
  return 0.5f * v * (1.0f + tanhf(c));
}

__device__ __forceinline__ unsigned short f16_1(float a) {
  _Float16 h = (_Float16)a;
  return __builtin_bit_cast(unsigned short, h);
}
__device__ __forceinline__ unsigned pk_f16(float a, float b) {
  return (unsigned)f16_1(a) | ((unsigned)f16_1(b) << 16);
}
// split a,b into f16 hi (packed) and f16 residual-lo (packed)
__device__ __forceinline__ void split2h(float a, float b, unsigned& hi, unsigned& lo) {
  _Float16 ah = (_Float16)a, bh = (_Float16)b;
  hi = (unsigned)__builtin_bit_cast(unsigned short, ah) |
       ((unsigned)__builtin_bit_cast(unsigned short, bh) << 16);
  lo = pk_f16(a - (float)ah, b - (float)bh);
}
// store float4 as f16 hi plane + residual plane (4 shorts each, 8B)
__device__ __forceinline__ void store4h(float4 v, unsigned short* dh,
                                        unsigned short* dl) {
  unsigned h0, l0, h1, l1;
  split2h(v.x, v.y, h0, l0);
  split2h(v.z, v.w, h1, l1);
  *(uint2*)dh = make_uint2(h0, h1);
  *(uint2*)dl = make_uint2(l0, l1);
}

// ---------------------------------------------------------------- cls rows
__global__ void k_set_cls(float* __restrict__ h, const float* __restrict__ cls) {
  h[(size_t)blockIdx.x * TT * DD + threadIdx.x] = cls[threadIdx.x];
}
__global__ void k_copy_cls(float* __restrict__ dst, const float* __restrict__ src) {
  size_t o = (size_t)blockIdx.x * TT * DD + threadIdx.x;
  dst[o] = src[o];
}

// ------------------------------------------------ W[K][N] -> Wt f16 [N][K]
__global__ __launch_bounds__(256) void k_cvt_wt(
    const float* __restrict__ W, unsigned short* __restrict__ Wth, int K, int N) {
  __shared__ float tile[32][33];
  int kb = blockIdx.x * 32, nb = blockIdx.y * 32;
  int t = threadIdx.x;
  int tr = t >> 3, tc4 = (t & 7) * 4;
  float4 v = *(const float4*)(W + (size_t)(kb + tr) * N + nb + tc4);
  tile[tr][tc4 + 0] = v.x;
  tile[tr][tc4 + 1] = v.y;
  tile[tr][tc4 + 2] = v.z;
  tile[tr][tc4 + 3] = v.w;
  __syncthreads();
  int n = nb + tr;
  ushort4 hs;
  hs.x = f16_1(tile[tc4 + 0][tr]);
  hs.y = f16_1(tile[tc4 + 1][tr]);
  hs.z = f16_1(tile[tc4 + 2][tr]);
  hs.w = f16_1(tile[tc4 + 3][tr]);
  *(ushort4*)(Wth + (size_t)n * K + kb + tc4) = hs;
}

// ---------------- fp32-via-2xf16 MFMA GEMM, 128x128 tile: C = (Ah+Al) @ Bh
// MODE 0: feat (A fp32, split in-kernel); MODE 1: qkv (A pre-split planes);
// MODE 2: proj (A fp32 split; +bias+residual, grid.z = batch)
template <int MODE>
__global__ __launch_bounds__(256) void k_gemm_mfma(
    const float* __restrict__ A, const unsigned short* __restrict__ Aph,
    const unsigned short* __restrict__ Apl, const unsigned short* __restrict__ Wth,
    const float* __restrict__ bias, float* __restrict__ C, int M, int K, int N,
    int lda) {
  __shared__ short Ash[128][40];
  __shared__ short Asl[128][40];
  __shared__ short Bsh[128][40];
  const int t = threadIdx.x;
  const int rb = blockIdx.x * 128, cb = blockIdx.y * 128;
  const float* Ab = A;
  float* Cb = C;
  if (MODE == 2) {
    int b = blockIdx.z;
    Ab = A + (size_t)b * NPAD * DD + (size_t)PADF * DD;
    Cb = C + (size_t)b * TT * DD;
  }
  const int lane = t & 63, wv = t >> 6;
  const int wr = wv >> 1, wc = wv & 1;
  const int fr = lane & 15, kg = lane >> 4;
  const int srow = t >> 1, skh = (t & 1) * 16;

  f32x4 acc[4][4];
  f32x4 zero4 = {0.f, 0.f, 0.f, 0.f};
#pragma unroll
  for (int i = 0; i < 4; ++i)
#pragma unroll
    for (int j = 0; j < 4; ++j) acc[i][j] = zero4;

  for (int k0 = 0; k0 < K; k0 += 32) {
    __syncthreads();
    if (MODE == 1) {  // pre-split planes: pure copy staging
      const unsigned short* ph = Aph + (size_t)(rb + srow) * lda + k0 + skh;
      const unsigned short* pl = Apl + (size_t)(rb + srow) * lda + k0 + skh;
      *(uint4*)&Ash[srow][skh] = *(const uint4*)ph;
      *(uint4*)&Ash[srow][skh + 8] = *(const uint4*)(ph + 8);
      *(uint4*)&Asl[srow][skh] = *(const uint4*)pl;
      *(uint4*)&Asl[srow][skh + 8] = *(const uint4*)(pl + 8);
    } else {  // fp32 A, split to f16 hi/lo in-kernel
      int grow = rb + srow;
      float4 f0 = {0, 0, 0, 0}, f1 = {0, 0, 0, 0}, f2 = {0, 0, 0, 0}, f3 = {0, 0, 0, 0};
      if (grow < M) {
        const float* p = Ab + (size_t)grow * lda + k0 + skh;
        f0 = *(const float4*)p;
        f1 = *(const float4*)(p + 4);
        f2 = *(const float4*)(p + 8);
        f3 = *(const float4*)(p + 12);
      }
      unsigned h0, h1, h2, h3, h4, h5, h6, h7;
      unsigned l0, l1, l2, l3, l4, l5, l6, l7;
      split2h(f0.x, f0.y, h0, l0);
      split2h(f0.z, f0.w, h1, l1);
      split2h(f1.x, f1.y, h2, l2);
      split2h(f1.z, f1.w, h3, l3);
      split2h(f2.x, f2.y, h4, l4);
      split2h(f2.z, f2.w, h5, l5);
      split2h(f3.x, f3.y, h6, l6);
      split2h(f3.z, f3.w, h7, l7);
      *(uint4*)&Ash[srow][skh] = make_uint4(h0, h1, h2, h3);
      *(uint4*)&Ash[srow][skh + 8] = make_uint4(h4, h5, h6, h7);
      *(uint4*)&Asl[srow][skh] = make_uint4(l0, l1, l2, l3);
      *(uint4*)&Asl[srow][skh + 8] = make_uint4(l4, l5, l6, l7);
    }
    {  // stage B hi plane (pre-cvt f16, row-major [N][K])
      int lc = t >> 1;
      const unsigned short* ph = Wth + (size_t)(cb + lc) * K + k0 + skh;
      *(uint4*)&Bsh[lc][skh] = *(const uint4*)ph;
      *(uint4*)&Bsh[lc][skh + 8] = *(const uint4*)(ph + 8);
    }
    __syncthreads();
    f16x8 ah[4], al[4], bh[4];
#pragma unroll
    for (int mf = 0; mf < 4; ++mf) {
      ah[mf] = *(const f16x8*)&Ash[wr * 64 + mf * 16 + fr][kg * 8];
      al[mf] = *(const f16x8*)&Asl[wr * 64 + mf * 16 + fr][kg * 8];
    }
#pragma unroll
    for (int nf = 0; nf < 4; ++nf)
      bh[nf] = *(const f16x8*)&Bsh[wc * 64 + nf * 16 + fr][kg * 8];
#pragma unroll
    for (int mf = 0; mf < 4; ++mf)
#pragma unroll
      for (int nf = 0; nf < 4; ++nf) {
        acc[mf][nf] =
            __builtin_amdgcn_mfma_f32_16x16x32_f16(ah[mf], bh[nf], acc[mf][nf], 0, 0, 0);
        acc[mf][nf] =
            __builtin_amdgcn_mfma_f32_16x16x32_f16(al[mf], bh[nf], acc[mf][nf], 0, 0, 0);
      }
  }
#pragma unroll
  for (int mf = 0; mf < 4; ++mf) {
#pragma unroll
    for (int r = 0; r < 4; ++r) {
      int row = rb + wr * 64 + mf * 16 + kg * 4 + r;
      if (MODE == 2 && row >= M) continue;
      size_t orow = (MODE == 0) ? (size_t)(row + (row >> 14) + 1) : (size_t)row;
#pragma unroll
      for (int nf = 0; nf < 4; ++nf) {
        int col = cb + wc * 64 + nf * 16 + fr;
        float v = acc[mf][nf][r];
        if (MODE == 0) {
          Cb[orow * DD + col] = gelu_f(v + bias[col]);
        } else if (MODE == 1) {
          Cb[orow * (size_t)N + col] = v;
        } else {
          float old = Cb[orow * DD + col];
          Cb[orow * DD + col] = old + v + bias[col];
        }
      }
    }
  }
}

// ------------------------- LN + pad -> writes f16 hi/lo planes (qkv A operand)
__global__ __launch_bounds__(256) void k_ln_pad(
    unsigned short* __restrict__ xph, unsigned short* __restrict__ xpl,
    const float* __restrict__ h, const float* __restrict__ gam,
    const float* __restrict__ bet) {
  int w = threadIdx.x >> 6, lane = threadIdx.x & 63;
  int row = blockIdx.x * 4 + w;
  if (row >= BB * TT) return;
  int b = row / TT, i = row - b * TT;
  const float* src = h + (size_t)row * DD;
  float4 x0 = *(const float4*)(src + lane * 4);
  float4 x1 = *(const float4*)(src + 256 + lane * 4);
  float s = x0.x + x0.y + x0.z + x0.w + x1.x + x1.y + x1.z + x1.w;
  for (int o = 32; o; o >>= 1) s += __shfl_xor(s, o);
  float mu = s * (1.f / 512.f);
  float q = (x0.x - mu) * (x0.x - mu) + (x0.y - mu) * (x0.y - mu) +
            (x0.z - mu) * (x0.z - mu) + (x0.w - mu) * (x0.w - mu) +
            (x1.x - mu) * (x1.x - mu) + (x1.y - mu) * (x1.y - mu) +
            (x1.z - mu) * (x1.z - mu) + (x1.w - mu) * (x1.w - mu);
  for (int o = 32; o; o >>= 1) q += __shfl_xor(q, o);
  float rs = rsqrtf(q * (1.f / 512.f) + 1e-5f);
  float4 g0 = *(const float4*)(gam + lane * 4);
  float4 g1 = *(const float4*)(gam + 256 + lane * 4);
  float4 b0 = *(const float4*)(bet + lane * 4);
  float4 b1 = *(const float4*)(bet + 256 + lane * 4);
  float4 o0, o1;
  o0.x = (x0.x - mu) * rs * g0.x + b0.x;
  o0.y = (x0.y - mu) * rs * g0.y + b0.y;
  o0.z = (x0.z - mu) * rs * g0.z + b0.z;
  o0.w = (x0.w - mu) * rs * g0.w + b0.w;
  o1.x = (x1.x - mu) * rs * g1.x + b1.x;
  o1.y = (x1.y - mu) * rs * g1.y + b1.y;
  o1.z = (x1.z - mu) * rs * g1.z + b1.z;
  o1.w = (x1.w - mu) * rs * g1.w + b1.w;
  size_t ro = ((size_t)b * NPAD + PADF + i) * DD;
  store4h(o0, xph + ro + lane * 4, xpl + ro + lane * 4);
  store4h(o1, xph + ro + 256 + lane * 4, xpl + ro + 256 + lane * 4);
}

__global__ void k_zero_pad(unsigned short* __restrict__ xph,
                           unsigned short* __restrict__ xpl) {
  int r = blockIdx.x;
  int b = r / PADF, j = r - b * PADF;
  size_t ro = ((size_t)b * NPAD + j) * DD;
  ((unsigned*)(xph + ro))[threadIdx.x] = 0u;
  ((unsigned*)(xpl + ro))[threadIdx.x] = 0u;
}

// ---------------------------------------------------------------- landmarks
__global__ __launch_bounds__(256) void k_landmarks(
    float* __restrict__ ql, float* __restrict__ kl, const float* __restrict__ qkv) {
  int t = threadIdx.x;
  int mi = t >> 6, d = t & 63;
  int blk = blockIdx.x;
  int bh = blk >> 6, mg = blk & 63;
  int b = bh >> 3, h = bh & 7;
  int m = mg * 4 + mi;
  const float* base = qkv + (size_t)b * NPAD * 1536 + h * 64 + d;
  float sq = 0.f, sk = 0.f;
  int t0 = m * 65;
  for (int j = 0; j < 65; ++j) {
    const float* p = base + (size_t)(t0 + j) * 1536;
    sq += p[0];
    sk += p[512];
  }
  ql[((size_t)bh * 256 + m) * 64 + d] = sq * (0.125f / 65.f);
  kl[((size_t)bh * 256 + m) * 64 + d] = sk * (1.f / 65.f);
}

// ---------------------------------------------------------------- sim2 = ql @ kl^T
__global__ __launch_bounds__(256) void k_sim2(
    float* __restrict__ sim, const float* __restrict__ ql, const float* __restrict__ kl) {
  __shared__ __align__(16) float Aq[64][68];
  __shared__ __align__(16) float Bk[64][68];
  int t = threadIdx.x;
  int tj = blockIdx.x, ti = blockIdx.y, bh = blockIdx.z;
  int r = t >> 2, cc = (t & 3) * 16;
  const float* ap = ql + ((size_t)bh * 256 + ti * 64 + r) * 64 + cc;
  const float* bp = kl + ((size_t)bh * 256 + tj * 64 + r) * 64 + cc;
#pragma unroll
  for (int i = 0; i < 16; i += 4) {
    *(float4*)&Aq[r][cc + i] = *(const float4*)(ap + i);
    *(float4*)&Bk[r][cc + i] = *(const float4*)(bp + i);
  }
  __syncthreads();
  int tx = t & 15, ty = t >> 4;
  float acc[4][4];
#pragma unroll
  for (int i = 0; i < 4; ++i)
#pragma unroll
    for (int j = 0; j < 4; ++j) acc[i][j] = 0.f;
  for (int d = 0; d < 64; d += 4) {
    float4 a4[4], b4[4];
#pragma unroll
    for (int ii = 0; ii < 4; ++ii) a4[ii] = *(float4*)&Aq[ty * 4 + ii][d];
#pragma unroll
    for (int jj = 0; jj < 4; ++jj) b4[jj] = *(float4*)&Bk[tx * 4 + jj][d];
#pragma unroll
    for (int ii = 0; ii < 4; ++ii)
#pragma unroll
      for (int jj = 0; jj < 4; ++jj)
        acc[ii][jj] += a4[ii].x * b4[jj].x + a4[ii].y * b4[jj].y + a4[ii].z * b4[jj].z +
                       a4[ii].w * b4[jj].w;
  }
#pragma unroll
  for (int ii = 0; ii < 4; ++ii)
#pragma unroll
    for (int jj = 0; jj < 4; ++jj)
      sim[((size_t)bh * 256 + ti * 64 + ty * 4 + ii) * 256 + tj * 64 + tx * 4 + jj] =
          acc[ii][jj];
}

// ---------------------------------------------------------------- row softmax (len 256)
__global__ __launch_bounds__(256) void k_softmax256(float* __restrict__ a) {
  int w = threadIdx.x >> 6, lane = threadIdx.x & 63;
  size_t row = (size_t)blockIdx.x * 4 + w;
  float* p = a + row * 256 + lane * 4;
  float4 v = *(float4*)p;
  float m = fmaxf(fmaxf(v.x, v.y), fmaxf(v.z, v.w));
  for (int o = 32; o; o >>= 1) m = fmaxf(m, __shfl_xor(m, o));
  v.x = expf(v.x - m); v.y = expf(v.y - m);
  v.z = expf(v.z - m); v.w = expf(v.w - m);
  float s = v.x + v.y + v.z + v.w;
  for (int o = 32; o; o >>= 1) s += __shfl_xor(s, o);
  float inv = 1.f / s;
  v.x *= inv; v.y *= inv; v.z *= inv; v.w *= inv;
  *(float4*)p = v;
}

// ---------------------------------------------------------------- pinv helpers
__global__ void k_pinv_sums(float* __restrict__ red, const float* __restrict__ a2) {
  int bh = blockIdx.x, t = threadIdx.x;
  const float* Ab = a2 + (size_t)bh * 65536;
  float s = 0.f;
  for (int i = 0; i < 256; ++i) s += fabsf(Ab[(size_t)i * 256 + t]);
  red[bh * 256 + t] = s;
  float c = 0.f;
  const float* rp = Ab + (size_t)t * 256;
  for (int j = 0; j < 256; j += 4) {
    float4 v = *(const float4*)(rp + j);
    c += fabsf(v.x) + fabsf(v.y) + fabsf(v.z) + fabsf(v.w);
  }
  red[4096 + bh * 256 + t] = c;
}

__global__ void k_pinv_scale(float* __restrict__ red) {
  __shared__ float sm[8];
  int t = threadIdx.x;
  float m1 = 0.f, m2 = 0.f;
  for (int k = t; k < 4096; k += 256) {
    m1 = fmaxf(m1, red[k]);
    m2 = fmaxf(m2, red[4096 + k]);
  }
  for (int o = 32; o; o >>= 1) {
    m1 = fmaxf(m1, __shfl_xor(m1, o));
    m2 = fmaxf(m2, __shfl_xor(m2, o));
  }
  int w = t >> 6;
  if ((t & 63) == 0) { sm[w] = m1; sm[4 + w] = m2; }
  __syncthreads();
  if (t == 0) {
    float a = fmaxf(fmaxf(sm[0], sm[1]), fmaxf(sm[2], sm[3]));
    float b = fmaxf(fmaxf(sm[4], sm[5]), fmaxf(sm[6], sm[7]));
    red[8192] = 1.0f / (a * b);
  }
}

__global__ void k_zinit(float* __restrict__ z, const float* __restrict__ a2,
                        const float* __restrict__ red) {
  float s = red[8192];
  int i = blockIdx.x, bh = blockIdx.y, j = threadIdx.x;
  z[((size_t)bh * 256 + i) * 256 + j] = a2[((size_t)bh * 256 + j) * 256 + i] * s;
}

// ------- batched 256x256 @ 256xN MFMA (f16 3-term); C1 = a1*(A@B)+d1*I; opt C2
__global__ __launch_bounds__(256) void k_bmm_mfma(
    const float* __restrict__ A, const float* __restrict__ Bm,
    float* __restrict__ C1, float a1, float d1,
    float* __restrict__ C2, float a2c, float d2, int N) {
  __shared__ short Ash[64][40];
  __shared__ short Asl[64][40];
  __shared__ short Bsh[64][40];
  __shared__ short Bsl[64][40];
  const int t = threadIdx.x;
  const int bh = blockIdx.z;
  const int i0 = blockIdx.y * 64, j0 = blockIdx.x * 64;
  const float* Ab = A + (size_t)bh * 65536;
  const float* Bb = Bm + (size_t)bh * 256 * N;
  const int lane = t & 63, w = t >> 6;
  const int fr = lane & 15, kg = lane >> 4;
  f32x4 acc[4];
  f32x4 zero4 = {0.f, 0.f, 0.f, 0.f};
#pragma unroll
  for (int i = 0; i < 4; ++i) acc[i] = zero4;

  const int ar = t >> 2, akseg = (t & 3) * 8;
  for (int k0 = 0; k0 < 256; k0 += 32) {
    __syncthreads();
    {  // stage A rows (f16 split)
      const float* p = Ab + (size_t)(i0 + ar) * 256 + k0 + akseg;
      float4 f0 = *(const float4*)p;
      float4 f1 = *(const float4*)(p + 4);
      unsigned h0, h1, h2, h3, l0, l1, l2, l3;
      split2h(f0.x, f0.y, h0, l0);
      split2h(f0.z, f0.w, h1, l1);
      split2h(f1.x, f1.y, h2, l2);
      split2h(f1.z, f1.w, h3, l3);
      *(uint2*)&Ash[ar][akseg] = make_uint2(h0, h1);
      *(uint2*)&Ash[ar][akseg + 4] = make_uint2(h2, h3);
      *(uint2*)&Asl[ar][akseg] = make_uint2(l0, l1);
      *(uint2*)&Asl[ar][akseg + 4] = make_uint2(l2, l3);
    }
    {  // stage B transposed (f16 split): Bsh[j_local][k_local]
#pragma unroll
      for (int pass = 0; pass < 2; ++pass) {
        int kr = pass * 16 + (t >> 4);
        int jseg = (t & 15) * 4;
        const float* p = Bb + (size_t)(k0 + kr) * N + j0 + jseg;
        float4 f = *(const float4*)p;
        float fv[4] = {f.x, f.y, f.z, f.w};
#pragma unroll
        for (int c = 0; c < 4; ++c) {
          _Float16 hh = (_Float16)fv[c];
          float lo = fv[c] - (float)hh;
          Bsh[jseg + c][kr] = (short)__builtin_bit_cast(unsigned short, hh);
          Bsl[jseg + c][kr] = (short)f16_1(lo);
        }
      }
    }
    __syncthreads();
    f16x8 bhf = *(const f16x8*)&Bsh[w * 16 + fr][kg * 8];
    f16x8 blf = *(const f16x8*)&Bsl[w * 16 + fr][kg * 8];
#pragma unroll
    for (int mf = 0; mf < 4; ++mf) {
      f16x8 ah = *(const f16x8*)&Ash[mf * 16 + fr][kg * 8];
      f16x8 al = *(const f16x8*)&Asl[mf * 16 + fr][kg * 8];
      acc[mf] = __builtin_amdgcn_mfma_f32_16x16x32_f16(ah, bhf, acc[mf], 0, 0, 0);
      acc[mf] = __builtin_amdgcn_mfma_f32_16x16x32_f16(al, bhf, acc[mf], 0, 0, 0);
      acc[mf] = __builtin_amdgcn_mfma_f32_16x16x32_f16(ah, blf, acc[mf], 0, 0, 0);
    }
  }
  int j = j0 + w * 16 + fr;
#pragma unroll
  for (int mf = 0; mf < 4; ++mf) {
#pragma unroll
    for (int rr = 0; rr < 4; ++rr) {
      int i = i0 + mf * 16 + kg * 4 + rr;
      float v = acc[mf][rr];
      size_t off = (size_t)bh * 256 * N + (size_t)i * N + j;
      C1[off] = a1 * v + ((i == j) ? d1 : 0.f);
      if (C2) C2[off] = a2c * v + ((i == j) ? d2 : 0.f);
    }
  }
}

// -------------------------- a3 @ v : MFMA flash (f16, no-max, split-K chunks)
__global__ __launch_bounds__(256, 2) void k_a3v_mfma(
    float* __restrict__ pacc, float* __restrict__ pL,
    const float* __restrict__ ql, const float* __restrict__ qkv) {
  __shared__ short Ks[64][72];
  __shared__ short Vt[64][72];
  __shared__ short Ps[4][64][72];
  const int t = threadIdx.x;
  const int bh = blockIdx.x;
  const int kc = blockIdx.y;
  const int b = bh >> 3, h = bh & 7;
  const int lane = t & 63, w = t >> 6;
  const int fr = lane & 15, kg = lane >> 4;

  f16x8 qf[4][2];
#pragma unroll
  for (int nf = 0; nf < 4; ++nf) {
    const float* qp = ql + ((size_t)bh * 256 + w * 64 + nf * 16 + fr) * 64 + kg * 8;
#pragma unroll
    for (int kw = 0; kw < 2; ++kw) {
      float4 a = *(const float4*)(qp + kw * 32);
      float4 c = *(const float4*)(qp + kw * 32 + 4);
      uint4 uu = make_uint4(pk_f16(a.x, a.y), pk_f16(a.z, a.w), pk_f16(c.x, c.y),
                            pk_f16(c.z, c.w));
      qf[nf][kw] = *(f16x8*)&uu;
    }
  }
  f32x4 oacc[4][4];
  f32x4 zero4 = {0.f, 0.f, 0.f, 0.f};
#pragma unroll
  for (int i = 0; i < 4; ++i)
#pragma unroll
    for (int j = 0; j < 4; ++j) oacc[i][j] = zero4;
  float Lp[4] = {0.f, 0.f, 0.f, 0.f};

  const int skey = t >> 2, sd = (t & 3) * 16;
  const float* kbase = qkv + (size_t)b * NPAD * 1536 + 512 + h * 64 + sd;

  for (int it = 0; it < A3CH / 64; ++it) {
    int nt = kc * A3CH + it * 64;
    __syncthreads();
    {
      const float* kp = kbase + (size_t)(nt + skey) * 1536;
      float4 k0 = *(const float4*)kp;
      float4 k1 = *(const float4*)(kp + 4);
      float4 k2 = *(const float4*)(kp + 8);
      float4 k3 = *(const float4*)(kp + 12);
      const float* vp = kp + 512;
      float4 v0 = *(const float4*)vp;
      float4 v1 = *(const float4*)(vp + 4);
      float4 v2 = *(const float4*)(vp + 8);
      float4 v3 = *(const float4*)(vp + 12);
      *(uint4*)&Ks[skey][sd] = make_uint4(pk_f16(k0.x, k0.y), pk_f16(k0.z, k0.w),
                                          pk_f16(k1.x, k1.y), pk_f16(k1.z, k1.w));
      *(uint4*)&Ks[skey][sd + 8] = make_uint4(pk_f16(k2.x, k2.y), pk_f16(k2.z, k2.w),
                                              pk_f16(k3.x, k3.y), pk_f16(k3.z, k3.w));
      Vt[sd + 0][skey] = (short)f16_1(v0.x);
      Vt[sd + 1][skey] = (short)f16_1(v0.y);
      Vt[sd + 2][skey] = (short)f16_1(v0.z);
      Vt[sd + 3][skey] = (short)f16_1(v0.w);
      Vt[sd + 4][skey] = (short)f16_1(v1.x);
      Vt[sd + 5][skey] = (short)f16_1(v1.y);
      Vt[sd + 6][skey] = (short)f16_1(v1.z);
      Vt[sd + 7][skey] = (short)f16_1(v1.w);
      Vt[sd + 8][skey] = (short)f16_1(v2.x);
      Vt[sd + 9][skey] = (short)f16_1(v2.y);
      Vt[sd + 10][skey] = (short)f16_1(v2.z);
      Vt[sd + 11][skey] = (short)f16_1(v2.w);
      Vt[sd + 12][skey] = (short)f16_1(v3.x);
      Vt[sd + 13][skey] = (short)f16_1(v3.y);
      Vt[sd + 14][skey] = (short)f16_1(v3.z);
      Vt[sd + 15][skey] = (short)f16_1(v3.w);
    }
    __syncthreads();
    f32x4 sacc[4][4];
#pragma unroll
    for (int i = 0; i < 4; ++i)
#pragma unroll
      for (int j = 0; j < 4; ++j) sacc[i][j] = zero4;
#pragma unroll
    for (int kw = 0; kw < 2; ++kw) {
      f16x8 kf[4];
#pragma unroll
      for (int mf = 0; mf < 4; ++mf)
        kf[mf] = *(const f16x8*)&Ks[mf * 16 + fr][kw * 32 + kg * 8];
#pragma unroll
      for (int mf = 0; mf < 4; ++mf)
#pragma unroll
        for (int nf = 0; nf < 4; ++nf)
          sacc[mf][nf] = __builtin_amdgcn_mfma_f32_16x16x32_f16(kf[mf], qf[nf][kw],
                                                                sacc[mf][nf], 0, 0, 0);
    }
#pragma unroll
    for (int mf = 0; mf < 4; ++mf)
#pragma unroll
      for (int nf = 0; nf < 4; ++nf) {
        f32x4 s = sacc[mf][nf];
        float p0 = __expf(s[0]);
        float p1 = __expf(s[1]);
        float p2 = __expf(s[2]);
        float p3 = __expf(s[3]);
        Lp[nf] += (p0 + p1) + (p2 + p3);
        uint2 pw = make_uint2(pk_f16(p0, p1), pk_f16(p2, p3));
        *(uint2*)&Ps[w][nf * 16 + fr][mf * 16 + kg * 4] = pw;
      }
    __syncthreads();
#pragma unroll
    for (int kw = 0; kw < 2; ++kw) {
      f16x8 vf[4], pf[4];
#pragma unroll
      for (int mf = 0; mf < 4; ++mf)
        vf[mf] = *(const f16x8*)&Vt[mf * 16 + fr][kw * 32 + kg * 8];
#pragma unroll
      for (int nf = 0; nf < 4; ++nf)
        pf[nf] = *(const f16x8*)&Ps[w][nf * 16 + fr][kw * 32 + kg * 8];
#pragma unroll
      for (int mf = 0; mf < 4; ++mf)
#pragma unroll
        for (int nf = 0; nf < 4; ++nf)
          oacc[mf][nf] = __builtin_amdgcn_mfma_f32_16x16x32_f16(vf[mf], pf[nf],
                                                                oacc[mf][nf], 0, 0, 0);
    }
  }
  size_t obase = ((size_t)kc * 16 + bh) * 256;
#pragma unroll
  for (int mf = 0; mf < 4; ++mf)
#pragma unroll
    for (int nf = 0; nf < 4; ++nf) {
      int lm = w * 64 + nf * 16 + fr;
      *(f32x4*)(pacc + (obase + lm) * 64 + mf * 16 + kg * 4) = oacc[mf][nf];
    }
#pragma unroll
  for (int nf = 0; nf < 4; ++nf) {
    Lp[nf] += __shfl_xor(Lp[nf], 16);
    Lp[nf] += __shfl_xor(Lp[nf], 32);
  }
  if (lane < 16) {
#pragma unroll
    for (int nf = 0; nf < 4; ++nf)
      pL[obase + w * 64 + nf * 16 + lane] = Lp[nf];
  }
}

__global__ __launch_bounds__(64) void k_a3v_red(
    float* __restrict__ bv, const float* __restrict__ pacc,
    const float* __restrict__ pL) {
  int row = blockIdx.x;
  int d = threadIdx.x;
  float A = 0.f, L = 0.f;
#pragma unroll
  for (int c = 0; c < A3KC; ++c) {
    size_t pr = (size_t)c * 4096 + row;
    A += pacc[pr * 64 + d];
    L += pL[pr];
  }
  bv[(size_t)row * 64 + d] = A / L;
}

// ------------- fused sim1: attout = softmax(0.125*q @ kl^T) @ w2 (f16 MFMA, no-max)
__global__ __launch_bounds__(256, 2) void k_att1(
    float* __restrict__ attout, const float* __restrict__ qkv,
    const float* __restrict__ kl, const float* __restrict__ w2) {
  __shared__ short KLs[64][72];
  __shared__ short W2t[64][72];
  __shared__ short Ps[4][64][72];
  const int t = threadIdx.x;
  const int tile = blockIdx.x, bh = blockIdx.y;
  const int b = bh >> 3, h = bh & 7;
  const int lane = t & 63, w = t >> 6;
  const int fr = lane & 15, kg = lane >> 4;
  const int n0 = tile * 256;

  f16x8 qf[4][2];
#pragma unroll
  for (int nf = 0; nf < 4; ++nf) {
    const float* qp =
        qkv + ((size_t)b * NPAD + n0 + w * 64 + nf * 16 + fr) * 1536 + h * 64 + kg * 8;
#pragma unroll
    for (int kw = 0; kw < 2; ++kw) {
      float4 a = *(const float4*)(qp + kw * 32);
      float4 c = *(const float4*)(qp + kw * 32 + 4);
      uint4 uu = make_uint4(pk_f16(a.x * 0.125f, a.y * 0.125f),
                            pk_f16(a.z * 0.125f, a.w * 0.125f),
                            pk_f16(c.x * 0.125f, c.y * 0.125f),
                            pk_f16(c.z * 0.125f, c.w * 0.125f));
      qf[nf][kw] = *(f16x8*)&uu;
    }
  }
  f32x4 oacc[4][4];
  f32x4 zero4 = {0.f, 0.f, 0.f, 0.f};
#pragma unroll
  for (int i = 0; i < 4; ++i)
#pragma unroll
    for (int j = 0; j < 4; ++j) oacc[i][j] = zero4;
  float Lp[4] = {0.f, 0.f, 0.f, 0.f};

  const int sr = t >> 2, sc = (t & 3) * 16;
  for (int cb = 0; cb < 4; ++cb) {
    __syncthreads();
    {
      const float* kp = kl + ((size_t)bh * 256 + cb * 64 + sr) * 64 + sc;
      float4 k0 = *(const float4*)kp;
      float4 k1 = *(const float4*)(kp + 4);
      float4 k2 = *(const float4*)(kp + 8);
      float4 k3 = *(const float4*)(kp + 12);
      *(uint4*)&KLs[sr][sc] = make_uint4(pk_f16(k0.x, k0.y), pk_f16(k0.z, k0.w),
                                         pk_f16(k1.x, k1.y), pk_f16(k1.z, k1.w));
      *(uint4*)&KLs[sr][sc + 8] = make_uint4(pk_f16(k2.x, k2.y), pk_f16(k2.z, k2.w),
                                             pk_f16(k3.x, k3.y), pk_f16(k3.z, k3.w));
      const float* wp = w2 + ((size_t)bh * 256 + cb * 64 + sr) * 64 + sc;
      float4 v0 = *(const float4*)wp;
      float4 v1 = *(const float4*)(wp + 4);
      float4 v2 = *(const float4*)(wp + 8);
      float4 v3 = *(const float4*)(wp + 12);
      W2t[sc + 0][sr] = (short)f16_1(v0.x);
      W2t[sc + 1][sr] = (short)f16_1(v0.y);
      W2t[sc + 2][sr] = (short)f16_1(v0.z);
      W2t[sc + 3][sr] = (short)f16_1(v0.w);
      W2t[sc + 4][sr] = (short)f16_1(v1.x);
      W2t[sc + 5][sr] = (short)f16_1(v1.y);
      W2t[sc + 6][sr] = (short)f16_1(v1.z);
      W2t[sc + 7][sr] = (short)f16_1(v1.w);
      W2t[sc + 8][sr] = (short)f16_1(v2.x);
      W2t[sc + 9][sr] = (short)f16_1(v2.y);
      W2t[sc + 10][sr] = (short)f16_1(v2.z);
      W2t[sc + 11][sr] = (short)f16_1(v2.w);
      W2t[sc + 12][sr] = (short)f16_1(v3.x);
      W2t[sc + 13][sr] = (short)f16_1(v3.y);
      W2t[sc + 14][sr] = (short)f16_1(v3.z);
      W2t[sc + 15][sr] = (short)f16_1(v3.w);
    }
    __syncthreads();
    f32x4 sacc[4][4];
#pragma unroll
    for (int i = 0; i < 4; ++i)
#pragma unroll
      for (int j = 0; j < 4; ++j) sacc[i][j] = zero4;
#pragma unroll
    for (int kw = 0; kw < 2; ++kw) {
      f16x8 kf[4];
#pragma unroll
      for (int mf = 0; mf < 4; ++mf)
        kf[mf] = *(const f16x8*)&KLs[mf * 16 + fr][kw * 32 + kg * 8];
#pragma unroll
      for (int mf = 0; mf < 4; ++mf)
#pragma unroll
        for (int nf = 0; nf < 4; ++nf)
          sacc[mf][nf] = __builtin_amdgcn_mfma_f32_16x16x32_f16(kf[mf], qf[nf][kw],
                                                                sacc[mf][nf], 0, 0, 0);
    }
#pragma unroll
    for (int mf = 0; mf < 4; ++mf)
#pragma unroll
      for (int nf = 0; nf < 4; ++nf) {
        f32x4 s = sacc[mf][nf];
        float p0 = __expf(s[0]);
        float p1 = __expf(s[1]);
        float p2 = __expf(s[2]);
        float p3 = __expf(s[3]);
        Lp[nf] += (p0 + p1) + (p2 + p3);
        uint2 pw = make_uint2(pk_f16(p0, p1), pk_f16(p2, p3));
        *(uint2*)&Ps[w][nf * 16 + fr][mf * 16 + kg * 4] = pw;
      }
    __syncthreads();
#pragma unroll
    for (int kw = 0; kw < 2; ++kw) {
      f16x8 vf[4], pf[4];
#pragma unroll
      for (int mf = 0; mf < 4; ++mf)
        vf[mf] = *(const f16x8*)&W2t[mf * 16 + fr][kw * 32 + kg * 8];
#pragma unroll
      for (int nf = 0; nf < 4; ++nf)
        pf[nf] = *(const f16x8*)&Ps[w][nf * 16 + fr][kw * 32 + kg * 8];
#pragma unroll
      for (int mf = 0; mf < 4; ++mf)
#pragma unroll
        for (int nf = 0; nf < 4; ++nf)
          oacc[mf][nf] = __builtin_amdgcn_mfma_f32_16x16x32_f16(vf[mf], pf[nf],
                                                                oacc[mf][nf], 0, 0, 0);
    }
  }
#pragma unroll
  for (int nf = 0; nf < 4; ++nf) {
    Lp[nf] += __shfl_xor(Lp[nf], 16);
    Lp[nf] += __shfl_xor(Lp[nf], 32);
  }
#pragma unroll
  for (int nf = 0; nf < 4; ++nf) {
    float inv = 1.0f / Lp[nf];
    int tok = n0 + w * 64 + nf * 16 + fr;
#pragma unroll
    for (int mf = 0; mf < 4; ++mf) {
      f32x4 o = oacc[mf][nf];
      o[0] *= inv; o[1] *= inv; o[2] *= inv; o[3] *= inv;
      *(f32x4*)(attout + ((size_t)b * NPAD + tok) * DD + h * 64 + mf * 16 + kg * 4) = o;
    }
  }
}

// ---------------- attout += depthwise33(v); grid (NPAD/64, 16 bh)
__global__ __launch_bounds__(256) void k_convres(
    float* __restrict__ attout, const float* __restrict__ qkv,
    const float* __restrict__ resw) {
  __shared__ float vS[96][68];
  __shared__ float w33[33];
  int t = threadIdx.x;
  int tb = blockIdx.x, bh = blockIdx.y;
  int b = bh >> 3, h = bh & 7;
  int n0 = tb * 64;
  if (t < 33) w33[t] = resw[h * 33 + t];
  int sc = (t & 3) * 16;
#pragma unroll
  for (int pass = 0; pass < 2; ++pass) {
    int r = (t >> 2) + pass * 64;
    if (r < 96) {
      int seq = n0 - 16 + r;
      if (seq >= 0 && seq < NPAD) {
        const float* p = qkv + ((size_t)b * NPAD + seq) * 1536 + 1024 + h * 64 + sc;
#pragma unroll
        for (int i = 0; i < 16; i += 4) *(float4*)&vS[r][sc + i] = *(const float4*)(p + i);
      } else {
        float4 z = {0, 0, 0, 0};
#pragma unroll
        for (int i = 0; i < 16; i += 4) *(float4*)&vS[r][sc + i] = z;
      }
    }
  }
  __syncthreads();
  int tg = t >> 5;
  int d2 = (t & 31) * 2;
#pragma unroll
  for (int tk = 0; tk < 8; ++tk) {
    int tokL = tg * 8 + tk;
    float ax = 0.f, ay = 0.f;
    for (int k = 0; k < 33; ++k) {
      float2 v = *(float2*)&vS[tokL + k][d2];
      ax += w33[k] * v.x;
      ay += w33[k] * v.y;
    }
    float* dst = attout + ((size_t)b * NPAD + n0 + tokL) * DD + h * 64 + d2;
    float2 o = *(float2*)dst;
    o.x += ax;
    o.y += ay;
    *(float2*)dst = o;
  }
}

// ---------------------------------------------------------------- PPEG (combined 7x7)
__global__ __launch_bounds__(128) void k_ppeg(
    float* __restrict__ hB, const float* __restrict__ hA,
    const float* __restrict__ w7, const float* __restrict__ b7,
    const float* __restrict__ w5, const float* __restrict__ b5,
    const float* __restrict__ w3, const float* __restrict__ b3) {
  __shared__ float cw[49][128];
  int t = threadIdx.x;
  int i = blockIdx.x >> 2;
  int j0 = (blockIdx.x & 3) * 32;
  int cg = blockIdx.y, b = blockIdx.z;
  int c = cg * 128 + t;
#pragma unroll
  for (int k = 0; k < 49; ++k) cw[k][t] = w7[c * 49 + k];
#pragma unroll
  for (int di = 0; di < 5; ++di)
#pragma unroll
    for (int dj = 0; dj < 5; ++dj)
      cw[(di + 1) * 7 + dj + 1][t] += w5[c * 25 + di * 5 + dj];
#pragma unroll
  for (int di = 0; di < 3; ++di)
#pragma unroll
    for (int dj = 0; dj < 3; ++dj)
      cw[(di + 2) * 7 + dj + 2][t] += w3[c * 9 + di * 3 + dj];
  cw[24][t] += 1.0f;
  float bias = b7[c] + b5[c] + b3[c];
  const float* base = hA + (size_t)b * TT * DD + DD + c;
  float* obase = hB + (size_t)b * TT * DD + DD + c;
  float acc[32];
#pragma unroll
  for (int j = 0; j < 32; ++j) acc[j] = bias;
  for (int di = 0; di < 7; ++di) {
    int ii = i + di - 3;
    if ((unsigned)ii >= 128u) continue;
    float win[38];
#pragma unroll
    for (int w = 0; w < 38; ++w) {
      int col = j0 - 3 + w;
      win[w] = ((unsigned)col < 128u) ? base[(size_t)(ii * 128 + col) * DD] : 0.f;
    }
#pragma unroll
    for (int dj = 0; dj < 7; ++dj) {
      float wv = cw[di * 7 + dj][t];
#pragma unroll
      for (int j = 0; j < 32; ++j) acc[j] += win[j + dj] * wv;
    }
  }
#pragma unroll
  for (int j = 0; j < 32; ++j) obase[(size_t)(i * 128 + j0 + j) * DD] = acc[j];
}

// ---------------------------------------------------------------- final head
__global__ __launch_bounds__(512) void k_final(
    float* __restrict__ out, const float* __restrict__ h,
    const float* __restrict__ g, const float* __restrict__ be,
    const float* __restrict__ cw, const float* __restrict__ cbias) {
  __shared__ float sm[16];
  int t = threadIdx.x;
  for (int b = 0; b < 2; ++b) {
    const float* row = h + (size_t)b * TT * DD;
    float x = row[t];
    float s = x;
    for (int o = 32; o; o >>= 1) s += __shfl_xor(s, o);
    if ((t & 63) == 0) sm[t >> 6] = s;
    __syncthreads();
    float mu = 0.f;
    for (int i = 0; i < 8; ++i) mu += sm[i];
    mu *= (1.f / 512.f);
    __syncthreads();
    float d = x - mu;
    s = d * d;
    for (int o = 32; o; o >>= 1) s += __shfl_xor(s, o);
    if ((t & 63) == 0) sm[t >> 6] = s;
    __syncthreads();
    float var = 0.f;
    for (int i = 0; i < 8; ++i) var += sm[i];
    var *= (1.f / 512.f);
    float rs = rsqrtf(var + 1e-5f);
    __syncthreads();
    float f = d * rs * g[t] + be[t];
    float p0 = f * cw[2 * t], p1 = f * cw[2 * t + 1];
    for (int o = 32; o; o >>= 1) {
      p0 += __shfl_xor(p0, o);
      p1 += __shfl_xor(p1, o);
    }
    if ((t & 63) == 0) {
      sm[t >> 6] = p0;
      sm[8 + (t >> 6)] = p1;
    }
    __syncthreads();
    if (t == 0) {
      float q0 = 0.f, q1 = 0.f;
      for (int i = 0; i < 8; ++i) {
        q0 += sm[i];
        q1 += sm[8 + i];
      }
      out[b * 2 + 0] = q0 + cbias[0];
      out[b * 2 + 1] = q1 + cbias[1];
    }
    __syncthreads();
  }
}

// ---------------------------------------------------------------- host side
static void run_attn(float* h, const float* lng, const float* lnb,
                     const float* wqkv, const float* wout, const float* bout,
                     const float* resw, float* xp, float* qkv, float* ql, float* kl,
                     float* a2, float* z0, float* z1, float* xz, float* yA, float* yB,
                     float* yC, float* bv, float* w2, float* red, float* Sbuf,
                     unsigned short* wth, hipStream_t stream) {
  // xp region doubles as: [f16 hi/lo planes for LN output] then [fp32 attout]
  unsigned short* xph = (unsigned short*)xp;
  unsigned short* xpl = xph + (size_t)BB * NPAD * DD;
  k_zero_pad<<<BB * PADF, 256, 0, stream>>>(xph, xpl);
  k_ln_pad<<<(BB * TT + 3) / 4, 256, 0, stream>>>(xph, xpl, h, lng, lnb);
  k_cvt_wt<<<dim3(DD / 32, 1536 / 32), 256, 0, stream>>>(wqkv, wth, DD, 1536);
  k_gemm_mfma<1><<<dim3(BB * NPAD / 128, 1536 / 128), 256, 0, stream>>>(
      nullptr, xph, xpl, wth, nullptr, qkv, BB * NPAD, DD, 1536, DD);
  k_landmarks<<<1024, 256, 0, stream>>>(ql, kl, qkv);
  float* pacc = Sbuf;
  float* pL = Sbuf + (size_t)A3KC * 4096 * 64;
  k_a3v_mfma<<<dim3(16, A3KC), 256, 0, stream>>>(pacc, pL, ql, qkv);
  k_a3v_red<<<4096, 64, 0, stream>>>(bv, pacc, pL);
  k_sim2<<<dim3(4, 4, 16), 256, 0, stream>>>(a2, ql, kl);
  k_softmax256<<<1024, 256, 0, stream>>>(a2);
  k_pinv_sums<<<16, 256, 0, stream>>>(red, a2);
  k_pinv_scale<<<1, 256, 0, stream>>>(red);
  k_zinit<<<dim3(256, 16), 256, 0, stream>>>(z0, a2, red);
  float* zc = z0;
  float* zn = z1;
  for (int it = 0; it < 6; ++it) {
    k_bmm_mfma<<<dim3(4, 4, 16), 256, 0, stream>>>(a2, zc, xz, 1.f, 0.f, yA, -1.f, 7.f, 256);
    k_bmm_mfma<<<dim3(4, 4, 16), 256, 0, stream>>>(xz, yA, yB, -1.f, 15.f, nullptr, 0.f, 0.f, 256);
    k_bmm_mfma<<<dim3(4, 4, 16), 256, 0, stream>>>(xz, yB, yC, -1.f, 13.f, nullptr, 0.f, 0.f, 256);
    k_bmm_mfma<<<dim3(4, 4, 16), 256, 0, stream>>>(zc, yC, zn, 0.25f, 0.f, nullptr, 0.f, 0.f, 256);
    float* tmp = zc; zc = zn; zn = tmp;
  }
  k_bmm_mfma<<<dim3(1, 4, 16), 256, 0, stream>>>(zc, bv, w2, 1.f, 0.f, nullptr, 0.f, 0.f, 64);
  k_att1<<<dim3(NPAD / 256, 16), 256, 0, stream>>>(xp, qkv, kl, w2);
  k_convres<<<dim3(NPAD / 64, 16), 256, 0, stream>>>(xp, qkv, resw);
  k_cvt_wt<<<dim3(DD / 32, DD / 32), 256, 0, stream>>>(wout, wth, DD, DD);
  k_gemm_mfma<2><<<dim3(129, 4, BB), 256, 0, stream>>>(xp, nullptr, nullptr, wth, bout,
                                                       h, TT, DD, DD, DD);
}

extern "C" void kernel_launch(void* const* d_in, const int* in_sizes, int n_in,
                              void* d_out, int out_size, void* d_ws, size_t ws_size,
                              hipStream_t stream) {
  const float* x        = (const float*)d_in[0];
  const float* w_feat   = (const float*)d_in[1];
  const float* b_feat   = (const float*)d_in[2];
  const float* cls_tok  = (const float*)d_in[3];
  const float* ln1_g    = (const float*)d_in[4];
  const float* ln1_b    = (const float*)d_in[5];
  const float* qkv1     = (const float*)d_in[6];
  const float* out1_w   = (const float*)d_in[7];
  const float* out1_b   = (const float*)d_in[8];
  const float* res1_w   = (const float*)d_in[9];
  const float* ppeg_w7  = (const float*)d_in[10];
  const float* ppeg_b7  = (const float*)d_in[11];
  const float* ppeg_w5  = (const float*)d_in[12];
  const float* ppeg_b5  = (const float*)d_in[13];
  const float* ppeg_w3  = (const float*)d_in[14];
  const float* ppeg_b3  = (const float*)d_in[15];
  const float* ln2_g    = (const float*)d_in[16];
  const float* ln2_b    = (const float*)d_in[17];
  const float* qkv2     = (const float*)d_in[18];
  const float* out2_w   = (const float*)d_in[19];
  const float* out2_b   = (const float*)d_in[20];
  const float* res2_w   = (const float*)d_in[21];
  const float* lnf_g    = (const float*)d_in[22];
  const float* lnf_b    = (const float*)d_in[23];
  const float* cls_w    = (const float*)d_in[24];
  const float* cls_b    = (const float*)d_in[25];

  float* ws = (float*)d_ws;
  size_t off = 0;
  float* hA  = ws + off; off += (size_t)BB * TT * DD;
  float* hB  = ws + off; off += (size_t)BB * TT * DD;
  float* xp  = ws + off; off += (size_t)BB * NPAD * DD;
  float* qkv = ws + off; off += (size_t)BB * NPAD * 3 * DD;
  float* ql  = ws + off; off += (size_t)BB * HH * 256 * 64;
  float* kl  = ws + off; off += (size_t)BB * HH * 256 * 64;
  float* a2  = ws + off; off += (size_t)16 * 65536;
  float* z0  = ws + off; off += (size_t)16 * 65536;
  float* z1  = ws + off; off += (size_t)16 * 65536;
  float* xz  = ws + off; off += (size_t)16 * 65536;
  float* yA  = ws + off; off += (size_t)16 * 65536;
  float* yB  = ws + off; off += (size_t)16 * 65536;
  float* yC  = ws + off; off += (size_t)16 * 65536;
  float* bv  = ws + off; off += (size_t)BB * HH * 256 * 64;
  float* w2  = ws + off; off += (size_t)BB * HH * 256 * 64;
  float* red = ws + off; off += 8448;
  unsigned short* wth = (unsigned short*)(ws + off); off += 393216;

  // Stage 1: h = gelu(x @ w_feat + b_feat), prepend cls token
  k_set_cls<<<2, 512, 0, stream>>>(hA, cls_tok);
  k_cvt_wt<<<dim3(1024 / 32, DD / 32), 256, 0, stream>>>(w_feat, wth, 1024, DD);
  k_gemm_mfma<0><<<dim3(32768 / 128, DD / 128), 256, 0, stream>>>(
      x, nullptr, nullptr, wth, b_feat, hA, 32768, 1024, DD, 1024);
  // Attention 1 (residual in-place on hA; hB is dead -> scratch)
  run_attn(hA, ln1_g, ln1_b, qkv1, out1_w, out1_b, res1_w, xp, qkv, ql, kl, a2, z0, z1,
           xz, yA, yB, yC, bv, w2, red, hB, wth, stream);
  // PPEG: hB = ppeg(hA)
  k_copy_cls<<<2, 512, 0, stream>>>(hB, hA);
  k_ppeg<<<dim3(512, 4, 2), 128, 0, stream>>>(hB, hA, ppeg_w7, ppeg_b7, ppeg_w5, ppeg_b5,
                                              ppeg_w3, ppeg_b3);
  // Attention 2 (residual in-place on hB; hA is dead -> scratch)
  run_attn(hB, ln2_g, ln2_b, qkv2, out2_w, out2_b, res2_w, xp, qkv, ql, kl, a2, z0, z1,
           xz, yA, yB, yC, bv, w2, red, hA, wth, stream);
  // Final: LN(cls) @ cls_w + cls_b
  k_final<<<1, 512, 0, stream>>>((float*)d_out, hB, lnf_g, lnf_b, cls_w, cls_b);
}